// Round 4
// baseline (10432.781 us; speedup 1.0000x reference)
//
#include <hip/hip_runtime.h>
#include <hip/hip_bf16.h>

#define NLIG 40000
#define NPRO 40000
#define NGRAPH 64
#define ELL 160000
#define ELP 240000
#define EPL 240000

// ---------- naive GEMM: C[M,256] = A[M,K] @ B[K,256], one thread/output ----------
__global__ __launch_bounds__(256) void gemm_naive(
    const float* __restrict__ A, const float* __restrict__ B,
    float* __restrict__ C, int M, int K) {
  const int t = blockIdx.x * 256 + threadIdx.x;
  if (t >= M * 256) return;
  const int m = t >> 8, c = t & 255;
  float s = 0.f;
  for (int k = 0; k < K; ++k)
    s = fmaf(A[(size_t)m * K + k], B[(size_t)k * 256 + c], s);
  C[t] = s;
}

// ---------- dot_av: out[n*4+h] = sum_{d<64} F[n,h*64+d] * avec[h*64+d] ----------
__global__ __launch_bounds__(256) void dot_av_kernel(
    const float* __restrict__ F, const float* __restrict__ avec,
    float* __restrict__ out, int n) {
  const int t = blockIdx.x * 256 + threadIdx.x;
  if (t >= n * 4) return;
  const int nn = t >> 2, h = t & 3;
  float s = 0.f;
  for (int d = 0; d < 64; ++d)
    s = fmaf(F[(size_t)nn * 256 + h * 64 + d], avec[h * 64 + d], s);
  out[t] = s;
}

// ---------- pass A: softmax denominator per (dst,head) ----------
__global__ __launch_bounds__(256) void edge_ssum_kernel(
    const float* __restrict__ el, const float* __restrict__ er,
    const int* __restrict__ src, const int* __restrict__ dst,
    float* __restrict__ ssum, int E) {
  const int t = blockIdx.x * 256 + threadIdx.x;
  if (t >= E * 4) return;
  const int i = t >> 2, h = t & 3;
  float e = el[src[i] * 4 + h] + er[dst[i] * 4 + h];
  e = e > 0.f ? e : 0.2f * e;
  atomicAdd(&ssum[dst[i] * 4 + h], expf(e));
}

// ---------- pass B: one wave per edge, scatter normalized contribution ----------
__global__ __launch_bounds__(256) void edge_scatter_kernel(
    const float* __restrict__ F, const float* __restrict__ el,
    const float* __restrict__ er, const float* __restrict__ ssum,
    const int* __restrict__ src, const int* __restrict__ dst,
    float* __restrict__ out, int E) {
  const int lane = threadIdx.x & 63;
  const int gw = (blockIdx.x * blockDim.x + threadIdx.x) >> 6;
  if (gw >= E) return;
  const int s = src[gw], d = dst[gw];
  const int myh = lane >> 4;
  float e = el[s * 4 + myh] + er[d * 4 + myh];
  e = e > 0.f ? e : 0.2f * e;
  const float w = expf(e) / ssum[d * 4 + myh];
  const float4 f = *reinterpret_cast<const float4*>(&F[(size_t)s * 256 + lane * 4]);
  float* po = &out[(size_t)d * 256 + lane * 4];
  atomicAdd(po + 0, w * f.x);
  atomicAdd(po + 1, w * f.y);
  atomicAdd(po + 2, w * f.z);
  atomicAdd(po + 3, w * f.w);
}

// ---------- bias (+optional second bias) + relu, in-place ----------
__global__ __launch_bounds__(256) void bias_relu_kernel(
    float* __restrict__ h, const float* __restrict__ b1,
    const float* __restrict__ b2, int n) {
  const int tot = n * 64;  // float4 count
  for (int i = blockIdx.x * blockDim.x + threadIdx.x; i < tot; i += gridDim.x * blockDim.x) {
    const int c4 = (i & 63) * 4;
    float4 v = reinterpret_cast<float4*>(h)[i];
    float4 bb = *reinterpret_cast<const float4*>(&b1[c4]);
    if (b2) {
      const float4 b2v = *reinterpret_cast<const float4*>(&b2[c4]);
      bb.x += b2v.x; bb.y += b2v.y; bb.z += b2v.z; bb.w += b2v.w;
    }
    v.x = fmaxf(v.x + bb.x, 0.f);
    v.y = fmaxf(v.y + bb.y, 0.f);
    v.z = fmaxf(v.z + bb.z, 0.f);
    v.w = fmaxf(v.w + bb.w, 0.f);
    reinterpret_cast<float4*>(h)[i] = v;
  }
}

// ---------- graph readout: atomic sum per graph ----------
__global__ __launch_bounds__(256) void graph_sum_kernel(
    const float* __restrict__ h, const int* __restrict__ gid,
    float* __restrict__ gsum, int* __restrict__ gcnt,
    int n, int colofs, int cntofs) {
  const int lane = threadIdx.x & 63;
  const int gw = (blockIdx.x * blockDim.x + threadIdx.x) >> 6;
  if (gw >= n) return;
  const int g = gid[gw];
  const float4 v = *reinterpret_cast<const float4*>(&h[(size_t)gw * 256 + lane * 4]);
  float* base = gsum + (size_t)g * 512 + colofs + lane * 4;
  atomicAdd(base + 0, v.x);
  atomicAdd(base + 1, v.y);
  atomicAdd(base + 2, v.z);
  atomicAdd(base + 3, v.w);
  if (lane == 0) atomicAdd(&gcnt[cntofs + g], 1);
}

// ---------- final MLP: out[b,c] = relu(bm[c] + sum_k g[b,k]*Wm[k,c]) ----------
// NOTE: output is FLOAT32 (reference returns f32).
__global__ __launch_bounds__(256) void mlp_kernel(
    const float* __restrict__ gsum, const int* __restrict__ gcnt,
    const float* __restrict__ Wm, const float* __restrict__ bm,
    float* __restrict__ out) {
  __shared__ float g[512];
  const int b = blockIdx.x, t = threadIdx.x;
  const float cl = fmaxf((float)gcnt[b], 1.f);
  const float cp = fmaxf((float)gcnt[64 + b], 1.f);
  for (int k = t; k < 512; k += 256)
    g[k] = gsum[(size_t)b * 512 + k] * (k < 256 ? 1.f / cl : 1.f / cp);
  __syncthreads();
  float acc = bm[t];
  for (int k = 0; k < 512; ++k) acc = fmaf(g[k], Wm[(size_t)k * 256 + t], acc);
  out[b * 256 + t] = fmaxf(acc, 0.f);
}

// =====================================================================
extern "C" void kernel_launch(void* const* d_in, const int* in_sizes, int n_in,
                              void* d_out, int out_size, void* d_ws, size_t ws_size,
                              hipStream_t stream) {
  const float* x_lig  = (const float*)d_in[0];
  const float* x_pro  = (const float*)d_in[1];
  const float* W1_ll  = (const float*)d_in[2];
  const float* al1_ll = (const float*)d_in[3];
  const float* ar1_ll = (const float*)d_in[4];
  const float* b1_ll  = (const float*)d_in[5];
  const float* W1_lps = (const float*)d_in[6];
  const float* W1_lpd = (const float*)d_in[7];
  const float* al1_lp = (const float*)d_in[8];
  const float* ar1_lp = (const float*)d_in[9];
  const float* b1_lp  = (const float*)d_in[10];
  const float* W1_pls = (const float*)d_in[11];
  const float* W1_pld = (const float*)d_in[12];
  const float* al1_pl = (const float*)d_in[13];
  const float* ar1_pl = (const float*)d_in[14];
  const float* b1_pl  = (const float*)d_in[15];
  const float* W2_ll  = (const float*)d_in[16];
  const float* al2_ll = (const float*)d_in[17];
  const float* ar2_ll = (const float*)d_in[18];
  const float* b2_ll  = (const float*)d_in[19];
  const float* W2_lps = (const float*)d_in[20];
  const float* W2_lpd = (const float*)d_in[21];
  const float* al2_lp = (const float*)d_in[22];
  const float* ar2_lp = (const float*)d_in[23];
  const float* b2_lp  = (const float*)d_in[24];
  const float* W2_pls = (const float*)d_in[25];
  const float* W2_pld = (const float*)d_in[26];
  const float* al2_pl = (const float*)d_in[27];
  const float* ar2_pl = (const float*)d_in[28];
  const float* b2_pl  = (const float*)d_in[29];
  const float* W_mlp  = (const float*)d_in[30];
  const float* b_mlp  = (const float*)d_in[31];
  const int* src_ll   = (const int*)d_in[32];
  const int* dst_ll   = (const int*)d_in[33];
  const int* src_lp   = (const int*)d_in[34];
  const int* dst_lp   = (const int*)d_in[35];
  const int* src_pl   = (const int*)d_in[36];
  const int* dst_pl   = (const int*)d_in[37];
  const int* gid_lig  = (const int*)d_in[38];
  const int* gid_pro  = (const int*)d_in[39];
  float* out = (float*)d_out;
  (void)in_sizes; (void)n_in; (void)out_size; (void)ws_size;

  // -------- workspace carving (~166 MB) --------
  size_t cur = 0;
  auto carve = [&](size_t bytes) -> char* {
    char* p = (char*)d_ws + cur;
    cur += (bytes + 511) & ~(size_t)511;
    return p;
  };
  const size_t NB = (size_t)40000 * 256 * sizeof(float);
  float* F    = (float*)carve(NB);   // fs / fd staging
  float* h_l  = (float*)carve(NB);
  float* h_p  = (float*)carve(NB);
  float* hX   = (float*)carve(NB);   // h_l2, then reused for h_p2
  float* el   = (float*)carve((size_t)40000 * 4 * sizeof(float));
  float* er   = (float*)carve((size_t)40000 * 4 * sizeof(float));
  float* ssum = (float*)carve((size_t)40000 * 4 * sizeof(float));
  float* gsum = (float*)carve((size_t)64 * 512 * sizeof(float));
  int* gcnt   = (int*)carve(128 * sizeof(int));

  const int B256 = 256;
  auto thrGrid  = [](long long n) { return (int)((n + 255) / 256); };
  auto waveGrid = [](int n) { return (n + 3) / 4; };  // 1 wave per item

  auto run_gemm = [&](const float* A, const float* Bw, float* C, int M, int K) {
    gemm_naive<<<thrGrid((long long)M * 256), B256, 0, stream>>>(A, Bw, C, M, K);
  };
  auto run_dot = [&](const float* Fm, const float* av, float* o, int n) {
    dot_av_kernel<<<thrGrid((long long)n * 4), B256, 0, stream>>>(Fm, av, o, n);
  };
  auto run_edges = [&](const int* s, const int* d, int E, int nDst, float* outbuf) {
    hipMemsetAsync(ssum, 0, (size_t)nDst * 4 * sizeof(float), stream);
    edge_ssum_kernel<<<thrGrid((long long)E * 4), B256, 0, stream>>>(el, er, s, d, ssum, E);
    edge_scatter_kernel<<<waveGrid(E), B256, 0, stream>>>(F, el, er, ssum, s, d, outbuf, E);
  };

  // ================= LAYER 1 =================
  // ligand dst: ll + pl
  hipMemsetAsync(h_l, 0, NB, stream);
  // ll: fs = fd = x_lig @ W1_ll
  run_gemm(x_lig, W1_ll, F, NLIG, 74);
  run_dot(F, al1_ll, el, NLIG);
  run_dot(F, ar1_ll, er, NLIG);
  run_edges(src_ll, dst_ll, ELL, NLIG, h_l);
  // pl: fd = x_lig @ W1_pld -> er; fs = x_pro @ W1_pls -> el; aggregate
  run_gemm(x_lig, W1_pld, F, NLIG, 74);
  run_dot(F, ar1_pl, er, NLIG);
  run_gemm(x_pro, W1_pls, F, NPRO, 128);
  run_dot(F, al1_pl, el, NPRO);
  run_edges(src_pl, dst_pl, EPL, NLIG, h_l);
  bias_relu_kernel<<<2048, B256, 0, stream>>>(h_l, b1_ll, b1_pl, NLIG);
  // protein dst: lp
  hipMemsetAsync(h_p, 0, NB, stream);
  run_gemm(x_pro, W1_lpd, F, NPRO, 128);
  run_dot(F, ar1_lp, er, NPRO);
  run_gemm(x_lig, W1_lps, F, NLIG, 74);
  run_dot(F, al1_lp, el, NLIG);
  run_edges(src_lp, dst_lp, ELP, NPRO, h_p);
  bias_relu_kernel<<<2048, B256, 0, stream>>>(h_p, b1_lp, nullptr, NPRO);

  // ================= LAYER 2 =================
  // ligand dst: ll + pl  -> hX (= h_l2)
  hipMemsetAsync(hX, 0, NB, stream);
  run_gemm(h_l, W2_ll, F, NLIG, 256);
  run_dot(F, al2_ll, el, NLIG);
  run_dot(F, ar2_ll, er, NLIG);
  run_edges(src_ll, dst_ll, ELL, NLIG, hX);
  run_gemm(h_l, W2_pld, F, NLIG, 256);
  run_dot(F, ar2_pl, er, NLIG);
  run_gemm(h_p, W2_pls, F, NPRO, 256);
  run_dot(F, al2_pl, el, NPRO);
  run_edges(src_pl, dst_pl, EPL, NLIG, hX);
  bias_relu_kernel<<<2048, B256, 0, stream>>>(hX, b2_ll, b2_pl, NLIG);

  // readout of h_l2 NOW, so hX can be reused for h_p2
  hipMemsetAsync(gsum, 0, (size_t)64 * 512 * sizeof(float), stream);
  hipMemsetAsync(gcnt, 0, 128 * sizeof(int), stream);
  graph_sum_kernel<<<waveGrid(NLIG), B256, 0, stream>>>(hX, gid_lig, gsum, gcnt, NLIG, 0, 0);

  // protein dst: lp -> hX (= h_p2)
  run_gemm(h_p, W2_lpd, F, NPRO, 256);
  run_dot(F, ar2_lp, er, NPRO);
  run_gemm(h_l, W2_lps, F, NLIG, 256);
  run_dot(F, al2_lp, el, NLIG);
  hipMemsetAsync(hX, 0, NB, stream);
  run_edges(src_lp, dst_lp, ELP, NPRO, hX);
  bias_relu_kernel<<<2048, B256, 0, stream>>>(hX, b2_lp, nullptr, NPRO);
  graph_sum_kernel<<<waveGrid(NPRO), B256, 0, stream>>>(hX, gid_pro, gsum, gcnt, NPRO, 256, 64);

  // ================= MLP =================
  mlp_kernel<<<64, B256, 0, stream>>>(gsum, gcnt, W_mlp, b_mlp, out);
}

// Round 5
// 6043.215 us; speedup vs baseline: 1.7264x; 1.7264x over previous
//
#include <hip/hip_runtime.h>
#include <hip/hip_bf16.h>

#define NLIG 40000
#define NPRO 40000
#define NGRAPH 64
#define ELL 160000
#define ELP 240000
#define EPL 240000

// ---------------- tiled GEMM: C[M,256] = A[M,K] @ B[K,256] ----------------
// 64x64 output tile per 256-thread block, 4x4 accumulators/thread.
__global__ __launch_bounds__(256) void sgemm256(
    const float* __restrict__ A, const float* __restrict__ B,
    float* __restrict__ C, int M, int K) {
  __shared__ float As[16][68];
  __shared__ float Bs[16][68];
  const int t = threadIdx.x;
  const int m0 = blockIdx.x * 64;
  const int n0 = blockIdx.y * 64;
  const int tx = t & 15, ty = t >> 4;
  float acc[4][4] = {};
  for (int k0 = 0; k0 < K; k0 += 16) {
    {
      const int r = t >> 2;          // 0..63 (tile row)
      const int c4 = (t & 3) * 4;    // k-offset within chunk
      const int row = m0 + r;
      const bool rok = row < M;
#pragma unroll
      for (int j = 0; j < 4; ++j) {
        const int kk = k0 + c4 + j;
        As[c4 + j][r] = (rok && kk < K) ? A[(size_t)row * K + kk] : 0.f;
      }
    }
    {
      const int rr = t >> 6;         // 0..3
      const int c = t & 63;
#pragma unroll
      for (int j = 0; j < 4; ++j) {
        const int kk = k0 + rr + j * 4;
        Bs[rr + j * 4][c] = (kk < K) ? B[(size_t)kk * 256 + n0 + c] : 0.f;
      }
    }
    __syncthreads();
#pragma unroll
    for (int kk = 0; kk < 16; ++kk) {
      const float4 av = *reinterpret_cast<const float4*>(&As[kk][ty * 4]);
      const float4 bv = *reinterpret_cast<const float4*>(&Bs[kk][tx * 4]);
      const float a[4] = {av.x, av.y, av.z, av.w};
      const float b[4] = {bv.x, bv.y, bv.z, bv.w};
#pragma unroll
      for (int i = 0; i < 4; ++i)
#pragma unroll
        for (int j = 0; j < 4; ++j) acc[i][j] = fmaf(a[i], b[j], acc[i][j]);
    }
    __syncthreads();
  }
#pragma unroll
  for (int i = 0; i < 4; ++i) {
    const int row = m0 + ty * 4 + i;
    if (row < M) {
      float4 o = {acc[i][0], acc[i][1], acc[i][2], acc[i][3]};
      *reinterpret_cast<float4*>(&C[(size_t)row * 256 + n0 + tx * 4]) = o;
    }
  }
}

// ---------- dot_av: out[n*4+h] = sum_{d<64} F[n,h*64+d] * avec[h*64+d] ----------
__global__ __launch_bounds__(256) void dot_av_kernel(
    const float* __restrict__ F, const float* __restrict__ avec,
    float* __restrict__ out, int n) {
  const int t = blockIdx.x * 256 + threadIdx.x;
  if (t >= n * 4) return;
  const int nn = t >> 2, h = t & 3;
  float s = 0.f;
  for (int d = 0; d < 64; ++d)
    s = fmaf(F[(size_t)nn * 256 + h * 64 + d], avec[h * 64 + d], s);
  out[t] = s;
}

// ---------- pass A: softmax denominator per (dst,head) ----------
__global__ __launch_bounds__(256) void edge_ssum_kernel(
    const float* __restrict__ el, const float* __restrict__ er,
    const int* __restrict__ src, const int* __restrict__ dst,
    float* __restrict__ ssum, int E) {
  const int t = blockIdx.x * 256 + threadIdx.x;
  if (t >= E * 4) return;
  const int i = t >> 2, h = t & 3;
  float e = el[src[i] * 4 + h] + er[dst[i] * 4 + h];
  e = e > 0.f ? e : 0.2f * e;
  atomicAdd(&ssum[dst[i] * 4 + h], expf(e));
}

// ---------- pass B: one wave per edge, scatter normalized contribution ----------
__global__ __launch_bounds__(256) void edge_scatter_kernel(
    const float* __restrict__ F, const float* __restrict__ el,
    const float* __restrict__ er, const float* __restrict__ ssum,
    const int* __restrict__ src, const int* __restrict__ dst,
    float* __restrict__ out, int E) {
  const int lane = threadIdx.x & 63;
  const int gw = (blockIdx.x * blockDim.x + threadIdx.x) >> 6;
  if (gw >= E) return;
  const int s = src[gw], d = dst[gw];
  const int myh = lane >> 4;
  float e = el[s * 4 + myh] + er[d * 4 + myh];
  e = e > 0.f ? e : 0.2f * e;
  const float w = expf(e) / ssum[d * 4 + myh];
  const float4 f = *reinterpret_cast<const float4*>(&F[(size_t)s * 256 + lane * 4]);
  float* po = &out[(size_t)d * 256 + lane * 4];
  atomicAdd(po + 0, w * f.x);
  atomicAdd(po + 1, w * f.y);
  atomicAdd(po + 2, w * f.z);
  atomicAdd(po + 3, w * f.w);
}

// ---------- bias (+optional second bias) + relu, in-place ----------
__global__ __launch_bounds__(256) void bias_relu_kernel(
    float* __restrict__ h, const float* __restrict__ b1,
    const float* __restrict__ b2, int n) {
  const int tot = n * 64;  // float4 count
  for (int i = blockIdx.x * blockDim.x + threadIdx.x; i < tot; i += gridDim.x * blockDim.x) {
    const int c4 = (i & 63) * 4;
    float4 v = reinterpret_cast<float4*>(h)[i];
    float4 bb = *reinterpret_cast<const float4*>(&b1[c4]);
    if (b2) {
      const float4 b2v = *reinterpret_cast<const float4*>(&b2[c4]);
      bb.x += b2v.x; bb.y += b2v.y; bb.z += b2v.z; bb.w += b2v.w;
    }
    v.x = fmaxf(v.x + bb.x, 0.f);
    v.y = fmaxf(v.y + bb.y, 0.f);
    v.z = fmaxf(v.z + bb.z, 0.f);
    v.w = fmaxf(v.w + bb.w, 0.f);
    reinterpret_cast<float4*>(h)[i] = v;
  }
}

// ---------- graph readout: atomic sum per graph ----------
__global__ __launch_bounds__(256) void graph_sum_kernel(
    const float* __restrict__ h, const int* __restrict__ gid,
    float* __restrict__ gsum, int* __restrict__ gcnt,
    int n, int colofs, int cntofs) {
  const int lane = threadIdx.x & 63;
  const int gw = (blockIdx.x * blockDim.x + threadIdx.x) >> 6;
  if (gw >= n) return;
  const int g = gid[gw];
  const float4 v = *reinterpret_cast<const float4*>(&h[(size_t)gw * 256 + lane * 4]);
  float* base = gsum + (size_t)g * 512 + colofs + lane * 4;
  atomicAdd(base + 0, v.x);
  atomicAdd(base + 1, v.y);
  atomicAdd(base + 2, v.z);
  atomicAdd(base + 3, v.w);
  if (lane == 0) atomicAdd(&gcnt[cntofs + g], 1);
}

// ---------- final MLP: out[b,c] = relu(bm[c] + sum_k g[b,k]*Wm[k,c]) ----------
__global__ __launch_bounds__(256) void mlp_kernel(
    const float* __restrict__ gsum, const int* __restrict__ gcnt,
    const float* __restrict__ Wm, const float* __restrict__ bm,
    float* __restrict__ out) {
  __shared__ float g[512];
  const int b = blockIdx.x, t = threadIdx.x;
  const float cl = fmaxf((float)gcnt[b], 1.f);
  const float cp = fmaxf((float)gcnt[64 + b], 1.f);
  for (int k = t; k < 512; k += 256)
    g[k] = gsum[(size_t)b * 512 + k] * (k < 256 ? 1.f / cl : 1.f / cp);
  __syncthreads();
  float acc = bm[t];
  for (int k = 0; k < 512; ++k) acc = fmaf(g[k], Wm[(size_t)k * 256 + t], acc);
  out[b * 256 + t] = fmaxf(acc, 0.f);
}

// =====================================================================
extern "C" void kernel_launch(void* const* d_in, const int* in_sizes, int n_in,
                              void* d_out, int out_size, void* d_ws, size_t ws_size,
                              hipStream_t stream) {
  const float* x_lig  = (const float*)d_in[0];
  const float* x_pro  = (const float*)d_in[1];
  const float* W1_ll  = (const float*)d_in[2];
  const float* al1_ll = (const float*)d_in[3];
  const float* ar1_ll = (const float*)d_in[4];
  const float* b1_ll  = (const float*)d_in[5];
  const float* W1_lps = (const float*)d_in[6];
  const float* W1_lpd = (const float*)d_in[7];
  const float* al1_lp = (const float*)d_in[8];
  const float* ar1_lp = (const float*)d_in[9];
  const float* b1_lp  = (const float*)d_in[10];
  const float* W1_pls = (const float*)d_in[11];
  const float* W1_pld = (const float*)d_in[12];
  const float* al1_pl = (const float*)d_in[13];
  const float* ar1_pl = (const float*)d_in[14];
  const float* b1_pl  = (const float*)d_in[15];
  const float* W2_ll  = (const float*)d_in[16];
  const float* al2_ll = (const float*)d_in[17];
  const float* ar2_ll = (const float*)d_in[18];
  const float* b2_ll  = (const float*)d_in[19];
  const float* W2_lps = (const float*)d_in[20];
  const float* W2_lpd = (const float*)d_in[21];
  const float* al2_lp = (const float*)d_in[22];
  const float* ar2_lp = (const float*)d_in[23];
  const float* b2_lp  = (const float*)d_in[24];
  const float* W2_pls = (const float*)d_in[25];
  const float* W2_pld = (const float*)d_in[26];
  const float* al2_pl = (const float*)d_in[27];
  const float* ar2_pl = (const float*)d_in[28];
  const float* b2_pl  = (const float*)d_in[29];
  const float* W_mlp  = (const float*)d_in[30];
  const float* b_mlp  = (const float*)d_in[31];
  const int* src_ll   = (const int*)d_in[32];
  const int* dst_ll   = (const int*)d_in[33];
  const int* src_lp   = (const int*)d_in[34];
  const int* dst_lp   = (const int*)d_in[35];
  const int* src_pl   = (const int*)d_in[36];
  const int* dst_pl   = (const int*)d_in[37];
  const int* gid_lig  = (const int*)d_in[38];
  const int* gid_pro  = (const int*)d_in[39];
  float* out = (float*)d_out;
  (void)in_sizes; (void)n_in; (void)out_size; (void)ws_size;

  // -------- workspace carving (~166 MB) --------
  size_t cur = 0;
  auto carve = [&](size_t bytes) -> char* {
    char* p = (char*)d_ws + cur;
    cur += (bytes + 511) & ~(size_t)511;
    return p;
  };
  const size_t NB = (size_t)40000 * 256 * sizeof(float);
  float* F    = (float*)carve(NB);   // fs / fd staging
  float* h_l  = (float*)carve(NB);
  float* h_p  = (float*)carve(NB);
  float* hX   = (float*)carve(NB);   // h_l2, then reused for h_p2
  float* el   = (float*)carve((size_t)40000 * 4 * sizeof(float));
  float* er   = (float*)carve((size_t)40000 * 4 * sizeof(float));
  float* ssum = (float*)carve((size_t)40000 * 4 * sizeof(float));
  float* gsum = (float*)carve((size_t)64 * 512 * sizeof(float));
  int* gcnt   = (int*)carve(128 * sizeof(int));

  const int B256 = 256;
  auto thrGrid  = [](long long n) { return (int)((n + 255) / 256); };
  auto waveGrid = [](int n) { return (n + 3) / 4; };  // 1 wave per item

  auto run_gemm = [&](const float* A, const float* Bw, float* C, int M, int K) {
    dim3 g((M + 63) / 64, 4);
    sgemm256<<<g, B256, 0, stream>>>(A, Bw, C, M, K);
  };
  auto run_dot = [&](const float* Fm, const float* av, float* o, int n) {
    dot_av_kernel<<<thrGrid((long long)n * 4), B256, 0, stream>>>(Fm, av, o, n);
  };
  auto run_edges = [&](const int* s, const int* d, int E, int nDst, float* outbuf) {
    hipMemsetAsync(ssum, 0, (size_t)nDst * 4 * sizeof(float), stream);
    edge_ssum_kernel<<<thrGrid((long long)E * 4), B256, 0, stream>>>(el, er, s, d, ssum, E);
    edge_scatter_kernel<<<waveGrid(E), B256, 0, stream>>>(F, el, er, ssum, s, d, outbuf, E);
  };

  // ================= LAYER 1 =================
  // ligand dst: ll + pl
  hipMemsetAsync(h_l, 0, NB, stream);
  // ll: fs = fd = x_lig @ W1_ll
  run_gemm(x_lig, W1_ll, F, NLIG, 74);
  run_dot(F, al1_ll, el, NLIG);
  run_dot(F, ar1_ll, er, NLIG);
  run_edges(src_ll, dst_ll, ELL, NLIG, h_l);
  // pl: fd = x_lig @ W1_pld -> er; fs = x_pro @ W1_pls -> el; aggregate
  run_gemm(x_lig, W1_pld, F, NLIG, 74);
  run_dot(F, ar1_pl, er, NLIG);
  run_gemm(x_pro, W1_pls, F, NPRO, 128);
  run_dot(F, al1_pl, el, NPRO);
  run_edges(src_pl, dst_pl, EPL, NLIG, h_l);
  bias_relu_kernel<<<2048, B256, 0, stream>>>(h_l, b1_ll, b1_pl, NLIG);
  // protein dst: lp
  hipMemsetAsync(h_p, 0, NB, stream);
  run_gemm(x_pro, W1_lpd, F, NPRO, 128);
  run_dot(F, ar1_lp, er, NPRO);
  run_gemm(x_lig, W1_lps, F, NLIG, 74);
  run_dot(F, al1_lp, el, NLIG);
  run_edges(src_lp, dst_lp, ELP, NPRO, h_p);
  bias_relu_kernel<<<2048, B256, 0, stream>>>(h_p, b1_lp, nullptr, NPRO);

  // ================= LAYER 2 =================
  // ligand dst: ll + pl  -> hX (= h_l2)
  hipMemsetAsync(hX, 0, NB, stream);
  run_gemm(h_l, W2_ll, F, NLIG, 256);
  run_dot(F, al2_ll, el, NLIG);
  run_dot(F, ar2_ll, er, NLIG);
  run_edges(src_ll, dst_ll, ELL, NLIG, hX);
  run_gemm(h_l, W2_pld, F, NLIG, 256);
  run_dot(F, ar2_pl, er, NLIG);
  run_gemm(h_p, W2_pls, F, NPRO, 256);
  run_dot(F, al2_pl, el, NPRO);
  run_edges(src_pl, dst_pl, EPL, NLIG, hX);
  bias_relu_kernel<<<2048, B256, 0, stream>>>(hX, b2_ll, b2_pl, NLIG);

  // readout of h_l2 NOW, so hX can be reused for h_p2
  hipMemsetAsync(gsum, 0, (size_t)64 * 512 * sizeof(float), stream);
  hipMemsetAsync(gcnt, 0, 128 * sizeof(int), stream);
  graph_sum_kernel<<<waveGrid(NLIG), B256, 0, stream>>>(hX, gid_lig, gsum, gcnt, NLIG, 0, 0);

  // protein dst: lp -> hX (= h_p2)
  run_gemm(h_p, W2_lpd, F, NPRO, 256);
  run_dot(F, ar2_lp, er, NPRO);
  run_gemm(h_l, W2_lps, F, NLIG, 256);
  run_dot(F, al2_lp, el, NLIG);
  hipMemsetAsync(hX, 0, NB, stream);
  run_edges(src_lp, dst_lp, ELP, NPRO, hX);
  bias_relu_kernel<<<2048, B256, 0, stream>>>(hX, b2_lp, nullptr, NPRO);
  graph_sum_kernel<<<waveGrid(NPRO), B256, 0, stream>>>(hX, gid_pro, gsum, gcnt, NPRO, 256, 64);

  // ================= MLP =================
  mlp_kernel<<<64, B256, 0, stream>>>(gsum, gcnt, W_mlp, b_mlp, out);
}

// Round 6
// 2342.085 us; speedup vs baseline: 4.4545x; 2.5803x over previous
//
#include <hip/hip_runtime.h>
#include <hip/hip_bf16.h>

#define NLIG 40000
#define NPRO 40000
#define NGRAPH 64
#define ELL 160000
#define ELP 240000
#define EPL 240000

// ---------------- tiled GEMM: C[M,256] = A[M,K] @ B[K,256] ----------------
__global__ __launch_bounds__(256) void sgemm256(
    const float* __restrict__ A, const float* __restrict__ B,
    float* __restrict__ C, int M, int K) {
  __shared__ float As[16][68];
  __shared__ float Bs[16][68];
  const int t = threadIdx.x;
  const int m0 = blockIdx.x * 64;
  const int n0 = blockIdx.y * 64;
  const int tx = t & 15, ty = t >> 4;
  float acc[4][4] = {};
  for (int k0 = 0; k0 < K; k0 += 16) {
    {
      const int r = t >> 2;
      const int c4 = (t & 3) * 4;
      const int row = m0 + r;
      const bool rok = row < M;
#pragma unroll
      for (int j = 0; j < 4; ++j) {
        const int kk = k0 + c4 + j;
        As[c4 + j][r] = (rok && kk < K) ? A[(size_t)row * K + kk] : 0.f;
      }
    }
    {
      const int rr = t >> 6;
      const int c = t & 63;
#pragma unroll
      for (int j = 0; j < 4; ++j) {
        const int kk = k0 + rr + j * 4;
        Bs[rr + j * 4][c] = (kk < K) ? B[(size_t)kk * 256 + n0 + c] : 0.f;
      }
    }
    __syncthreads();
#pragma unroll
    for (int kk = 0; kk < 16; ++kk) {
      const float4 av = *reinterpret_cast<const float4*>(&As[kk][ty * 4]);
      const float4 bv = *reinterpret_cast<const float4*>(&Bs[kk][tx * 4]);
      const float a[4] = {av.x, av.y, av.z, av.w};
      const float b[4] = {bv.x, bv.y, bv.z, bv.w};
#pragma unroll
      for (int i = 0; i < 4; ++i)
#pragma unroll
        for (int j = 0; j < 4; ++j) acc[i][j] = fmaf(a[i], b[j], acc[i][j]);
    }
    __syncthreads();
  }
#pragma unroll
  for (int i = 0; i < 4; ++i) {
    const int row = m0 + ty * 4 + i;
    if (row < M) {
      float4 o = {acc[i][0], acc[i][1], acc[i][2], acc[i][3]};
      *reinterpret_cast<float4*>(&C[(size_t)row * 256 + n0 + tx * 4]) = o;
    }
  }
}

// ---------- dot_av: out[n*4+h] = sum_{d<64} F[n,h*64+d] * avec[h*64+d] ----------
__global__ __launch_bounds__(256) void dot_av_kernel(
    const float* __restrict__ F, const float* __restrict__ avec,
    float* __restrict__ out, int n) {
  const int t = blockIdx.x * 256 + threadIdx.x;
  if (t >= n * 4) return;
  const int nn = t >> 2, h = t & 3;
  float s = 0.f;
  for (int d = 0; d < 64; ++d)
    s = fmaf(F[(size_t)nn * 256 + h * 64 + d], avec[h * 64 + d], s);
  out[t] = s;
}

// ------------- CSR build -------------
__global__ void count_kernel(const int* __restrict__ dst, int* __restrict__ cnt, int E) {
  for (int i = blockIdx.x * blockDim.x + threadIdx.x; i < E; i += gridDim.x * blockDim.x)
    atomicAdd(&cnt[dst[i]], 1);
}

__global__ __launch_bounds__(1024) void excl_scan_kernel(int* __restrict__ data, int n) {
  __shared__ int sm[1024];
  __shared__ int carry;
  const int tid = threadIdx.x;
  if (tid == 0) carry = 0;
  __syncthreads();
  for (int base = 0; base < n; base += 1024) {
    const int i = base + tid;
    const int v = (i < n) ? data[i] : 0;
    sm[tid] = v;
    __syncthreads();
    for (int ofs = 1; ofs < 1024; ofs <<= 1) {
      const int tmp = (tid >= ofs) ? sm[tid - ofs] : 0;
      __syncthreads();
      sm[tid] += tmp;
      __syncthreads();
    }
    const int incl = sm[tid];
    const int blocktotal = sm[1023];
    const int c = carry;
    __syncthreads();
    if (i < n) data[i] = c + incl - v;   // exclusive
    if (tid == 0) carry = c + blocktotal;
    __syncthreads();
  }
  if (tid == 0) data[n] = carry;
}

__global__ void fill_kernel(const int* __restrict__ src, const int* __restrict__ dst,
                            const int* __restrict__ off, int* __restrict__ cursor,
                            int* __restrict__ csrsrc, int E) {
  for (int i = blockIdx.x * blockDim.x + threadIdx.x; i < E; i += gridDim.x * blockDim.x) {
    const int d = dst[i];
    const int p = atomicAdd(&cursor[d], 1);
    csrsrc[off[d] + p] = src[i];
  }
}

// ------------- GAT aggregation: one wave per dst node, fused softmax -------------
__global__ __launch_bounds__(256) void gat_aggregate(
    const float* __restrict__ F, const float* __restrict__ el,
    const float* __restrict__ er, const int* __restrict__ off,
    const int* __restrict__ csrsrc, float* __restrict__ out,
    int n_dst, int add_flag) {
  const int lane = threadIdx.x & 63;
  const int myh = lane >> 4;
  const int gw = (blockIdx.x * blockDim.x + threadIdx.x) >> 6;
  if (gw >= n_dst) return;
  const int n = gw;
  const int s0 = off[n], s1 = off[n + 1];
  const float ern = er[n * 4 + myh];
  float4 acc = {0.f, 0.f, 0.f, 0.f};
  float ssum = 0.f;
  for (int p = s0; p < s1; ++p) {
    const int src = csrsrc[p];
    float e = el[src * 4 + myh] + ern;
    e = e > 0.f ? e : 0.2f * e;
    const float ex = expf(e);
    ssum += ex;
    const float4 f = *reinterpret_cast<const float4*>(&F[(size_t)src * 256 + lane * 4]);
    acc.x = fmaf(ex, f.x, acc.x);
    acc.y = fmaf(ex, f.y, acc.y);
    acc.z = fmaf(ex, f.z, acc.z);
    acc.w = fmaf(ex, f.w, acc.w);
  }
  const float inv = ssum > 0.f ? 1.f / ssum : 0.f;
  float4 res = {acc.x * inv, acc.y * inv, acc.z * inv, acc.w * inv};
  float4* po = reinterpret_cast<float4*>(&out[(size_t)n * 256 + lane * 4]);
  if (add_flag) {
    const float4 prev = *po;
    res.x += prev.x; res.y += prev.y; res.z += prev.z; res.w += prev.w;
  }
  *po = res;
}

// ---------- bias (+optional second bias) + relu, in-place ----------
__global__ __launch_bounds__(256) void bias_relu_kernel(
    float* __restrict__ h, const float* __restrict__ b1,
    const float* __restrict__ b2, int n) {
  const int tot = n * 64;
  for (int i = blockIdx.x * blockDim.x + threadIdx.x; i < tot; i += gridDim.x * blockDim.x) {
    const int c4 = (i & 63) * 4;
    float4 v = reinterpret_cast<float4*>(h)[i];
    float4 bb = *reinterpret_cast<const float4*>(&b1[c4]);
    if (b2) {
      const float4 b2v = *reinterpret_cast<const float4*>(&b2[c4]);
      bb.x += b2v.x; bb.y += b2v.y; bb.z += b2v.z; bb.w += b2v.w;
    }
    v.x = fmaxf(v.x + bb.x, 0.f);
    v.y = fmaxf(v.y + bb.y, 0.f);
    v.z = fmaxf(v.z + bb.z, 0.f);
    v.w = fmaxf(v.w + bb.w, 0.f);
    reinterpret_cast<float4*>(h)[i] = v;
  }
}

// ---------- graph readout: atomic sum per graph ----------
__global__ __launch_bounds__(256) void graph_sum_kernel(
    const float* __restrict__ h, const int* __restrict__ gid,
    float* __restrict__ gsum, int* __restrict__ gcnt,
    int n, int colofs, int cntofs) {
  const int lane = threadIdx.x & 63;
  const int gw = (blockIdx.x * blockDim.x + threadIdx.x) >> 6;
  if (gw >= n) return;
  const int g = gid[gw];
  const float4 v = *reinterpret_cast<const float4*>(&h[(size_t)gw * 256 + lane * 4]);
  float* base = gsum + (size_t)g * 512 + colofs + lane * 4;
  atomicAdd(base + 0, v.x);
  atomicAdd(base + 1, v.y);
  atomicAdd(base + 2, v.z);
  atomicAdd(base + 3, v.w);
  if (lane == 0) atomicAdd(&gcnt[cntofs + g], 1);
}

// ---------- final MLP ----------
__global__ __launch_bounds__(256) void mlp_kernel(
    const float* __restrict__ gsum, const int* __restrict__ gcnt,
    const float* __restrict__ Wm, const float* __restrict__ bm,
    float* __restrict__ out) {
  __shared__ float g[512];
  const int b = blockIdx.x, t = threadIdx.x;
  const float cl = fmaxf((float)gcnt[b], 1.f);
  const float cp = fmaxf((float)gcnt[64 + b], 1.f);
  for (int k = t; k < 512; k += 256)
    g[k] = gsum[(size_t)b * 512 + k] * (k < 256 ? 1.f / cl : 1.f / cp);
  __syncthreads();
  float acc = bm[t];
  for (int k = 0; k < 512; ++k) acc = fmaf(g[k], Wm[(size_t)k * 256 + t], acc);
  out[b * 256 + t] = fmaxf(acc, 0.f);
}

// =====================================================================
extern "C" void kernel_launch(void* const* d_in, const int* in_sizes, int n_in,
                              void* d_out, int out_size, void* d_ws, size_t ws_size,
                              hipStream_t stream) {
  const float* x_lig  = (const float*)d_in[0];
  const float* x_pro  = (const float*)d_in[1];
  const float* W1_ll  = (const float*)d_in[2];
  const float* al1_ll = (const float*)d_in[3];
  const float* ar1_ll = (const float*)d_in[4];
  const float* b1_ll  = (const float*)d_in[5];
  const float* W1_lps = (const float*)d_in[6];
  const float* W1_lpd = (const float*)d_in[7];
  const float* al1_lp = (const float*)d_in[8];
  const float* ar1_lp = (const float*)d_in[9];
  const float* b1_lp  = (const float*)d_in[10];
  const float* W1_pls = (const float*)d_in[11];
  const float* W1_pld = (const float*)d_in[12];
  const float* al1_pl = (const float*)d_in[13];
  const float* ar1_pl = (const float*)d_in[14];
  const float* b1_pl  = (const float*)d_in[15];
  const float* W2_ll  = (const float*)d_in[16];
  const float* al2_ll = (const float*)d_in[17];
  const float* ar2_ll = (const float*)d_in[18];
  const float* b2_ll  = (const float*)d_in[19];
  const float* W2_lps = (const float*)d_in[20];
  const float* W2_lpd = (const float*)d_in[21];
  const float* al2_lp = (const float*)d_in[22];
  const float* ar2_lp = (const float*)d_in[23];
  const float* b2_lp  = (const float*)d_in[24];
  const float* W2_pls = (const float*)d_in[25];
  const float* W2_pld = (const float*)d_in[26];
  const float* al2_pl = (const float*)d_in[27];
  const float* ar2_pl = (const float*)d_in[28];
  const float* b2_pl  = (const float*)d_in[29];
  const float* W_mlp  = (const float*)d_in[30];
  const float* b_mlp  = (const float*)d_in[31];
  const int* src_ll   = (const int*)d_in[32];
  const int* dst_ll   = (const int*)d_in[33];
  const int* src_lp   = (const int*)d_in[34];
  const int* dst_lp   = (const int*)d_in[35];
  const int* src_pl   = (const int*)d_in[36];
  const int* dst_pl   = (const int*)d_in[37];
  const int* gid_lig  = (const int*)d_in[38];
  const int* gid_pro  = (const int*)d_in[39];
  float* out = (float*)d_out;
  (void)in_sizes; (void)n_in; (void)out_size; (void)ws_size;

  // -------- workspace carving (~170 MB) --------
  size_t cur = 0;
  auto carve = [&](size_t bytes) -> char* {
    char* p = (char*)d_ws + cur;
    cur += (bytes + 511) & ~(size_t)511;
    return p;
  };
  const size_t NB = (size_t)40000 * 256 * sizeof(float);
  float* F    = (float*)carve(NB);   // fs / fd staging
  float* h_l  = (float*)carve(NB);
  float* h_p  = (float*)carve(NB);
  float* hX   = (float*)carve(NB);   // h_l2, then reused for h_p2
  float* el   = (float*)carve((size_t)40000 * 4 * sizeof(float));
  float* er   = (float*)carve((size_t)40000 * 4 * sizeof(float));
  float* gsum = (float*)carve((size_t)64 * 512 * sizeof(float));
  int* gcnt   = (int*)carve(128 * sizeof(int));
  int* off_ll = (int*)carve((NLIG + 1) * sizeof(int));
  int* off_lp = (int*)carve((NPRO + 1) * sizeof(int));
  int* off_pl = (int*)carve((NLIG + 1) * sizeof(int));
  int* cursor = (int*)carve((NLIG + 1) * sizeof(int));
  int* csr_ll = (int*)carve((size_t)ELL * sizeof(int));
  int* csr_lp = (int*)carve((size_t)ELP * sizeof(int));
  int* csr_pl = (int*)carve((size_t)EPL * sizeof(int));

  const int B256 = 256;
  auto thrGrid  = [](long long n) { return (int)((n + 255) / 256); };
  auto waveGrid = [](int n) { return (n + 3) / 4; };  // 1 wave per item

  auto run_gemm = [&](const float* A, const float* Bw, float* C, int M, int K) {
    dim3 g((M + 63) / 64, 4);
    sgemm256<<<g, B256, 0, stream>>>(A, Bw, C, M, K);
  };
  auto run_dot = [&](const float* Fm, const float* av, float* o, int n) {
    dot_av_kernel<<<thrGrid((long long)n * 4), B256, 0, stream>>>(Fm, av, o, n);
  };
  auto run_agg = [&](const int* off, const int* csr, int nDst, float* outbuf, int addf) {
    gat_aggregate<<<waveGrid(nDst), B256, 0, stream>>>(F, el, er, off, csr, outbuf, nDst, addf);
  };

  // -------- CSR builds (shared by both layers) --------
  struct Rel { const int* src; const int* dst; int* off; int* csr; int E; int Nd; };
  Rel rels[3] = {
    {src_ll, dst_ll, off_ll, csr_ll, ELL, NLIG},
    {src_lp, dst_lp, off_lp, csr_lp, ELP, NPRO},
    {src_pl, dst_pl, off_pl, csr_pl, EPL, NLIG},
  };
  for (int r = 0; r < 3; ++r) {
    hipMemsetAsync(rels[r].off, 0, (rels[r].Nd + 1) * sizeof(int), stream);
    count_kernel<<<thrGrid(rels[r].E), B256, 0, stream>>>(rels[r].dst, rels[r].off, rels[r].E);
    excl_scan_kernel<<<1, 1024, 0, stream>>>(rels[r].off, rels[r].Nd);
    hipMemsetAsync(cursor, 0, (rels[r].Nd + 1) * sizeof(int), stream);
    fill_kernel<<<thrGrid(rels[r].E), B256, 0, stream>>>(
        rels[r].src, rels[r].dst, rels[r].off, cursor, rels[r].csr, rels[r].E);
  }

  // ================= LAYER 1 =================
  // ligand dst: ll then pl (add)
  run_gemm(x_lig, W1_ll, F, NLIG, 74);
  run_dot(F, al1_ll, el, NLIG);
  run_dot(F, ar1_ll, er, NLIG);
  run_agg(off_ll, csr_ll, NLIG, h_l, 0);
  // pl: fd = x_lig @ W1_pld -> er; fs = x_pro @ W1_pls -> el
  run_gemm(x_lig, W1_pld, F, NLIG, 74);
  run_dot(F, ar1_pl, er, NLIG);
  run_gemm(x_pro, W1_pls, F, NPRO, 128);
  run_dot(F, al1_pl, el, NPRO);
  run_agg(off_pl, csr_pl, NLIG, h_l, 1);
  bias_relu_kernel<<<2048, B256, 0, stream>>>(h_l, b1_ll, b1_pl, NLIG);
  // protein dst: lp
  run_gemm(x_pro, W1_lpd, F, NPRO, 128);
  run_dot(F, ar1_lp, er, NPRO);
  run_gemm(x_lig, W1_lps, F, NLIG, 74);
  run_dot(F, al1_lp, el, NLIG);
  run_agg(off_lp, csr_lp, NPRO, h_p, 0);
  bias_relu_kernel<<<2048, B256, 0, stream>>>(h_p, b1_lp, nullptr, NPRO);

  // ================= LAYER 2 =================
  // ligand dst: ll + pl -> hX (= h_l2)
  run_gemm(h_l, W2_ll, F, NLIG, 256);
  run_dot(F, al2_ll, el, NLIG);
  run_dot(F, ar2_ll, er, NLIG);
  run_agg(off_ll, csr_ll, NLIG, hX, 0);
  run_gemm(h_l, W2_pld, F, NLIG, 256);
  run_dot(F, ar2_pl, er, NLIG);
  run_gemm(h_p, W2_pls, F, NPRO, 256);
  run_dot(F, al2_pl, el, NPRO);
  run_agg(off_pl, csr_pl, NLIG, hX, 1);
  bias_relu_kernel<<<2048, B256, 0, stream>>>(hX, b2_ll, b2_pl, NLIG);

  // readout of h_l2 NOW, so hX can be reused for h_p2
  hipMemsetAsync(gsum, 0, (size_t)64 * 512 * sizeof(float), stream);
  hipMemsetAsync(gcnt, 0, 128 * sizeof(int), stream);
  graph_sum_kernel<<<waveGrid(NLIG), B256, 0, stream>>>(hX, gid_lig, gsum, gcnt, NLIG, 0, 0);

  // protein dst: lp -> hX (= h_p2)
  run_gemm(h_p, W2_lpd, F, NPRO, 256);
  run_dot(F, ar2_lp, er, NPRO);
  run_gemm(h_l, W2_lps, F, NLIG, 256);
  run_dot(F, al2_lp, el, NLIG);
  run_agg(off_lp, csr_lp, NPRO, hX, 0);
  bias_relu_kernel<<<2048, B256, 0, stream>>>(hX, b2_lp, nullptr, NPRO);
  graph_sum_kernel<<<waveGrid(NPRO), B256, 0, stream>>>(hX, gid_pro, gsum, gcnt, NPRO, 256, 64);

  // ================= MLP =================
  mlp_kernel<<<64, B256, 0, stream>>>(gsum, gcnt, W_mlp, b_mlp, out);
}

// Round 7
// 1812.033 us; speedup vs baseline: 5.7575x; 1.2925x over previous
//
#include <hip/hip_runtime.h>
#include <hip/hip_bf16.h>

#define NLIG 40000
#define NPRO 40000
#define NGRAPH 64
#define ELL 160000
#define ELP 240000
#define EPL 240000

#define GS_SLICES 4            // 4 slices x 64 cols = 256 cols
#define GS_BLOCKS_PER_SLICE 32

// ---------------- tiled GEMM: C[M,256] = A[M,K] @ B[K,256] ----------------
__global__ __launch_bounds__(256) void sgemm256(
    const float* __restrict__ A, const float* __restrict__ B,
    float* __restrict__ C, int M, int K) {
  __shared__ float As[16][68];
  __shared__ float Bs[16][68];
  const int t = threadIdx.x;
  const int m0 = blockIdx.x * 64;
  const int n0 = blockIdx.y * 64;
  const int tx = t & 15, ty = t >> 4;
  float acc[4][4] = {};
  for (int k0 = 0; k0 < K; k0 += 16) {
    {
      const int r = t >> 2;
      const int c4 = (t & 3) * 4;
      const int row = m0 + r;
      const bool rok = row < M;
#pragma unroll
      for (int j = 0; j < 4; ++j) {
        const int kk = k0 + c4 + j;
        As[c4 + j][r] = (rok && kk < K) ? A[(size_t)row * K + kk] : 0.f;
      }
    }
    {
      const int rr = t >> 6;
      const int c = t & 63;
#pragma unroll
      for (int j = 0; j < 4; ++j) {
        const int kk = k0 + rr + j * 4;
        Bs[rr + j * 4][c] = (kk < K) ? B[(size_t)kk * 256 + n0 + c] : 0.f;
      }
    }
    __syncthreads();
#pragma unroll
    for (int kk = 0; kk < 16; ++kk) {
      const float4 av = *reinterpret_cast<const float4*>(&As[kk][ty * 4]);
      const float4 bv = *reinterpret_cast<const float4*>(&Bs[kk][tx * 4]);
      const float a[4] = {av.x, av.y, av.z, av.w};
      const float b[4] = {bv.x, bv.y, bv.z, bv.w};
#pragma unroll
      for (int i = 0; i < 4; ++i)
#pragma unroll
        for (int j = 0; j < 4; ++j) acc[i][j] = fmaf(a[i], b[j], acc[i][j]);
    }
    __syncthreads();
  }
#pragma unroll
  for (int i = 0; i < 4; ++i) {
    const int row = m0 + ty * 4 + i;
    if (row < M) {
      float4 o = {acc[i][0], acc[i][1], acc[i][2], acc[i][3]};
      *reinterpret_cast<float4*>(&C[(size_t)row * 256 + n0 + tx * 4]) = o;
    }
  }
}

// ---------- dot_av: out[n*4+h] = sum_{d<64} F[n,h*64+d] * avec[h*64+d] ----------
__global__ __launch_bounds__(256) void dot_av_kernel(
    const float* __restrict__ F, const float* __restrict__ avec,
    float* __restrict__ out, int n) {
  const int t = blockIdx.x * 256 + threadIdx.x;
  if (t >= n * 4) return;
  const int nn = t >> 2, h = t & 3;
  float s = 0.f;
  for (int d = 0; d < 64; ++d)
    s = fmaf(F[(size_t)nn * 256 + h * 64 + d], avec[h * 64 + d], s);
  out[t] = s;
}

// ------------- CSR build -------------
__global__ void count_kernel(const int* __restrict__ dst, int* __restrict__ cnt, int E) {
  for (int i = blockIdx.x * blockDim.x + threadIdx.x; i < E; i += gridDim.x * blockDim.x)
    atomicAdd(&cnt[dst[i]], 1);
}

__global__ __launch_bounds__(1024) void excl_scan_kernel(int* __restrict__ data, int n) {
  __shared__ int sm[1024];
  __shared__ int carry;
  const int tid = threadIdx.x;
  if (tid == 0) carry = 0;
  __syncthreads();
  for (int base = 0; base < n; base += 1024) {
    const int i = base + tid;
    const int v = (i < n) ? data[i] : 0;
    sm[tid] = v;
    __syncthreads();
    for (int ofs = 1; ofs < 1024; ofs <<= 1) {
      const int tmp = (tid >= ofs) ? sm[tid - ofs] : 0;
      __syncthreads();
      sm[tid] += tmp;
      __syncthreads();
    }
    const int incl = sm[tid];
    const int blocktotal = sm[1023];
    const int c = carry;
    __syncthreads();
    if (i < n) data[i] = c + incl - v;   // exclusive
    if (tid == 0) carry = c + blocktotal;
    __syncthreads();
  }
  if (tid == 0) data[n] = carry;
}

__global__ void fill_kernel(const int* __restrict__ src, const int* __restrict__ dst,
                            const int* __restrict__ off, int* __restrict__ cursor,
                            int* __restrict__ csrsrc, int E) {
  for (int i = blockIdx.x * blockDim.x + threadIdx.x; i < E; i += gridDim.x * blockDim.x) {
    const int d = dst[i];
    const int p = atomicAdd(&cursor[d], 1);
    csrsrc[off[d] + p] = src[i];
  }
}

// ------------- GAT aggregation: one wave per dst node, fused softmax -------------
__global__ __launch_bounds__(256) void gat_aggregate(
    const float* __restrict__ F, const float* __restrict__ el,
    const float* __restrict__ er, const int* __restrict__ off,
    const int* __restrict__ csrsrc, float* __restrict__ out,
    int n_dst, int add_flag) {
  const int lane = threadIdx.x & 63;
  const int myh = lane >> 4;
  const int gw = (blockIdx.x * blockDim.x + threadIdx.x) >> 6;
  if (gw >= n_dst) return;
  const int n = gw;
  const int s0 = off[n], s1 = off[n + 1];
  const float ern = er[n * 4 + myh];
  float4 acc = {0.f, 0.f, 0.f, 0.f};
  float ssum = 0.f;
  for (int p = s0; p < s1; ++p) {
    const int src = csrsrc[p];
    float e = el[src * 4 + myh] + ern;
    e = e > 0.f ? e : 0.2f * e;
    const float ex = expf(e);
    ssum += ex;
    const float4 f = *reinterpret_cast<const float4*>(&F[(size_t)src * 256 + lane * 4]);
    acc.x = fmaf(ex, f.x, acc.x);
    acc.y = fmaf(ex, f.y, acc.y);
    acc.z = fmaf(ex, f.z, acc.z);
    acc.w = fmaf(ex, f.w, acc.w);
  }
  const float inv = ssum > 0.f ? 1.f / ssum : 0.f;
  float4 res = {acc.x * inv, acc.y * inv, acc.z * inv, acc.w * inv};
  float4* po = reinterpret_cast<float4*>(&out[(size_t)n * 256 + lane * 4]);
  if (add_flag) {
    const float4 prev = *po;
    res.x += prev.x; res.y += prev.y; res.z += prev.z; res.w += prev.w;
  }
  *po = res;
}

// ---------- bias (+optional second bias) + relu, in-place ----------
__global__ __launch_bounds__(256) void bias_relu_kernel(
    float* __restrict__ h, const float* __restrict__ b1,
    const float* __restrict__ b2, int n) {
  const int tot = n * 64;
  for (int i = blockIdx.x * blockDim.x + threadIdx.x; i < tot; i += gridDim.x * blockDim.x) {
    const int c4 = (i & 63) * 4;
    float4 v = reinterpret_cast<float4*>(h)[i];
    float4 bb = *reinterpret_cast<const float4*>(&b1[c4]);
    if (b2) {
      const float4 b2v = *reinterpret_cast<const float4*>(&b2[c4]);
      bb.x += b2v.x; bb.y += b2v.y; bb.z += b2v.z; bb.w += b2v.w;
    }
    v.x = fmaxf(v.x + bb.x, 0.f);
    v.y = fmaxf(v.y + bb.y, 0.f);
    v.z = fmaxf(v.z + bb.z, 0.f);
    v.w = fmaxf(v.w + bb.w, 0.f);
    reinterpret_cast<float4*>(h)[i] = v;
  }
}

// ---------- graph readout v2: LDS two-level reduction ----------
// grid = GS_SLICES * GS_BLOCKS_PER_SLICE blocks of 256.
// Each block: column slice of 64, node stripe; accumulate [64 graphs][64 cols]
// in LDS, then one global atomicAdd per entry.
__global__ __launch_bounds__(256) void graph_sum_v2(
    const float* __restrict__ h, const int* __restrict__ gid,
    float* __restrict__ gsum, int n, int colofs) {
  __shared__ float sm[NGRAPH][64];
  const int slice = blockIdx.x & (GS_SLICES - 1);
  const int bs    = blockIdx.x >> 2;        // block index within slice
  const int c  = threadIdx.x & 63;
  const int nl = threadIdx.x >> 6;          // 0..3 node sub-lane
  for (int i = threadIdx.x; i < NGRAPH * 64; i += 256) (&sm[0][0])[i] = 0.f;
  __syncthreads();
  for (int node = bs * 4 + nl; node < n; node += GS_BLOCKS_PER_SLICE * 4) {
    const int g = gid[node];
    const float v = h[(size_t)node * 256 + slice * 64 + c];
    atomicAdd(&sm[g][c], v);
  }
  __syncthreads();
  for (int i = threadIdx.x; i < NGRAPH * 64; i += 256) {
    const int g = i >> 6, cc = i & 63;
    const float v = sm[g][cc];
    if (v != 0.f) atomicAdd(&gsum[(size_t)g * 512 + colofs + slice * 64 + cc], v);
  }
}

// ---------- graph node-count: LDS histogram ----------
__global__ __launch_bounds__(256) void graph_count_kernel(
    const int* __restrict__ gid, int* __restrict__ gcnt, int n, int cntofs) {
  __shared__ int c[NGRAPH];
  if (threadIdx.x < NGRAPH) c[threadIdx.x] = 0;
  __syncthreads();
  for (int i = blockIdx.x * blockDim.x + threadIdx.x; i < n; i += gridDim.x * blockDim.x)
    atomicAdd(&c[gid[i]], 1);
  __syncthreads();
  if (threadIdx.x < NGRAPH && c[threadIdx.x])
    atomicAdd(&gcnt[cntofs + threadIdx.x], c[threadIdx.x]);
}

// ---------- final MLP ----------
__global__ __launch_bounds__(256) void mlp_kernel(
    const float* __restrict__ gsum, const int* __restrict__ gcnt,
    const float* __restrict__ Wm, const float* __restrict__ bm,
    float* __restrict__ out) {
  __shared__ float g[512];
  const int b = blockIdx.x, t = threadIdx.x;
  const float cl = fmaxf((float)gcnt[b], 1.f);
  const float cp = fmaxf((float)gcnt[64 + b], 1.f);
  for (int k = t; k < 512; k += 256)
    g[k] = gsum[(size_t)b * 512 + k] * (k < 256 ? 1.f / cl : 1.f / cp);
  __syncthreads();
  float acc = bm[t];
  for (int k = 0; k < 512; ++k) acc = fmaf(g[k], Wm[(size_t)k * 256 + t], acc);
  out[b * 256 + t] = fmaxf(acc, 0.f);
}

// =====================================================================
extern "C" void kernel_launch(void* const* d_in, const int* in_sizes, int n_in,
                              void* d_out, int out_size, void* d_ws, size_t ws_size,
                              hipStream_t stream) {
  const float* x_lig  = (const float*)d_in[0];
  const float* x_pro  = (const float*)d_in[1];
  const float* W1_ll  = (const float*)d_in[2];
  const float* al1_ll = (const float*)d_in[3];
  const float* ar1_ll = (const float*)d_in[4];
  const float* b1_ll  = (const float*)d_in[5];
  const float* W1_lps = (const float*)d_in[6];
  const float* W1_lpd = (const float*)d_in[7];
  const float* al1_lp = (const float*)d_in[8];
  const float* ar1_lp = (const float*)d_in[9];
  const float* b1_lp  = (const float*)d_in[10];
  const float* W1_pls = (const float*)d_in[11];
  const float* W1_pld = (const float*)d_in[12];
  const float* al1_pl = (const float*)d_in[13];
  const float* ar1_pl = (const float*)d_in[14];
  const float* b1_pl  = (const float*)d_in[15];
  const float* W2_ll  = (const float*)d_in[16];
  const float* al2_ll = (const float*)d_in[17];
  const float* ar2_ll = (const float*)d_in[18];
  const float* b2_ll  = (const float*)d_in[19];
  const float* W2_lps = (const float*)d_in[20];
  const float* W2_lpd = (const float*)d_in[21];
  const float* al2_lp = (const float*)d_in[22];
  const float* ar2_lp = (const float*)d_in[23];
  const float* b2_lp  = (const float*)d_in[24];
  const float* W2_pls = (const float*)d_in[25];
  const float* W2_pld = (const float*)d_in[26];
  const float* al2_pl = (const float*)d_in[27];
  const float* ar2_pl = (const float*)d_in[28];
  const float* b2_pl  = (const float*)d_in[29];
  const float* W_mlp  = (const float*)d_in[30];
  const float* b_mlp  = (const float*)d_in[31];
  const int* src_ll   = (const int*)d_in[32];
  const int* dst_ll   = (const int*)d_in[33];
  const int* src_lp   = (const int*)d_in[34];
  const int* dst_lp   = (const int*)d_in[35];
  const int* src_pl   = (const int*)d_in[36];
  const int* dst_pl   = (const int*)d_in[37];
  const int* gid_lig  = (const int*)d_in[38];
  const int* gid_pro  = (const int*)d_in[39];
  float* out = (float*)d_out;
  (void)in_sizes; (void)n_in; (void)out_size; (void)ws_size;

  // -------- workspace carving (~170 MB) --------
  size_t cur = 0;
  auto carve = [&](size_t bytes) -> char* {
    char* p = (char*)d_ws + cur;
    cur += (bytes + 511) & ~(size_t)511;
    return p;
  };
  const size_t NB = (size_t)40000 * 256 * sizeof(float);
  float* F    = (float*)carve(NB);   // fs / fd staging
  float* h_l  = (float*)carve(NB);
  float* h_p  = (float*)carve(NB);
  float* hX   = (float*)carve(NB);   // h_l2, then reused for h_p2
  float* el   = (float*)carve((size_t)40000 * 4 * sizeof(float));
  float* er   = (float*)carve((size_t)40000 * 4 * sizeof(float));
  float* gsum = (float*)carve((size_t)64 * 512 * sizeof(float));
  int* gcnt   = (int*)carve(128 * sizeof(int));
  int* off_ll = (int*)carve((NLIG + 1) * sizeof(int));
  int* off_lp = (int*)carve((NPRO + 1) * sizeof(int));
  int* off_pl = (int*)carve((NLIG + 1) * sizeof(int));
  int* cursor = (int*)carve((NLIG + 1) * sizeof(int));
  int* csr_ll = (int*)carve((size_t)ELL * sizeof(int));
  int* csr_lp = (int*)carve((size_t)ELP * sizeof(int));
  int* csr_pl = (int*)carve((size_t)EPL * sizeof(int));

  const int B256 = 256;
  auto thrGrid  = [](long long n) { return (int)((n + 255) / 256); };
  auto waveGrid = [](int n) { return (n + 3) / 4; };  // 1 wave per item

  auto run_gemm = [&](const float* A, const float* Bw, float* C, int M, int K) {
    dim3 g((M + 63) / 64, 4);
    sgemm256<<<g, B256, 0, stream>>>(A, Bw, C, M, K);
  };
  auto run_dot = [&](const float* Fm, const float* av, float* o, int n) {
    dot_av_kernel<<<thrGrid((long long)n * 4), B256, 0, stream>>>(Fm, av, o, n);
  };
  auto run_agg = [&](const int* off, const int* csr, int nDst, float* outbuf, int addf) {
    gat_aggregate<<<waveGrid(nDst), B256, 0, stream>>>(F, el, er, off, csr, outbuf, nDst, addf);
  };

  // -------- CSR builds (shared by both layers) --------
  struct Rel { const int* src; const int* dst; int* off; int* csr; int E; int Nd; };
  Rel rels[3] = {
    {src_ll, dst_ll, off_ll, csr_ll, ELL, NLIG},
    {src_lp, dst_lp, off_lp, csr_lp, ELP, NPRO},
    {src_pl, dst_pl, off_pl, csr_pl, EPL, NLIG},
  };
  for (int r = 0; r < 3; ++r) {
    hipMemsetAsync(rels[r].off, 0, (rels[r].Nd + 1) * sizeof(int), stream);
    count_kernel<<<thrGrid(rels[r].E), B256, 0, stream>>>(rels[r].dst, rels[r].off, rels[r].E);
    excl_scan_kernel<<<1, 1024, 0, stream>>>(rels[r].off, rels[r].Nd);
    hipMemsetAsync(cursor, 0, (rels[r].Nd + 1) * sizeof(int), stream);
    fill_kernel<<<thrGrid(rels[r].E), B256, 0, stream>>>(
        rels[r].src, rels[r].dst, rels[r].off, cursor, rels[r].csr, rels[r].E);
  }

  // ================= LAYER 1 =================
  // ligand dst: ll then pl (add)
  run_gemm(x_lig, W1_ll, F, NLIG, 74);
  run_dot(F, al1_ll, el, NLIG);
  run_dot(F, ar1_ll, er, NLIG);
  run_agg(off_ll, csr_ll, NLIG, h_l, 0);
  // pl: fd = x_lig @ W1_pld -> er; fs = x_pro @ W1_pls -> el
  run_gemm(x_lig, W1_pld, F, NLIG, 74);
  run_dot(F, ar1_pl, er, NLIG);
  run_gemm(x_pro, W1_pls, F, NPRO, 128);
  run_dot(F, al1_pl, el, NPRO);
  run_agg(off_pl, csr_pl, NLIG, h_l, 1);
  bias_relu_kernel<<<2048, B256, 0, stream>>>(h_l, b1_ll, b1_pl, NLIG);
  // protein dst: lp
  run_gemm(x_pro, W1_lpd, F, NPRO, 128);
  run_dot(F, ar1_lp, er, NPRO);
  run_gemm(x_lig, W1_lps, F, NLIG, 74);
  run_dot(F, al1_lp, el, NLIG);
  run_agg(off_lp, csr_lp, NPRO, h_p, 0);
  bias_relu_kernel<<<2048, B256, 0, stream>>>(h_p, b1_lp, nullptr, NPRO);

  // ================= LAYER 2 =================
  // ligand dst: ll + pl -> hX (= h_l2)
  run_gemm(h_l, W2_ll, F, NLIG, 256);
  run_dot(F, al2_ll, el, NLIG);
  run_dot(F, ar2_ll, er, NLIG);
  run_agg(off_ll, csr_ll, NLIG, hX, 0);
  run_gemm(h_l, W2_pld, F, NLIG, 256);
  run_dot(F, ar2_pl, er, NLIG);
  run_gemm(h_p, W2_pls, F, NPRO, 256);
  run_dot(F, al2_pl, el, NPRO);
  run_agg(off_pl, csr_pl, NLIG, hX, 1);
  bias_relu_kernel<<<2048, B256, 0, stream>>>(hX, b2_ll, b2_pl, NLIG);

  // readout of h_l2 NOW, so hX can be reused for h_p2
  hipMemsetAsync(gsum, 0, (size_t)64 * 512 * sizeof(float), stream);
  hipMemsetAsync(gcnt, 0, 128 * sizeof(int), stream);
  graph_sum_v2<<<GS_SLICES * GS_BLOCKS_PER_SLICE, B256, 0, stream>>>(hX, gid_lig, gsum, NLIG, 0);
  graph_count_kernel<<<64, B256, 0, stream>>>(gid_lig, gcnt, NLIG, 0);

  // protein dst: lp -> hX (= h_p2)
  run_gemm(h_p, W2_lpd, F, NPRO, 256);
  run_dot(F, ar2_lp, er, NPRO);
  run_gemm(h_l, W2_lps, F, NLIG, 256);
  run_dot(F, al2_lp, el, NLIG);
  run_agg(off_lp, csr_lp, NPRO, hX, 0);
  bias_relu_kernel<<<2048, B256, 0, stream>>>(hX, b2_lp, nullptr, NPRO);
  graph_sum_v2<<<GS_SLICES * GS_BLOCKS_PER_SLICE, B256, 0, stream>>>(hX, gid_pro, gsum, NPRO, 256);
  graph_count_kernel<<<64, B256, 0, stream>>>(gid_pro, gcnt, NPRO, 64);

  // ================= MLP =================
  mlp_kernel<<<64, B256, 0, stream>>>(gsum, gcnt, W_mlp, b_mlp, out);
}

// Round 8
// 1430.216 us; speedup vs baseline: 7.2946x; 1.2670x over previous
//
#include <hip/hip_runtime.h>
#include <hip/hip_bf16.h>

#define NLIG 40000
#define NPRO 40000
#define NGRAPH 64
#define ELL 160000
#define ELP 240000
#define EPL 240000

#define GS_SLICES 4
#define GS_BLOCKS_PER_SLICE 32

// ---------------- tiled GEMM + fused head-dot epilogue ----------------
// C[M,256] = A[M,K] @ B[K,256].  BM=128, BN=64, 256 threads, grid (ceil(M/128), 4).
// Since BN==D==64, column-block n0 covers exactly head h=n0/64, so the epilogue
// can compute el[m*4+h] = sum_d C[m][h*64+d]*al[h*64+d] (and er with ar) via an
// in-wave 16-lane shuffle reduction. al/ar may be null.
__global__ __launch_bounds__(256) void sgemm_fused(
    const float* __restrict__ A, const float* __restrict__ B,
    float* __restrict__ C, int M, int K,
    const float* __restrict__ al, float* __restrict__ el,
    const float* __restrict__ ar, float* __restrict__ er) {
  __shared__ float As[16][132];
  __shared__ float Bs[16][68];
  const int t = threadIdx.x;
  const int m0 = blockIdx.x * 128;
  const int n0 = blockIdx.y * 64;
  const int tx = t & 15, ty = t >> 4;
  float acc[8][4] = {};
  for (int k0 = 0; k0 < K; k0 += 16) {
    {
      const int r  = t >> 1;           // 0..127 tile row
      const int c4 = (t & 1) * 8;      // 0 or 8
      const int row = m0 + r;
      const bool rok = row < M;
#pragma unroll
      for (int j = 0; j < 8; ++j) {
        const int kk = k0 + c4 + j;
        As[c4 + j][r] = (rok && kk < K) ? A[(size_t)row * K + kk] : 0.f;
      }
    }
    {
      const int rr = t >> 6;           // 0..3
      const int c  = t & 63;
#pragma unroll
      for (int j = 0; j < 4; ++j) {
        const int kk = k0 + rr + j * 4;
        Bs[rr + j * 4][c] = (kk < K) ? B[(size_t)kk * 256 + n0 + c] : 0.f;
      }
    }
    __syncthreads();
#pragma unroll
    for (int kk = 0; kk < 16; ++kk) {
      const float4 a0 = *reinterpret_cast<const float4*>(&As[kk][ty * 8]);
      const float4 a1 = *reinterpret_cast<const float4*>(&As[kk][ty * 8 + 4]);
      const float4 bv = *reinterpret_cast<const float4*>(&Bs[kk][tx * 4]);
      const float a[8] = {a0.x, a0.y, a0.z, a0.w, a1.x, a1.y, a1.z, a1.w};
      const float b[4] = {bv.x, bv.y, bv.z, bv.w};
#pragma unroll
      for (int i = 0; i < 8; ++i)
#pragma unroll
        for (int j = 0; j < 4; ++j) acc[i][j] = fmaf(a[i], b[j], acc[i][j]);
    }
    __syncthreads();
  }
#pragma unroll
  for (int i = 0; i < 8; ++i) {
    const int row = m0 + ty * 8 + i;
    if (row < M) {
      float4 o = {acc[i][0], acc[i][1], acc[i][2], acc[i][3]};
      *reinterpret_cast<float4*>(&C[(size_t)row * 256 + n0 + tx * 4]) = o;
    }
  }
  if (el) {
    const int h = n0 >> 6;
    const float4 av = *reinterpret_cast<const float4*>(&al[n0 + tx * 4]);
    float4 rv = {0.f, 0.f, 0.f, 0.f};
    if (er) rv = *reinterpret_cast<const float4*>(&ar[n0 + tx * 4]);
#pragma unroll
    for (int i = 0; i < 8; ++i) {
      float sl = acc[i][0] * av.x + acc[i][1] * av.y + acc[i][2] * av.z + acc[i][3] * av.w;
      float sr = acc[i][0] * rv.x + acc[i][1] * rv.y + acc[i][2] * rv.z + acc[i][3] * rv.w;
      sl += __shfl_xor(sl, 1); sr += __shfl_xor(sr, 1);
      sl += __shfl_xor(sl, 2); sr += __shfl_xor(sr, 2);
      sl += __shfl_xor(sl, 4); sr += __shfl_xor(sr, 4);
      sl += __shfl_xor(sl, 8); sr += __shfl_xor(sr, 8);
      const int row = m0 + ty * 8 + i;
      if (tx == 0 && row < M) {
        el[row * 4 + h] = sl;
        if (er) er[row * 4 + h] = sr;
      }
    }
  }
}

// ------------- make_wr: wr[k,h] = sum_d Wd[k,h*64+d]*ar[h*64+d] -------------
__global__ void make_wr_kernel(const float* __restrict__ Wd,
                               const float* __restrict__ ar,
                               float* __restrict__ wr, int K) {
  const int t = blockIdx.x * blockDim.x + threadIdx.x;
  if (t < K * 4) {
    const int k = t >> 2, h = t & 3;
    float s = 0.f;
    for (int d = 0; d < 64; ++d)
      s = fmaf(Wd[(size_t)k * 256 + h * 64 + d], ar[h * 64 + d], s);
    wr[t] = s;
  }
}

// ------------- er gemv: er[n,h] = sum_k X[n,k]*wr[k,h], one wave/row -------------
__global__ __launch_bounds__(256) void er_gemv_kernel(
    const float* __restrict__ X, const float* __restrict__ wr,
    float* __restrict__ er, int n, int K) {
  __shared__ float swr[1024];
  const int t = threadIdx.x;
  for (int i = t; i < K * 4; i += blockDim.x) swr[i] = wr[i];
  __syncthreads();
  const int lane = t & 63;
  const int gw = (blockIdx.x * blockDim.x + t) >> 6;
  if (gw >= n) return;
  float a0 = 0.f, a1 = 0.f, a2 = 0.f, a3 = 0.f;
  for (int k = lane; k < K; k += 64) {
    const float x = X[(size_t)gw * K + k];
    a0 = fmaf(x, swr[k * 4 + 0], a0);
    a1 = fmaf(x, swr[k * 4 + 1], a1);
    a2 = fmaf(x, swr[k * 4 + 2], a2);
    a3 = fmaf(x, swr[k * 4 + 3], a3);
  }
#pragma unroll
  for (int o = 32; o; o >>= 1) {
    a0 += __shfl_xor(a0, o);
    a1 += __shfl_xor(a1, o);
    a2 += __shfl_xor(a2, o);
    a3 += __shfl_xor(a3, o);
  }
  if (lane == 0) {
    er[gw * 4 + 0] = a0; er[gw * 4 + 1] = a1;
    er[gw * 4 + 2] = a2; er[gw * 4 + 3] = a3;
  }
}

// ------------- CSR build -------------
__global__ void count_kernel(const int* __restrict__ dst, int* __restrict__ cnt, int E) {
  for (int i = blockIdx.x * blockDim.x + threadIdx.x; i < E; i += gridDim.x * blockDim.x)
    atomicAdd(&cnt[dst[i]], 1);
}

__global__ __launch_bounds__(1024) void excl_scan_kernel(int* __restrict__ data, int n) {
  __shared__ int sm[1024];
  __shared__ int carry;
  const int tid = threadIdx.x;
  if (tid == 0) carry = 0;
  __syncthreads();
  for (int base = 0; base < n; base += 1024) {
    const int i = base + tid;
    const int v = (i < n) ? data[i] : 0;
    sm[tid] = v;
    __syncthreads();
    for (int ofs = 1; ofs < 1024; ofs <<= 1) {
      const int tmp = (tid >= ofs) ? sm[tid - ofs] : 0;
      __syncthreads();
      sm[tid] += tmp;
      __syncthreads();
    }
    const int incl = sm[tid];
    const int blocktotal = sm[1023];
    const int c = carry;
    __syncthreads();
    if (i < n) data[i] = c + incl - v;   // exclusive
    if (tid == 0) carry = c + blocktotal;
    __syncthreads();
  }
  if (tid == 0) data[n] = carry;
}

__global__ void fill_kernel(const int* __restrict__ src, const int* __restrict__ dst,
                            const int* __restrict__ off, int* __restrict__ cursor,
                            int* __restrict__ csrsrc, int E) {
  for (int i = blockIdx.x * blockDim.x + threadIdx.x; i < E; i += gridDim.x * blockDim.x) {
    const int d = dst[i];
    const int p = atomicAdd(&cursor[d], 1);
    csrsrc[off[d] + p] = src[i];
  }
}

// ------------- GAT aggregation: one wave per dst node, fused softmax -------------
__global__ __launch_bounds__(256) void gat_aggregate(
    const float* __restrict__ F, const float* __restrict__ el,
    const float* __restrict__ er, const int* __restrict__ off,
    const int* __restrict__ csrsrc, float* __restrict__ out,
    int n_dst, int add_flag) {
  const int lane = threadIdx.x & 63;
  const int myh = lane >> 4;
  const int gw = (blockIdx.x * blockDim.x + threadIdx.x) >> 6;
  if (gw >= n_dst) return;
  const int n = gw;
  const int s0 = off[n], s1 = off[n + 1];
  const float ern = er[n * 4 + myh];
  float4 acc = {0.f, 0.f, 0.f, 0.f};
  float ssum = 0.f;
  for (int p = s0; p < s1; ++p) {
    const int src = csrsrc[p];
    float e = el[src * 4 + myh] + ern;
    e = e > 0.f ? e : 0.2f * e;
    const float ex = expf(e);
    ssum += ex;
    const float4 f = *reinterpret_cast<const float4*>(&F[(size_t)src * 256 + lane * 4]);
    acc.x = fmaf(ex, f.x, acc.x);
    acc.y = fmaf(ex, f.y, acc.y);
    acc.z = fmaf(ex, f.z, acc.z);
    acc.w = fmaf(ex, f.w, acc.w);
  }
  const float inv = ssum > 0.f ? 1.f / ssum : 0.f;
  float4 res = {acc.x * inv, acc.y * inv, acc.z * inv, acc.w * inv};
  float4* po = reinterpret_cast<float4*>(&out[(size_t)n * 256 + lane * 4]);
  if (add_flag) {
    const float4 prev = *po;
    res.x += prev.x; res.y += prev.y; res.z += prev.z; res.w += prev.w;
  }
  *po = res;
}

// ---------- bias (+optional second bias) + relu, in-place ----------
__global__ __launch_bounds__(256) void bias_relu_kernel(
    float* __restrict__ h, const float* __restrict__ b1,
    const float* __restrict__ b2, int n) {
  const int tot = n * 64;
  for (int i = blockIdx.x * blockDim.x + threadIdx.x; i < tot; i += gridDim.x * blockDim.x) {
    const int c4 = (i & 63) * 4;
    float4 v = reinterpret_cast<float4*>(h)[i];
    float4 bb = *reinterpret_cast<const float4*>(&b1[c4]);
    if (b2) {
      const float4 b2v = *reinterpret_cast<const float4*>(&b2[c4]);
      bb.x += b2v.x; bb.y += b2v.y; bb.z += b2v.z; bb.w += b2v.w;
    }
    v.x = fmaxf(v.x + bb.x, 0.f);
    v.y = fmaxf(v.y + bb.y, 0.f);
    v.z = fmaxf(v.z + bb.z, 0.f);
    v.w = fmaxf(v.w + bb.w, 0.f);
    reinterpret_cast<float4*>(h)[i] = v;
  }
}

// ---------- graph readout: LDS two-level reduction ----------
__global__ __launch_bounds__(256) void graph_sum_v2(
    const float* __restrict__ h, const int* __restrict__ gid,
    float* __restrict__ gsum, int n, int colofs) {
  __shared__ float sm[NGRAPH][64];
  const int slice = blockIdx.x & (GS_SLICES - 1);
  const int bs    = blockIdx.x >> 2;
  const int c  = threadIdx.x & 63;
  const int nl = threadIdx.x >> 6;
  for (int i = threadIdx.x; i < NGRAPH * 64; i += 256) (&sm[0][0])[i] = 0.f;
  __syncthreads();
  for (int node = bs * 4 + nl; node < n; node += GS_BLOCKS_PER_SLICE * 4) {
    const int g = gid[node];
    const float v = h[(size_t)node * 256 + slice * 64 + c];
    atomicAdd(&sm[g][c], v);
  }
  __syncthreads();
  for (int i = threadIdx.x; i < NGRAPH * 64; i += 256) {
    const int g = i >> 6, cc = i & 63;
    const float v = sm[g][cc];
    if (v != 0.f) atomicAdd(&gsum[(size_t)g * 512 + colofs + slice * 64 + cc], v);
  }
}

// ---------- graph node-count: LDS histogram ----------
__global__ __launch_bounds__(256) void graph_count_kernel(
    const int* __restrict__ gid, int* __restrict__ gcnt, int n, int cntofs) {
  __shared__ int c[NGRAPH];
  if (threadIdx.x < NGRAPH) c[threadIdx.x] = 0;
  __syncthreads();
  for (int i = blockIdx.x * blockDim.x + threadIdx.x; i < n; i += gridDim.x * blockDim.x)
    atomicAdd(&c[gid[i]], 1);
  __syncthreads();
  if (threadIdx.x < NGRAPH && c[threadIdx.x])
    atomicAdd(&gcnt[cntofs + threadIdx.x], c[threadIdx.x]);
}

// ---------- final MLP ----------
__global__ __launch_bounds__(256) void mlp_kernel(
    const float* __restrict__ gsum, const int* __restrict__ gcnt,
    const float* __restrict__ Wm, const float* __restrict__ bm,
    float* __restrict__ out) {
  __shared__ float g[512];
  const int b = blockIdx.x, t = threadIdx.x;
  const float cl = fmaxf((float)gcnt[b], 1.f);
  const float cp = fmaxf((float)gcnt[64 + b], 1.f);
  for (int k = t; k < 512; k += 256)
    g[k] = gsum[(size_t)b * 512 + k] * (k < 256 ? 1.f / cl : 1.f / cp);
  __syncthreads();
  float acc = bm[t];
  for (int k = 0; k < 512; ++k) acc = fmaf(g[k], Wm[(size_t)k * 256 + t], acc);
  out[b * 256 + t] = fmaxf(acc, 0.f);
}

// =====================================================================
extern "C" void kernel_launch(void* const* d_in, const int* in_sizes, int n_in,
                              void* d_out, int out_size, void* d_ws, size_t ws_size,
                              hipStream_t stream) {
  const float* x_lig  = (const float*)d_in[0];
  const float* x_pro  = (const float*)d_in[1];
  const float* W1_ll  = (const float*)d_in[2];
  const float* al1_ll = (const float*)d_in[3];
  const float* ar1_ll = (const float*)d_in[4];
  const float* b1_ll  = (const float*)d_in[5];
  const float* W1_lps = (const float*)d_in[6];
  const float* W1_lpd = (const float*)d_in[7];
  const float* al1_lp = (const float*)d_in[8];
  const float* ar1_lp = (const float*)d_in[9];
  const float* b1_lp  = (const float*)d_in[10];
  const float* W1_pls = (const float*)d_in[11];
  const float* W1_pld = (const float*)d_in[12];
  const float* al1_pl = (const float*)d_in[13];
  const float* ar1_pl = (const float*)d_in[14];
  const float* b1_pl  = (const float*)d_in[15];
  const float* W2_ll  = (const float*)d_in[16];
  const float* al2_ll = (const float*)d_in[17];
  const float* ar2_ll = (const float*)d_in[18];
  const float* b2_ll  = (const float*)d_in[19];
  const float* W2_lps = (const float*)d_in[20];
  const float* W2_lpd = (const float*)d_in[21];
  const float* al2_lp = (const float*)d_in[22];
  const float* ar2_lp = (const float*)d_in[23];
  const float* b2_lp  = (const float*)d_in[24];
  const float* W2_pls = (const float*)d_in[25];
  const float* W2_pld = (const float*)d_in[26];
  const float* al2_pl = (const float*)d_in[27];
  const float* ar2_pl = (const float*)d_in[28];
  const float* b2_pl  = (const float*)d_in[29];
  const float* W_mlp  = (const float*)d_in[30];
  const float* b_mlp  = (const float*)d_in[31];
  const int* src_ll   = (const int*)d_in[32];
  const int* dst_ll   = (const int*)d_in[33];
  const int* src_lp   = (const int*)d_in[34];
  const int* dst_lp   = (const int*)d_in[35];
  const int* src_pl   = (const int*)d_in[36];
  const int* dst_pl   = (const int*)d_in[37];
  const int* gid_lig  = (const int*)d_in[38];
  const int* gid_pro  = (const int*)d_in[39];
  float* out = (float*)d_out;
  (void)in_sizes; (void)n_in; (void)out_size; (void)ws_size;

  // -------- workspace carving --------
  size_t cur = 0;
  auto carve = [&](size_t bytes) -> char* {
    char* p = (char*)d_ws + cur;
    cur += (bytes + 511) & ~(size_t)511;
    return p;
  };
  const size_t NB = (size_t)40000 * 256 * sizeof(float);
  float* F    = (float*)carve(NB);
  float* h_l  = (float*)carve(NB);
  float* h_p  = (float*)carve(NB);
  float* hX   = (float*)carve(NB);   // h_l2, then reused for h_p2
  float* el   = (float*)carve((size_t)40000 * 4 * sizeof(float));
  float* er   = (float*)carve((size_t)40000 * 4 * sizeof(float));
  float* wr   = (float*)carve((size_t)256 * 4 * sizeof(float));
  float* gsum = (float*)carve((size_t)64 * 512 * sizeof(float));
  int* gcnt   = (int*)carve(128 * sizeof(int));
  int* off_ll = (int*)carve((NLIG + 1) * sizeof(int));
  int* off_lp = (int*)carve((NPRO + 1) * sizeof(int));
  int* off_pl = (int*)carve((NLIG + 1) * sizeof(int));
  int* cursor = (int*)carve((NLIG + 1) * sizeof(int));
  int* csr_ll = (int*)carve((size_t)ELL * sizeof(int));
  int* csr_lp = (int*)carve((size_t)ELP * sizeof(int));
  int* csr_pl = (int*)carve((size_t)EPL * sizeof(int));

  const int B256 = 256;
  auto thrGrid  = [](long long n) { return (int)((n + 255) / 256); };
  auto waveGrid = [](int n) { return (n + 3) / 4; };

  // GEMM + optional fused head-dots (el/er may be null)
  auto run_gemm = [&](const float* A, const float* Bw, float* C, int M, int K,
                      const float* alv, float* elp, const float* arv, float* erp) {
    dim3 g((M + 127) / 128, 4);
    sgemm_fused<<<g, B256, 0, stream>>>(A, Bw, C, M, K, alv, elp, arv, erp);
  };
  auto run_er_gemv = [&](const float* Wd, const float* arv, const float* X, int n, int K) {
    make_wr_kernel<<<(K * 4 + 255) / 256, B256, 0, stream>>>(Wd, arv, wr, K);
    er_gemv_kernel<<<waveGrid(n), B256, 0, stream>>>(X, wr, er, n, K);
  };
  auto run_agg = [&](const int* off, const int* csr, int nDst, float* outbuf, int addf) {
    gat_aggregate<<<waveGrid(nDst), B256, 0, stream>>>(F, el, er, off, csr, outbuf, nDst, addf);
  };

  // -------- CSR builds --------
  struct Rel { const int* src; const int* dst; int* off; int* csr; int E; int Nd; };
  Rel rels[3] = {
    {src_ll, dst_ll, off_ll, csr_ll, ELL, NLIG},
    {src_lp, dst_lp, off_lp, csr_lp, ELP, NPRO},
    {src_pl, dst_pl, off_pl, csr_pl, EPL, NLIG},
  };
  for (int r = 0; r < 3; ++r) {
    hipMemsetAsync(rels[r].off, 0, (rels[r].Nd + 1) * sizeof(int), stream);
    count_kernel<<<thrGrid(rels[r].E), B256, 0, stream>>>(rels[r].dst, rels[r].off, rels[r].E);
    excl_scan_kernel<<<1, 1024, 0, stream>>>(rels[r].off, rels[r].Nd);
    hipMemsetAsync(cursor, 0, (rels[r].Nd + 1) * sizeof(int), stream);
    fill_kernel<<<thrGrid(rels[r].E), B256, 0, stream>>>(
        rels[r].src, rels[r].dst, rels[r].off, cursor, rels[r].csr, rels[r].E);
  }

  // ================= LAYER 1 =================
  // ll (lig->lig): F = x_lig@W1_ll with fused el+er
  run_gemm(x_lig, W1_ll, F, NLIG, 74, al1_ll, el, ar1_ll, er);
  run_agg(off_ll, csr_ll, NLIG, h_l, 0);
  // pl (pro->lig): er via GEMV on dst features; F/el from src GEMM
  run_er_gemv(W1_pld, ar1_pl, x_lig, NLIG, 74);
  run_gemm(x_pro, W1_pls, F, NPRO, 128, al1_pl, el, nullptr, nullptr);
  run_agg(off_pl, csr_pl, NLIG, h_l, 1);
  bias_relu_kernel<<<2048, B256, 0, stream>>>(h_l, b1_ll, b1_pl, NLIG);
  // lp (lig->pro)
  run_er_gemv(W1_lpd, ar1_lp, x_pro, NPRO, 128);
  run_gemm(x_lig, W1_lps, F, NLIG, 74, al1_lp, el, nullptr, nullptr);
  run_agg(off_lp, csr_lp, NPRO, h_p, 0);
  bias_relu_kernel<<<2048, B256, 0, stream>>>(h_p, b1_lp, nullptr, NPRO);

  // ================= LAYER 2 =================
  // ll
  run_gemm(h_l, W2_ll, F, NLIG, 256, al2_ll, el, ar2_ll, er);
  run_agg(off_ll, csr_ll, NLIG, hX, 0);
  // pl
  run_er_gemv(W2_pld, ar2_pl, h_l, NLIG, 256);
  run_gemm(h_p, W2_pls, F, NPRO, 256, al2_pl, el, nullptr, nullptr);
  run_agg(off_pl, csr_pl, NLIG, hX, 1);
  bias_relu_kernel<<<2048, B256, 0, stream>>>(hX, b2_ll, b2_pl, NLIG);

  // readout of h_l2 now so hX can be reused for h_p2
  hipMemsetAsync(gsum, 0, (size_t)64 * 512 * sizeof(float), stream);
  hipMemsetAsync(gcnt, 0, 128 * sizeof(int), stream);
  graph_sum_v2<<<GS_SLICES * GS_BLOCKS_PER_SLICE, B256, 0, stream>>>(hX, gid_lig, gsum, NLIG, 0);
  graph_count_kernel<<<64, B256, 0, stream>>>(gid_lig, gcnt, NLIG, 0);

  // lp
  run_er_gemv(W2_lpd, ar2_lp, h_p, NPRO, 256);
  run_gemm(h_l, W2_lps, F, NLIG, 256, al2_lp, el, nullptr, nullptr);
  run_agg(off_lp, csr_lp, NPRO, hX, 0);
  bias_relu_kernel<<<2048, B256, 0, stream>>>(hX, b2_lp, nullptr, NPRO);
  graph_sum_v2<<<GS_SLICES * GS_BLOCKS_PER_SLICE, B256, 0, stream>>>(hX, gid_pro, gsum, NPRO, 256);
  graph_count_kernel<<<64, B256, 0, stream>>>(gid_pro, gcnt, NPRO, 64);

  // ================= MLP =================
  mlp_kernel<<<64, B256, 0, stream>>>(gsum, gcnt, W_mlp, b_mlp, out);
}

// Round 9
// 1225.415 us; speedup vs baseline: 8.5137x; 1.1671x over previous
//
#include <hip/hip_runtime.h>
#include <hip/hip_bf16.h>

#define NLIG 40000
#define NPRO 40000
#define NGRAPH 64
#define ELL 160000
#define ELP 240000
#define EPL 240000

#define GS_SLICES 4
#define GS_BLOCKS_PER_SLICE 32

typedef __hip_bfloat16 bf16;
typedef __attribute__((ext_vector_type(8))) short short8;
typedef __attribute__((ext_vector_type(4))) float f32x4;

// ---------- convA: f32 [M,K] -> bf16 hi/lo [M,Kp], zero-padded ----------
__global__ __launch_bounds__(256) void convA_kernel(
    const float* __restrict__ A, bf16* __restrict__ hi, bf16* __restrict__ lo,
    int M, int K, int Kp) {
  const long long tot = (long long)M * Kp;
  for (long long i = blockIdx.x * 256LL + threadIdx.x; i < tot; i += gridDim.x * 256LL) {
    const int m = (int)(i / Kp), k = (int)(i % Kp);
    float v = (k < K) ? A[(size_t)m * K + k] : 0.f;
    bf16 h = __float2bfloat16(v);
    float r = v - __bfloat162float(h);
    hi[i] = h;
    lo[i] = __float2bfloat16(r);
  }
}

// ---------- convBt: f32 B[K,256] -> bf16 hi/lo transposed [256,Kp] ----------
__global__ __launch_bounds__(256) void convBt_kernel(
    const float* __restrict__ B, bf16* __restrict__ thi, bf16* __restrict__ tlo,
    int K, int Kp) {
  const int tot = 256 * Kp;
  for (int i = blockIdx.x * 256 + threadIdx.x; i < tot; i += gridDim.x * 256) {
    const int n = i / Kp, k = i % Kp;
    float v = (k < K) ? B[(size_t)k * 256 + n] : 0.f;
    bf16 h = __float2bfloat16(v);
    float r = v - __bfloat162float(h);
    thi[i] = h;
    tlo[i] = __float2bfloat16(r);
  }
}

// ---------- MFMA GEMM: C[M,256] = A[M,Kp] @ B[Kp,256] (split bf16) ----------
// A as hi/lo [M,Kp]; B as TRANSPOSED hi/lo [256,Kp]. Kp % 32 == 0.
// Block: 256 thr = 4 waves; tile 128 rows x 64 cols; wave w: rows w*32..+32.
// Fragments 16x16x32: A lane: row=l&15, k=(l>>4)*8+e ; B(from Bt): col=l&15, k likewise.
// D: col=lane&15, row=(lane>>4)*4+reg  [m89-verified].
// Fused epilogue: el[row*4+h] = sum_col C*al, er likewise (al/ar may be null).
#define LP 40   // LDS row pitch in bf16 (80B)
__global__ __launch_bounds__(256) void mfma_gemm(
    const bf16* __restrict__ AhiP, const bf16* __restrict__ AloP,
    const bf16* __restrict__ BthiP, const bf16* __restrict__ BtloP,
    float* __restrict__ C, int M, int Kp,
    const float* __restrict__ al, float* __restrict__ el,
    const float* __restrict__ ar, float* __restrict__ er) {
  __shared__ short sA[2][128 * LP];
  __shared__ short sB[2][64 * LP];
  const short* Ahi = (const short*)AhiP;
  const short* Alo = (const short*)AloP;
  const short* Bthi = (const short*)BthiP;
  const short* Btlo = (const short*)BtloP;
  const int t = threadIdx.x;
  const int w = t >> 6, l = t & 63;
  const int m0 = blockIdx.x * 128;
  const int n0 = blockIdx.y * 64;
  const f32x4 zf = {0.f, 0.f, 0.f, 0.f};
  const short8 zs = {0, 0, 0, 0, 0, 0, 0, 0};
  f32x4 acc[2][4];
#pragma unroll
  for (int i = 0; i < 2; ++i)
#pragma unroll
    for (int j = 0; j < 4; ++j) acc[i][j] = zf;

  const int fr = l & 15, kg = l >> 4;

  for (int k0 = 0; k0 < Kp; k0 += 32) {
    // stage A tile: 128 rows x 32 k (hi+lo). 512 16B-chunks per matrix.
#pragma unroll
    for (int rep = 0; rep < 2; ++rep) {
      const int p = t + rep * 256;
      const int row = p >> 2, c = p & 3;
      const int gr = m0 + row;
      short8 vh = zs, vl = zs;
      if (gr < M) {
        const size_t g = (size_t)gr * Kp + k0 + c * 8;
        vh = *(const short8*)(Ahi + g);
        vl = *(const short8*)(Alo + g);
      }
      *(short8*)(&sA[0][row * LP + c * 8]) = vh;
      *(short8*)(&sA[1][row * LP + c * 8]) = vl;
    }
    // stage B tile: 64 cols x 32 k (hi+lo). 256 16B-chunks per matrix.
    {
      const int row = t >> 2, c = t & 3;
      const size_t g = (size_t)(n0 + row) * Kp + k0 + c * 8;
      *(short8*)(&sB[0][row * LP + c * 8]) = *(const short8*)(Bthi + g);
      *(short8*)(&sB[1][row * LP + c * 8]) = *(const short8*)(Btlo + g);
    }
    __syncthreads();
    short8 aF[2][2], bF[2][4];
#pragma unroll
    for (int i = 0; i < 2; ++i) {
      const int r = (w * 32 + i * 16 + fr) * LP + kg * 8;
      aF[0][i] = *(const short8*)(&sA[0][r]);
      aF[1][i] = *(const short8*)(&sA[1][r]);
    }
#pragma unroll
    for (int j = 0; j < 4; ++j) {
      const int r = (j * 16 + fr) * LP + kg * 8;
      bF[0][j] = *(const short8*)(&sB[0][r]);
      bF[1][j] = *(const short8*)(&sB[1][r]);
    }
#pragma unroll
    for (int i = 0; i < 2; ++i)
#pragma unroll
      for (int j = 0; j < 4; ++j) {
        acc[i][j] = __builtin_amdgcn_mfma_f32_16x16x32_bf16(aF[0][i], bF[0][j], acc[i][j], 0, 0, 0);
        acc[i][j] = __builtin_amdgcn_mfma_f32_16x16x32_bf16(aF[0][i], bF[1][j], acc[i][j], 0, 0, 0);
        acc[i][j] = __builtin_amdgcn_mfma_f32_16x16x32_bf16(aF[1][i], bF[0][j], acc[i][j], 0, 0, 0);
      }
    __syncthreads();
  }

  // C write
#pragma unroll
  for (int i = 0; i < 2; ++i) {
    const int rbase = m0 + w * 32 + i * 16 + kg * 4;
#pragma unroll
    for (int j = 0; j < 4; ++j) {
      const int col = n0 + j * 16 + fr;
#pragma unroll
      for (int r = 0; r < 4; ++r) {
        const int row = rbase + r;
        if (row < M) C[(size_t)row * 256 + col] = acc[i][j][r];
      }
    }
  }

  // fused el/er epilogue
  if (el) {
    float alv[4], arv[4];
#pragma unroll
    for (int j = 0; j < 4; ++j) {
      alv[j] = al[n0 + j * 16 + fr];
      arv[j] = er ? ar[n0 + j * 16 + fr] : 0.f;
    }
    const int h = n0 >> 6;
#pragma unroll
    for (int i = 0; i < 2; ++i) {
#pragma unroll
      for (int r = 0; r < 4; ++r) {
        float sl = 0.f, sr = 0.f;
#pragma unroll
        for (int j = 0; j < 4; ++j) {
          sl = fmaf(acc[i][j][r], alv[j], sl);
          sr = fmaf(acc[i][j][r], arv[j], sr);
        }
        sl += __shfl_xor(sl, 1); sl += __shfl_xor(sl, 2);
        sl += __shfl_xor(sl, 4); sl += __shfl_xor(sl, 8);
        sr += __shfl_xor(sr, 1); sr += __shfl_xor(sr, 2);
        sr += __shfl_xor(sr, 4); sr += __shfl_xor(sr, 8);
        const int row = m0 + w * 32 + i * 16 + kg * 4 + r;
        if (fr == 0 && row < M) {
          el[row * 4 + h] = sl;
          if (er) er[row * 4 + h] = sr;
        }
      }
    }
  }
}

// ------------- make_wr: wr[k,h] = sum_d Wd[k,h*64+d]*ar[h*64+d] -------------
__global__ void make_wr_kernel(const float* __restrict__ Wd,
                               const float* __restrict__ ar,
                               float* __restrict__ wr, int K) {
  const int t = blockIdx.x * blockDim.x + threadIdx.x;
  if (t < K * 4) {
    const int k = t >> 2, h = t & 3;
    float s = 0.f;
    for (int d = 0; d < 64; ++d)
      s = fmaf(Wd[(size_t)k * 256 + h * 64 + d], ar[h * 64 + d], s);
    wr[t] = s;
  }
}

// ------------- er gemv: er[n,h] = sum_k X[n,k]*wr[k,h], one wave/row -------------
__global__ __launch_bounds__(256) void er_gemv_kernel(
    const float* __restrict__ X, const float* __restrict__ wr,
    float* __restrict__ er, int n, int K) {
  __shared__ float swr[1024];
  const int t = threadIdx.x;
  for (int i = t; i < K * 4; i += blockDim.x) swr[i] = wr[i];
  __syncthreads();
  const int lane = t & 63;
  const int gw = (blockIdx.x * blockDim.x + t) >> 6;
  if (gw >= n) return;
  float a0 = 0.f, a1 = 0.f, a2 = 0.f, a3 = 0.f;
  for (int k = lane; k < K; k += 64) {
    const float x = X[(size_t)gw * K + k];
    a0 = fmaf(x, swr[k * 4 + 0], a0);
    a1 = fmaf(x, swr[k * 4 + 1], a1);
    a2 = fmaf(x, swr[k * 4 + 2], a2);
    a3 = fmaf(x, swr[k * 4 + 3], a3);
  }
#pragma unroll
  for (int o = 32; o; o >>= 1) {
    a0 += __shfl_xor(a0, o);
    a1 += __shfl_xor(a1, o);
    a2 += __shfl_xor(a2, o);
    a3 += __shfl_xor(a3, o);
  }
  if (lane == 0) {
    er[gw * 4 + 0] = a0; er[gw * 4 + 1] = a1;
    er[gw * 4 + 2] = a2; er[gw * 4 + 3] = a3;
  }
}

// ------------- CSR build -------------
__global__ void count_kernel(const int* __restrict__ dst, int* __restrict__ cnt, int E) {
  for (int i = blockIdx.x * blockDim.x + threadIdx.x; i < E; i += gridDim.x * blockDim.x)
    atomicAdd(&cnt[dst[i]], 1);
}

__global__ __launch_bounds__(1024) void excl_scan_kernel(int* __restrict__ data, int n) {
  __shared__ int sm[1024];
  __shared__ int carry;
  const int tid = threadIdx.x;
  if (tid == 0) carry = 0;
  __syncthreads();
  for (int base = 0; base < n; base += 1024) {
    const int i = base + tid;
    const int v = (i < n) ? data[i] : 0;
    sm[tid] = v;
    __syncthreads();
    for (int ofs = 1; ofs < 1024; ofs <<= 1) {
      const int tmp = (tid >= ofs) ? sm[tid - ofs] : 0;
      __syncthreads();
      sm[tid] += tmp;
      __syncthreads();
    }
    const int incl = sm[tid];
    const int blocktotal = sm[1023];
    const int c = carry;
    __syncthreads();
    if (i < n) data[i] = c + incl - v;
    if (tid == 0) carry = c + blocktotal;
    __syncthreads();
  }
  if (tid == 0) data[n] = carry;
}

__global__ void fill_kernel(const int* __restrict__ src, const int* __restrict__ dst,
                            const int* __restrict__ off, int* __restrict__ cursor,
                            int* __restrict__ csrsrc, int E) {
  for (int i = blockIdx.x * blockDim.x + threadIdx.x; i < E; i += gridDim.x * blockDim.x) {
    const int d = dst[i];
    const int p = atomicAdd(&cursor[d], 1);
    csrsrc[off[d] + p] = src[i];
  }
}

// ------------- GAT aggregation: one wave per dst node, fused softmax -------------
__global__ __launch_bounds__(256) void gat_aggregate(
    const float* __restrict__ F, const float* __restrict__ el,
    const float* __restrict__ er, const int* __restrict__ off,
    const int* __restrict__ csrsrc, float* __restrict__ out,
    int n_dst, int add_flag) {
  const int lane = threadIdx.x & 63;
  const int myh = lane >> 4;
  const int gw = (blockIdx.x * blockDim.x + threadIdx.x) >> 6;
  if (gw >= n_dst) return;
  const int n = gw;
  const int s0 = off[n], s1 = off[n + 1];
  const float ern = er[n * 4 + myh];
  float4 acc = {0.f, 0.f, 0.f, 0.f};
  float ssum = 0.f;
  for (int p = s0; p < s1; ++p) {
    const int src = csrsrc[p];
    float e = el[src * 4 + myh] + ern;
    e = e > 0.f ? e : 0.2f * e;
    const float ex = expf(e);
    ssum += ex;
    const float4 f = *reinterpret_cast<const float4*>(&F[(size_t)src * 256 + lane * 4]);
    acc.x = fmaf(ex, f.x, acc.x);
    acc.y = fmaf(ex, f.y, acc.y);
    acc.z = fmaf(ex, f.z, acc.z);
    acc.w = fmaf(ex, f.w, acc.w);
  }
  const float inv = ssum > 0.f ? 1.f / ssum : 0.f;
  float4 res = {acc.x * inv, acc.y * inv, acc.z * inv, acc.w * inv};
  float4* po = reinterpret_cast<float4*>(&out[(size_t)n * 256 + lane * 4]);
  if (add_flag) {
    const float4 prev = *po;
    res.x += prev.x; res.y += prev.y; res.z += prev.z; res.w += prev.w;
  }
  *po = res;
}

// ---------- bias (+optional second bias) + relu, in-place ----------
__global__ __launch_bounds__(256) void bias_relu_kernel(
    float* __restrict__ h, const float* __restrict__ b1,
    const float* __restrict__ b2, int n) {
  const int tot = n * 64;
  for (int i = blockIdx.x * blockDim.x + threadIdx.x; i < tot; i += gridDim.x * blockDim.x) {
    const int c4 = (i & 63) * 4;
    float4 v = reinterpret_cast<float4*>(h)[i];
    float4 bb = *reinterpret_cast<const float4*>(&b1[c4]);
    if (b2) {
      const float4 b2v = *reinterpret_cast<const float4*>(&b2[c4]);
      bb.x += b2v.x; bb.y += b2v.y; bb.z += b2v.z; bb.w += b2v.w;
    }
    v.x = fmaxf(v.x + bb.x, 0.f);
    v.y = fmaxf(v.y + bb.y, 0.f);
    v.z = fmaxf(v.z + bb.z, 0.f);
    v.w = fmaxf(v.w + bb.w, 0.f);
    reinterpret_cast<float4*>(h)[i] = v;
  }
}

// ---------- graph readout: LDS two-level reduction ----------
__global__ __launch_bounds__(256) void graph_sum_v2(
    const float* __restrict__ h, const int* __restrict__ gid,
    float* __restrict__ gsum, int n, int colofs) {
  __shared__ float sm[NGRAPH][64];
  const int slice = blockIdx.x & (GS_SLICES - 1);
  const int bs    = blockIdx.x >> 2;
  const int c  = threadIdx.x & 63;
  const int nl = threadIdx.x >> 6;
  for (int i = threadIdx.x; i < NGRAPH * 64; i += 256) (&sm[0][0])[i] = 0.f;
  __syncthreads();
  for (int node = bs * 4 + nl; node < n; node += GS_BLOCKS_PER_SLICE * 4) {
    const int g = gid[node];
    const float v = h[(size_t)node * 256 + slice * 64 + c];
    atomicAdd(&sm[g][c], v);
  }
  __syncthreads();
  for (int i = threadIdx.x; i < NGRAPH * 64; i += 256) {
    const int g = i >> 6, cc = i & 63;
    const float v = sm[g][cc];
    if (v != 0.f) atomicAdd(&gsum[(size_t)g * 512 + colofs + slice * 64 + cc], v);
  }
}

// ---------- graph node-count: LDS histogram ----------
__global__ __launch_bounds__(256) void graph_count_kernel(
    const int* __restrict__ gid, int* __restrict__ gcnt, int n, int cntofs) {
  __shared__ int c[NGRAPH];
  if (threadIdx.x < NGRAPH) c[threadIdx.x] = 0;
  __syncthreads();
  for (int i = blockIdx.x * blockDim.x + threadIdx.x; i < n; i += gridDim.x * blockDim.x)
    atomicAdd(&c[gid[i]], 1);
  __syncthreads();
  if (threadIdx.x < NGRAPH && c[threadIdx.x])
    atomicAdd(&gcnt[cntofs + threadIdx.x], c[threadIdx.x]);
}

// ---------- final MLP ----------
__global__ __launch_bounds__(256) void mlp_kernel(
    const float* __restrict__ gsum, const int* __restrict__ gcnt,
    const float* __restrict__ Wm, const float* __restrict__ bm,
    float* __restrict__ out) {
  __shared__ float g[512];
  const int b = blockIdx.x, t = threadIdx.x;
  const float cl = fmaxf((float)gcnt[b], 1.f);
  const float cp = fmaxf((float)gcnt[64 + b], 1.f);
  for (int k = t; k < 512; k += 256)
    g[k] = gsum[(size_t)b * 512 + k] * (k < 256 ? 1.f / cl : 1.f / cp);
  __syncthreads();
  float acc = bm[t];
  for (int k = 0; k < 512; ++k) acc = fmaf(g[k], Wm[(size_t)k * 256 + t], acc);
  out[b * 256 + t] = fmaxf(acc, 0.f);
}

// =====================================================================
extern "C" void kernel_launch(void* const* d_in, const int* in_sizes, int n_in,
                              void* d_out, int out_size, void* d_ws, size_t ws_size,
                              hipStream_t stream) {
  const float* x_lig  = (const float*)d_in[0];
  const float* x_pro  = (const float*)d_in[1];
  const float* W1_ll  = (const float*)d_in[2];
  const float* al1_ll = (const float*)d_in[3];
  const float* ar1_ll = (const float*)d_in[4];
  const float* b1_ll  = (const float*)d_in[5];
  const float* W1_lps = (const float*)d_in[6];
  const float* W1_lpd = (const float*)d_in[7];
  const float* al1_lp = (const float*)d_in[8];
  const float* ar1_lp = (const float*)d_in[9];
  const float* b1_lp  = (const float*)d_in[10];
  const float* W1_pls = (const float*)d_in[11];
  const float* W1_pld = (const float*)d_in[12];
  const float* al1_pl = (const float*)d_in[13];
  const float* ar1_pl = (const float*)d_in[14];
  const float* b1_pl  = (const float*)d_in[15];
  const float* W2_ll  = (const float*)d_in[16];
  const float* al2_ll = (const float*)d_in[17];
  const float* ar2_ll = (const float*)d_in[18];
  const float* b2_ll  = (const float*)d_in[19];
  const float* W2_lps = (const float*)d_in[20];
  const float* W2_lpd = (const float*)d_in[21];
  const float* al2_lp = (const float*)d_in[22];
  const float* ar2_lp = (const float*)d_in[23];
  const float* b2_lp  = (const float*)d_in[24];
  const float* W2_pls = (const float*)d_in[25];
  const float* W2_pld = (const float*)d_in[26];
  const float* al2_pl = (const float*)d_in[27];
  const float* ar2_pl = (const float*)d_in[28];
  const float* b2_pl  = (const float*)d_in[29];
  const float* W_mlp  = (const float*)d_in[30];
  const float* b_mlp  = (const float*)d_in[31];
  const int* src_ll   = (const int*)d_in[32];
  const int* dst_ll   = (const int*)d_in[33];
  const int* src_lp   = (const int*)d_in[34];
  const int* dst_lp   = (const int*)d_in[35];
  const int* src_pl   = (const int*)d_in[36];
  const int* dst_pl   = (const int*)d_in[37];
  const int* gid_lig  = (const int*)d_in[38];
  const int* gid_pro  = (const int*)d_in[39];
  float* out = (float*)d_out;
  (void)in_sizes; (void)n_in; (void)out_size; (void)ws_size;

  // -------- workspace carving (~209 MB with overlays) --------
  size_t cur = 0;
  auto carve = [&](size_t bytes) -> char* {
    char* p = (char*)d_ws + cur;
    cur += (bytes + 511) & ~(size_t)511;
    return p;
  };
  const size_t NB = (size_t)40000 * 256 * sizeof(float);  // 40.96 MB
  float* F    = (float*)carve(NB);
  float* h_l  = (float*)carve(NB);   // later: S2 bf16 staging (conv of h_p)
  float* h_p  = (float*)carve(NB);
  float* hX   = (float*)carve(NB);   // h_l2
  char*  S    = carve(NB);           // L1: XL/XP staging; L2: S1 staging; then P2 (h_p2)
  float* el   = (float*)carve((size_t)40000 * 4 * sizeof(float));
  float* er   = (float*)carve((size_t)40000 * 4 * sizeof(float));
  float* erPL = (float*)carve((size_t)40000 * 4 * sizeof(float));
  float* erLP = (float*)carve((size_t)40000 * 4 * sizeof(float));
  float* wr   = (float*)carve((size_t)256 * 4 * sizeof(float));
  bf16* Bthi  = (bf16*)carve((size_t)256 * 256 * sizeof(bf16));
  bf16* Btlo  = (bf16*)carve((size_t)256 * 256 * sizeof(bf16));
  float* gsum = (float*)carve((size_t)64 * 512 * sizeof(float));
  int* gcnt   = (int*)carve(128 * sizeof(int));
  int* off_ll = (int*)carve((NLIG + 1) * sizeof(int));
  int* off_lp = (int*)carve((NPRO + 1) * sizeof(int));
  int* off_pl = (int*)carve((NLIG + 1) * sizeof(int));
  int* cursor = (int*)carve((NLIG + 1) * sizeof(int));
  int* csr_ll = (int*)carve((size_t)ELL * sizeof(int));
  int* csr_lp = (int*)carve((size_t)ELP * sizeof(int));
  int* csr_pl = (int*)carve((size_t)EPL * sizeof(int));

  // staging sub-pointers (bf16 elements)
  bf16* XLhi = (bf16*)S;                                   // 40000 x 96
  bf16* XLlo = XLhi + (size_t)40000 * 96;
  bf16* XPhi = XLlo + (size_t)40000 * 96;                  // 40000 x 128
  bf16* XPlo = XPhi + (size_t)40000 * 128;
  bf16* S1hi = (bf16*)S;                                   // 40000 x 256 (L2, h_l)
  bf16* S1lo = S1hi + (size_t)40000 * 256;
  float* P2  = (float*)S;                                  // h_p2 (after S1 dead)
  bf16* S2hi = (bf16*)h_l;                                 // 40000 x 256 (L2, h_p)
  bf16* S2lo = S2hi + (size_t)40000 * 256;

  const int B256 = 256;
  auto thrGrid  = [](long long n) { return (int)((n + 255) / 256); };
  auto waveGrid = [](int n) { return (n + 3) / 4; };

  auto conv_a = [&](const float* A, bf16* hi, bf16* lo, int M, int K, int Kp) {
    convA_kernel<<<2048, B256, 0, stream>>>(A, hi, lo, M, K, Kp);
  };
  auto run_mfma = [&](const bf16* ahi, const bf16* alo, const float* W, int K, int Kp,
                      float* C, int M, const float* alv, float* elp,
                      const float* arv, float* erp) {
    convBt_kernel<<<256, B256, 0, stream>>>(W, Bthi, Btlo, K, Kp);
    dim3 g((M + 127) / 128, 4);
    mfma_gemm<<<g, B256, 0, stream>>>(ahi, alo, Bthi, Btlo, C, M, Kp, alv, elp, arv, erp);
  };
  auto run_er_gemv = [&](const float* Wd, const float* arv, const float* X,
                         float* dst_er, int n, int K) {
    make_wr_kernel<<<(K * 4 + 255) / 256, B256, 0, stream>>>(Wd, arv, wr, K);
    er_gemv_kernel<<<waveGrid(n), B256, 0, stream>>>(X, wr, dst_er, n, K);
  };
  auto run_agg = [&](const int* off, const int* csr, int nDst, float* outbuf, int addf,
                     const float* erp) {
    gat_aggregate<<<waveGrid(nDst), B256, 0, stream>>>(F, el, erp, off, csr, outbuf, nDst, addf);
  };

  // -------- CSR builds --------
  struct Rel { const int* src; const int* dst; int* off; int* csr; int E; int Nd; };
  Rel rels[3] = {
    {src_ll, dst_ll, off_ll, csr_ll, ELL, NLIG},
    {src_lp, dst_lp, off_lp, csr_lp, ELP, NPRO},
    {src_pl, dst_pl, off_pl, csr_pl, EPL, NLIG},
  };
  for (int r = 0; r < 3; ++r) {
    hipMemsetAsync(rels[r].off, 0, (rels[r].Nd + 1) * sizeof(int), stream);
    count_kernel<<<thrGrid(rels[r].E), B256, 0, stream>>>(rels[r].dst, rels[r].off, rels[r].E);
    excl_scan_kernel<<<1, 1024, 0, stream>>>(rels[r].off, rels[r].Nd);
    hipMemsetAsync(cursor, 0, (rels[r].Nd + 1) * sizeof(int), stream);
    fill_kernel<<<thrGrid(rels[r].E), B256, 0, stream>>>(
        rels[r].src, rels[r].dst, rels[r].off, cursor, rels[r].csr, rels[r].E);
  }

  // ================= LAYER 1 =================
  conv_a(x_lig, XLhi, XLlo, NLIG, 74, 96);
  conv_a(x_pro, XPhi, XPlo, NPRO, 128, 128);
  // ll
  run_mfma(XLhi, XLlo, W1_ll, 74, 96, F, NLIG, al1_ll, el, ar1_ll, er);
  run_agg(off_ll, csr_ll, NLIG, h_l, 0, er);
  // pl: er via GEMV on dst (x_lig); src GEMM x_pro @ W1_pls
  run_er_gemv(W1_pld, ar1_pl, x_lig, er, NLIG, 74);
  run_mfma(XPhi, XPlo, W1_pls, 128, 128, F, NPRO, al1_pl, el, nullptr, nullptr);
  run_agg(off_pl, csr_pl, NLIG, h_l, 1, er);
  bias_relu_kernel<<<2048, B256, 0, stream>>>(h_l, b1_ll, b1_pl, NLIG);
  // lp
  run_er_gemv(W1_lpd, ar1_lp, x_pro, er, NPRO, 128);
  run_mfma(XLhi, XLlo, W1_lps, 74, 96, F, NLIG, al1_lp, el, nullptr, nullptr);
  run_agg(off_lp, csr_lp, NPRO, h_p, 0, er);
  bias_relu_kernel<<<2048, B256, 0, stream>>>(h_p, b1_lp, nullptr, NPRO);

  // ================= LAYER 2 =================
  // dst-side er GEMVs first (need h_l/h_p as f32)
  run_er_gemv(W2_pld, ar2_pl, h_l, erPL, NLIG, 256);
  run_er_gemv(W2_lpd, ar2_lp, h_p, erLP, NPRO, 256);
  // convert h_l -> S1 (h_l f32 dead afterwards)
  conv_a(h_l, S1hi, S1lo, NLIG, 256, 256);
  // ll
  run_mfma(S1hi, S1lo, W2_ll, 256, 256, F, NLIG, al2_ll, el, ar2_ll, er);
  run_agg(off_ll, csr_ll, NLIG, hX, 0, er);
  // lp (src h_l via S1); after this mfma S1 is dead -> P2 overlays it
  run_mfma(S1hi, S1lo, W2_lps, 256, 256, F, NLIG, al2_lp, el, nullptr, nullptr);
  run_agg(off_lp, csr_lp, NPRO, P2, 0, erLP);
  bias_relu_kernel<<<2048, B256, 0, stream>>>(P2, b2_lp, nullptr, NPRO);
  // convert h_p -> S2 (overlays h_l region, free since conv to S1)
  conv_a(h_p, S2hi, S2lo, NPRO, 256, 256);
  // pl
  run_mfma(S2hi, S2lo, W2_pls, 256, 256, F, NPRO, al2_pl, el, nullptr, nullptr);
  run_agg(off_pl, csr_pl, NLIG, hX, 1, erPL);
  bias_relu_kernel<<<2048, B256, 0, stream>>>(hX, b2_ll, b2_pl, NLIG);

  // ================= READOUT + MLP =================
  hipMemsetAsync(gsum, 0, (size_t)64 * 512 * sizeof(float), stream);
  hipMemsetAsync(gcnt, 0, 128 * sizeof(int), stream);
  graph_sum_v2<<<GS_SLICES * GS_BLOCKS_PER_SLICE, B256, 0, stream>>>(hX, gid_lig, gsum, NLIG, 0);
  graph_count_kernel<<<64, B256, 0, stream>>>(gid_lig, gcnt, NLIG, 0);
  graph_sum_v2<<<GS_SLICES * GS_BLOCKS_PER_SLICE, B256, 0, stream>>>(P2, gid_pro, gsum, NPRO, 256);
  graph_count_kernel<<<64, B256, 0, stream>>>(gid_pro, gcnt, NPRO, 64);
  mlp_kernel<<<64, B256, 0, stream>>>(gsum, gcnt, W_mlp, b_mlp, out);
}

// Round 10
// 1082.938 us; speedup vs baseline: 9.6338x; 1.1316x over previous
//
#include <hip/hip_runtime.h>
#include <hip/hip_bf16.h>

#define NLIG 40000
#define NPRO 40000
#define NGRAPH 64
#define ELL 160000
#define ELP 240000
#define EPL 240000

#define RD_STRIPES 256

typedef __hip_bfloat16 bf16;
typedef __attribute__((ext_vector_type(8))) short short8;
typedef __attribute__((ext_vector_type(4))) float f32x4;

// ---------- convA: f32 [M,K] -> bf16 hi/lo [M,Kp], zero-padded ----------
__global__ __launch_bounds__(256) void convA_kernel(
    const float* __restrict__ A, bf16* __restrict__ hi, bf16* __restrict__ lo,
    int M, int K, int Kp) {
  const long long tot = (long long)M * Kp;
  for (long long i = blockIdx.x * 256LL + threadIdx.x; i < tot; i += gridDim.x * 256LL) {
    const int m = (int)(i / Kp), k = (int)(i % Kp);
    float v = (k < K) ? A[(size_t)m * K + k] : 0.f;
    bf16 h = __float2bfloat16(v);
    float r = v - __bfloat162float(h);
    hi[i] = h;
    lo[i] = __float2bfloat16(r);
  }
}

// ---------- convBt: f32 B[K,256] -> bf16 hi/lo transposed [256,Kp] ----------
__global__ __launch_bounds__(256) void convBt_kernel(
    const float* __restrict__ B, bf16* __restrict__ thi, bf16* __restrict__ tlo,
    int K, int Kp) {
  const int tot = 256 * Kp;
  for (int i = blockIdx.x * 256 + threadIdx.x; i < tot; i += gridDim.x * 256) {
    const int n = i / Kp, k = i % Kp;
    float v = (k < K) ? B[(size_t)k * 256 + n] : 0.f;
    bf16 h = __float2bfloat16(v);
    float r = v - __bfloat162float(h);
    thi[i] = h;
    tlo[i] = __float2bfloat16(r);
  }
}

// ---------- MFMA GEMM: C[M,256] = A[M,Kp] @ B[Kp,256] (split bf16) ----------
#define LP 40   // LDS row pitch in bf16 (80B)
__global__ __launch_bounds__(256) void mfma_gemm(
    const bf16* __restrict__ AhiP, const bf16* __restrict__ AloP,
    const bf16* __restrict__ BthiP, const bf16* __restrict__ BtloP,
    float* __restrict__ C, int M, int Kp,
    const float* __restrict__ al, float* __restrict__ el,
    const float* __restrict__ ar, float* __restrict__ er) {
  __shared__ short sA[2][128 * LP];
  __shared__ short sB[2][64 * LP];
  const short* Ahi = (const short*)AhiP;
  const short* Alo = (const short*)AloP;
  const short* Bthi = (const short*)BthiP;
  const short* Btlo = (const short*)BtloP;
  const int t = threadIdx.x;
  const int w = t >> 6, l = t & 63;
  const int m0 = blockIdx.x * 128;
  const int n0 = blockIdx.y * 64;
  const f32x4 zf = {0.f, 0.f, 0.f, 0.f};
  const short8 zs = {0, 0, 0, 0, 0, 0, 0, 0};
  f32x4 acc[2][4];
#pragma unroll
  for (int i = 0; i < 2; ++i)
#pragma unroll
    for (int j = 0; j < 4; ++j) acc[i][j] = zf;

  const int fr = l & 15, kg = l >> 4;

  for (int k0 = 0; k0 < Kp; k0 += 32) {
#pragma unroll
    for (int rep = 0; rep < 2; ++rep) {
      const int p = t + rep * 256;
      const int row = p >> 2, c = p & 3;
      const int gr = m0 + row;
      short8 vh = zs, vl = zs;
      if (gr < M) {
        const size_t g = (size_t)gr * Kp + k0 + c * 8;
        vh = *(const short8*)(Ahi + g);
        vl = *(const short8*)(Alo + g);
      }
      *(short8*)(&sA[0][row * LP + c * 8]) = vh;
      *(short8*)(&sA[1][row * LP + c * 8]) = vl;
    }
    {
      const int row = t >> 2, c = t & 3;
      const size_t g = (size_t)(n0 + row) * Kp + k0 + c * 8;
      *(short8*)(&sB[0][row * LP + c * 8]) = *(const short8*)(Bthi + g);
      *(short8*)(&sB[1][row * LP + c * 8]) = *(const short8*)(Btlo + g);
    }
    __syncthreads();
    short8 aF[2][2], bF[2][4];
#pragma unroll
    for (int i = 0; i < 2; ++i) {
      const int r = (w * 32 + i * 16 + fr) * LP + kg * 8;
      aF[0][i] = *(const short8*)(&sA[0][r]);
      aF[1][i] = *(const short8*)(&sA[1][r]);
    }
#pragma unroll
    for (int j = 0; j < 4; ++j) {
      const int r = (j * 16 + fr) * LP + kg * 8;
      bF[0][j] = *(const short8*)(&sB[0][r]);
      bF[1][j] = *(const short8*)(&sB[1][r]);
    }
#pragma unroll
    for (int i = 0; i < 2; ++i)
#pragma unroll
      for (int j = 0; j < 4; ++j) {
        acc[i][j] = __builtin_amdgcn_mfma_f32_16x16x32_bf16(aF[0][i], bF[0][j], acc[i][j], 0, 0, 0);
        acc[i][j] = __builtin_amdgcn_mfma_f32_16x16x32_bf16(aF[0][i], bF[1][j], acc[i][j], 0, 0, 0);
        acc[i][j] = __builtin_amdgcn_mfma_f32_16x16x32_bf16(aF[1][i], bF[0][j], acc[i][j], 0, 0, 0);
      }
    __syncthreads();
  }

#pragma unroll
  for (int i = 0; i < 2; ++i) {
    const int rbase = m0 + w * 32 + i * 16 + kg * 4;
#pragma unroll
    for (int j = 0; j < 4; ++j) {
      const int col = n0 + j * 16 + fr;
#pragma unroll
      for (int r = 0; r < 4; ++r) {
        const int row = rbase + r;
        if (row < M) C[(size_t)row * 256 + col] = acc[i][j][r];
      }
    }
  }

  if (el) {
    float alv[4], arv[4];
#pragma unroll
    for (int j = 0; j < 4; ++j) {
      alv[j] = al[n0 + j * 16 + fr];
      arv[j] = er ? ar[n0 + j * 16 + fr] : 0.f;
    }
    const int h = n0 >> 6;
#pragma unroll
    for (int i = 0; i < 2; ++i) {
#pragma unroll
      for (int r = 0; r < 4; ++r) {
        float sl = 0.f, sr = 0.f;
#pragma unroll
        for (int j = 0; j < 4; ++j) {
          sl = fmaf(acc[i][j][r], alv[j], sl);
          sr = fmaf(acc[i][j][r], arv[j], sr);
        }
        sl += __shfl_xor(sl, 1); sl += __shfl_xor(sl, 2);
        sl += __shfl_xor(sl, 4); sl += __shfl_xor(sl, 8);
        sr += __shfl_xor(sr, 1); sr += __shfl_xor(sr, 2);
        sr += __shfl_xor(sr, 4); sr += __shfl_xor(sr, 8);
        const int row = m0 + w * 32 + i * 16 + kg * 4 + r;
        if (fr == 0 && row < M) {
          el[row * 4 + h] = sl;
          if (er) er[row * 4 + h] = sr;
        }
      }
    }
  }
}

// ------------- make_wr: wr[k,h] = sum_d Wd[k,h*64+d]*ar[h*64+d] -------------
__global__ void make_wr_kernel(const float* __restrict__ Wd,
                               const float* __restrict__ ar,
                               float* __restrict__ wr, int K) {
  const int t = blockIdx.x * blockDim.x + threadIdx.x;
  if (t < K * 4) {
    const int k = t >> 2, h = t & 3;
    float s = 0.f;
    for (int d = 0; d < 64; ++d)
      s = fmaf(Wd[(size_t)k * 256 + h * 64 + d], ar[h * 64 + d], s);
    wr[t] = s;
  }
}

// ------------- er gemv: er[n,h] = sum_k X[n,k]*wr[k,h], one wave/row -------------
__global__ __launch_bounds__(256) void er_gemv_kernel(
    const float* __restrict__ X, const float* __restrict__ wr,
    float* __restrict__ er, int n, int K) {
  __shared__ float swr[1024];
  const int t = threadIdx.x;
  for (int i = t; i < K * 4; i += blockDim.x) swr[i] = wr[i];
  __syncthreads();
  const int lane = t & 63;
  const int gw = (blockIdx.x * blockDim.x + t) >> 6;
  if (gw >= n) return;
  float a0 = 0.f, a1 = 0.f, a2 = 0.f, a3 = 0.f;
  for (int k = lane; k < K; k += 64) {
    const float x = X[(size_t)gw * K + k];
    a0 = fmaf(x, swr[k * 4 + 0], a0);
    a1 = fmaf(x, swr[k * 4 + 1], a1);
    a2 = fmaf(x, swr[k * 4 + 2], a2);
    a3 = fmaf(x, swr[k * 4 + 3], a3);
  }
#pragma unroll
  for (int o = 32; o; o >>= 1) {
    a0 += __shfl_xor(a0, o);
    a1 += __shfl_xor(a1, o);
    a2 += __shfl_xor(a2, o);
    a3 += __shfl_xor(a3, o);
  }
  if (lane == 0) {
    er[gw * 4 + 0] = a0; er[gw * 4 + 1] = a1;
    er[gw * 4 + 2] = a2; er[gw * 4 + 3] = a3;
  }
}

// ------------- CSR build -------------
__global__ void count_kernel(const int* __restrict__ dst, int* __restrict__ cnt, int E) {
  for (int i = blockIdx.x * blockDim.x + threadIdx.x; i < E; i += gridDim.x * blockDim.x)
    atomicAdd(&cnt[dst[i]], 1);
}

__global__ __launch_bounds__(1024) void excl_scan_kernel(int* __restrict__ data, int n) {
  __shared__ int sm[1024];
  __shared__ int carry;
  const int tid = threadIdx.x;
  if (tid == 0) carry = 0;
  __syncthreads();
  for (int base = 0; base < n; base += 1024) {
    const int i = base + tid;
    const int v = (i < n) ? data[i] : 0;
    sm[tid] = v;
    __syncthreads();
    for (int ofs = 1; ofs < 1024; ofs <<= 1) {
      const int tmp = (tid >= ofs) ? sm[tid - ofs] : 0;
      __syncthreads();
      sm[tid] += tmp;
      __syncthreads();
    }
    const int incl = sm[tid];
    const int blocktotal = sm[1023];
    const int c = carry;
    __syncthreads();
    if (i < n) data[i] = c + incl - v;
    if (tid == 0) carry = c + blocktotal;
    __syncthreads();
  }
  if (tid == 0) data[n] = carry;
}

__global__ void fill_kernel(const int* __restrict__ src, const int* __restrict__ dst,
                            const int* __restrict__ off, int* __restrict__ cursor,
                            int* __restrict__ csrsrc, int E) {
  for (int i = blockIdx.x * blockDim.x + threadIdx.x; i < E; i += gridDim.x * blockDim.x) {
    const int d = dst[i];
    const int p = atomicAdd(&cursor[d], 1);
    csrsrc[off[d] + p] = src[i];
  }
}

// ------------- GAT aggregation: one wave per dst node, fused softmax -------------
__global__ __launch_bounds__(256) void gat_aggregate(
    const float* __restrict__ F, const float* __restrict__ el,
    const float* __restrict__ er, const int* __restrict__ off,
    const int* __restrict__ csrsrc, float* __restrict__ out,
    int n_dst, int add_flag) {
  const int lane = threadIdx.x & 63;
  const int myh = lane >> 4;
  const int gw = (blockIdx.x * blockDim.x + threadIdx.x) >> 6;
  if (gw >= n_dst) return;
  const int n = gw;
  const int s0 = off[n], s1 = off[n + 1];
  const float ern = er[n * 4 + myh];
  float4 acc = {0.f, 0.f, 0.f, 0.f};
  float ssum = 0.f;
  for (int p = s0; p < s1; ++p) {
    const int src = csrsrc[p];
    float e = el[src * 4 + myh] + ern;
    e = e > 0.f ? e : 0.2f * e;
    const float ex = expf(e);
    ssum += ex;
    const float4 f = *reinterpret_cast<const float4*>(&F[(size_t)src * 256 + lane * 4]);
    acc.x = fmaf(ex, f.x, acc.x);
    acc.y = fmaf(ex, f.y, acc.y);
    acc.z = fmaf(ex, f.z, acc.z);
    acc.w = fmaf(ex, f.w, acc.w);
  }
  const float inv = ssum > 0.f ? 1.f / ssum : 0.f;
  float4 res = {acc.x * inv, acc.y * inv, acc.z * inv, acc.w * inv};
  float4* po = reinterpret_cast<float4*>(&out[(size_t)n * 256 + lane * 4]);
  if (add_flag) {
    const float4 prev = *po;
    res.x += prev.x; res.y += prev.y; res.z += prev.z; res.w += prev.w;
  }
  *po = res;
}

// ---------- bias (+optional second bias) + relu, in-place ----------
__global__ __launch_bounds__(256) void bias_relu_kernel(
    float* __restrict__ h, const float* __restrict__ b1,
    const float* __restrict__ b2, int n) {
  const int tot = n * 64;
  for (int i = blockIdx.x * blockDim.x + threadIdx.x; i < tot; i += gridDim.x * blockDim.x) {
    const int c4 = (i & 63) * 4;
    float4 v = reinterpret_cast<float4*>(h)[i];
    float4 bb = *reinterpret_cast<const float4*>(&b1[c4]);
    if (b2) {
      const float4 b2v = *reinterpret_cast<const float4*>(&b2[c4]);
      bb.x += b2v.x; bb.y += b2v.y; bb.z += b2v.z; bb.w += b2v.w;
    }
    v.x = fmaxf(v.x + bb.x, 0.f);
    v.y = fmaxf(v.y + bb.y, 0.f);
    v.z = fmaxf(v.z + bb.z, 0.f);
    v.w = fmaxf(v.w + bb.w, 0.f);
    reinterpret_cast<float4*>(h)[i] = v;
  }
}

// ---------- graph readout stage 1: atomic-free per-stripe LDS table ----------
// 256 blocks; block b owns nodes [b*chunk,(b+1)*chunk); thread t owns col t.
__global__ __launch_bounds__(256) void graph_sum_v3(
    const float* __restrict__ h, const int* __restrict__ gid,
    float* __restrict__ pbuf, int n) {
  __shared__ float sm[NGRAPH * 256];
  const int t = threadIdx.x;
  for (int i = t; i < NGRAPH * 256; i += 256) sm[i] = 0.f;
  __syncthreads();
  const int chunk = (n + RD_STRIPES - 1) / RD_STRIPES;
  const int lo = blockIdx.x * chunk;
  const int hiN = min(n, lo + chunk);
#pragma unroll 8
  for (int node = lo; node < hiN; ++node) {
    const int g = gid[node];
    const float v = h[(size_t)node * 256 + t];
    sm[g * 256 + t] += v;
  }
  __syncthreads();
  float* dst = pbuf + (size_t)blockIdx.x * (NGRAPH * 256);
  for (int i = t; i < NGRAPH * 256; i += 256) dst[i] = sm[i];
}

// ---------- graph readout stage 2: reduce stripes, write gsum directly ----------
__global__ __launch_bounds__(256) void graph_reduce_kernel(
    const float* __restrict__ pbuf, float* __restrict__ gsum, int colofs) {
  const int g = blockIdx.x, t = threadIdx.x;
  float acc = 0.f;
#pragma unroll 8
  for (int s = 0; s < RD_STRIPES; ++s)
    acc += pbuf[(size_t)s * (NGRAPH * 256) + g * 256 + t];
  gsum[(size_t)g * 512 + colofs + t] = acc;
}

// ---------- graph node-count: LDS histogram ----------
__global__ __launch_bounds__(256) void graph_count_kernel(
    const int* __restrict__ gid, int* __restrict__ gcnt, int n, int cntofs) {
  __shared__ int c[NGRAPH];
  if (threadIdx.x < NGRAPH) c[threadIdx.x] = 0;
  __syncthreads();
  for (int i = blockIdx.x * blockDim.x + threadIdx.x; i < n; i += gridDim.x * blockDim.x)
    atomicAdd(&c[gid[i]], 1);
  __syncthreads();
  if (threadIdx.x < NGRAPH && c[threadIdx.x])
    atomicAdd(&gcnt[cntofs + threadIdx.x], c[threadIdx.x]);
}

// ---------- final MLP ----------
__global__ __launch_bounds__(256) void mlp_kernel(
    const float* __restrict__ gsum, const int* __restrict__ gcnt,
    const float* __restrict__ Wm, const float* __restrict__ bm,
    float* __restrict__ out) {
  __shared__ float g[512];
  const int b = blockIdx.x, t = threadIdx.x;
  const float cl = fmaxf((float)gcnt[b], 1.f);
  const float cp = fmaxf((float)gcnt[64 + b], 1.f);
  for (int k = t; k < 512; k += 256)
    g[k] = gsum[(size_t)b * 512 + k] * (k < 256 ? 1.f / cl : 1.f / cp);
  __syncthreads();
  float acc = bm[t];
  for (int k = 0; k < 512; ++k) acc = fmaf(g[k], Wm[(size_t)k * 256 + t], acc);
  out[b * 256 + t] = fmaxf(acc, 0.f);
}

// =====================================================================
extern "C" void kernel_launch(void* const* d_in, const int* in_sizes, int n_in,
                              void* d_out, int out_size, void* d_ws, size_t ws_size,
                              hipStream_t stream) {
  const float* x_lig  = (const float*)d_in[0];
  const float* x_pro  = (const float*)d_in[1];
  const float* W1_ll  = (const float*)d_in[2];
  const float* al1_ll = (const float*)d_in[3];
  const float* ar1_ll = (const float*)d_in[4];
  const float* b1_ll  = (const float*)d_in[5];
  const float* W1_lps = (const float*)d_in[6];
  const float* W1_lpd = (const float*)d_in[7];
  const float* al1_lp = (const float*)d_in[8];
  const float* ar1_lp = (const float*)d_in[9];
  const float* b1_lp  = (const float*)d_in[10];
  const float* W1_pls = (const float*)d_in[11];
  const float* W1_pld = (const float*)d_in[12];
  const float* al1_pl = (const float*)d_in[13];
  const float* ar1_pl = (const float*)d_in[14];
  const float* b1_pl  = (const float*)d_in[15];
  const float* W2_ll  = (const float*)d_in[16];
  const float* al2_ll = (const float*)d_in[17];
  const float* ar2_ll = (const float*)d_in[18];
  const float* b2_ll  = (const float*)d_in[19];
  const float* W2_lps = (const float*)d_in[20];
  const float* W2_lpd = (const float*)d_in[21];
  const float* al2_lp = (const float*)d_in[22];
  const float* ar2_lp = (const float*)d_in[23];
  const float* b2_lp  = (const float*)d_in[24];
  const float* W2_pls = (const float*)d_in[25];
  const float* W2_pld = (const float*)d_in[26];
  const float* al2_pl = (const float*)d_in[27];
  const float* ar2_pl = (const float*)d_in[28];
  const float* b2_pl  = (const float*)d_in[29];
  const float* W_mlp  = (const float*)d_in[30];
  const float* b_mlp  = (const float*)d_in[31];
  const int* src_ll   = (const int*)d_in[32];
  const int* dst_ll   = (const int*)d_in[33];
  const int* src_lp   = (const int*)d_in[34];
  const int* dst_lp   = (const int*)d_in[35];
  const int* src_pl   = (const int*)d_in[36];
  const int* dst_pl   = (const int*)d_in[37];
  const int* gid_lig  = (const int*)d_in[38];
  const int* gid_pro  = (const int*)d_in[39];
  float* out = (float*)d_out;
  (void)in_sizes; (void)n_in; (void)out_size; (void)ws_size;

  // -------- workspace carving (~209 MB with overlays) --------
  size_t cur = 0;
  auto carve = [&](size_t bytes) -> char* {
    char* p = (char*)d_ws + cur;
    cur += (bytes + 511) & ~(size_t)511;
    return p;
  };
  const size_t NB = (size_t)40000 * 256 * sizeof(float);  // 40.96 MB
  float* F    = (float*)carve(NB);   // fs staging; dead by readout -> pbuf overlay
  float* h_l  = (float*)carve(NB);   // later: S2 bf16 staging (conv of h_p)
  float* h_p  = (float*)carve(NB);
  float* hX   = (float*)carve(NB);   // h_l2
  char*  S    = carve(NB);           // L1: XL/XP staging; L2: S1 staging; then P2 (h_p2)
  float* el   = (float*)carve((size_t)40000 * 4 * sizeof(float));
  float* er   = (float*)carve((size_t)40000 * 4 * sizeof(float));
  float* erPL = (float*)carve((size_t)40000 * 4 * sizeof(float));
  float* erLP = (float*)carve((size_t)40000 * 4 * sizeof(float));
  float* wr   = (float*)carve((size_t)256 * 4 * sizeof(float));
  bf16* Bthi  = (bf16*)carve((size_t)256 * 256 * sizeof(bf16));
  bf16* Btlo  = (bf16*)carve((size_t)256 * 256 * sizeof(bf16));
  float* gsum = (float*)carve((size_t)64 * 512 * sizeof(float));
  int* gcnt   = (int*)carve(128 * sizeof(int));
  int* off_ll = (int*)carve((NLIG + 1) * sizeof(int));
  int* off_lp = (int*)carve((NPRO + 1) * sizeof(int));
  int* off_pl = (int*)carve((NLIG + 1) * sizeof(int));
  int* cursor = (int*)carve((NLIG + 1) * sizeof(int));
  int* csr_ll = (int*)carve((size_t)ELL * sizeof(int));
  int* csr_lp = (int*)carve((size_t)ELP * sizeof(int));
  int* csr_pl = (int*)carve((size_t)EPL * sizeof(int));

  // staging sub-pointers (bf16 elements)
  bf16* XLhi = (bf16*)S;                                   // 40000 x 96
  bf16* XLlo = XLhi + (size_t)40000 * 96;
  bf16* XPhi = XLlo + (size_t)40000 * 96;                  // 40000 x 128
  bf16* XPlo = XPhi + (size_t)40000 * 128;
  bf16* S1hi = (bf16*)S;                                   // 40000 x 256 (L2, h_l)
  bf16* S1lo = S1hi + (size_t)40000 * 256;
  float* P2  = (float*)S;                                  // h_p2 (after S1 dead)
  bf16* S2hi = (bf16*)h_l;                                 // 40000 x 256 (L2, h_p)
  bf16* S2lo = S2hi + (size_t)40000 * 256;
  float* pbuf = F;                                         // 16 MB readout partials (F dead)

  const int B256 = 256;
  auto thrGrid  = [](long long n) { return (int)((n + 255) / 256); };
  auto waveGrid = [](int n) { return (n + 3) / 4; };

  auto conv_a = [&](const float* A, bf16* hi, bf16* lo, int M, int K, int Kp) {
    convA_kernel<<<2048, B256, 0, stream>>>(A, hi, lo, M, K, Kp);
  };
  auto run_mfma = [&](const bf16* ahi, const bf16* alo, const float* W, int K, int Kp,
                      float* C, int M, const float* alv, float* elp,
                      const float* arv, float* erp) {
    convBt_kernel<<<256, B256, 0, stream>>>(W, Bthi, Btlo, K, Kp);
    dim3 g((M + 127) / 128, 4);
    mfma_gemm<<<g, B256, 0, stream>>>(ahi, alo, Bthi, Btlo, C, M, Kp, alv, elp, arv, erp);
  };
  auto run_er_gemv = [&](const float* Wd, const float* arv, const float* X,
                         float* dst_er, int n, int K) {
    make_wr_kernel<<<(K * 4 + 255) / 256, B256, 0, stream>>>(Wd, arv, wr, K);
    er_gemv_kernel<<<waveGrid(n), B256, 0, stream>>>(X, wr, dst_er, n, K);
  };
  auto run_agg = [&](const int* off, const int* csr, int nDst, float* outbuf, int addf,
                     const float* erp) {
    gat_aggregate<<<waveGrid(nDst), B256, 0, stream>>>(F, el, erp, off, csr, outbuf, nDst, addf);
  };

  // -------- CSR builds --------
  struct Rel { const int* src; const int* dst; int* off; int* csr; int E; int Nd; };
  Rel rels[3] = {
    {src_ll, dst_ll, off_ll, csr_ll, ELL, NLIG},
    {src_lp, dst_lp, off_lp, csr_lp, ELP, NPRO},
    {src_pl, dst_pl, off_pl, csr_pl, EPL, NLIG},
  };
  for (int r = 0; r < 3; ++r) {
    hipMemsetAsync(rels[r].off, 0, (rels[r].Nd + 1) * sizeof(int), stream);
    count_kernel<<<thrGrid(rels[r].E), B256, 0, stream>>>(rels[r].dst, rels[r].off, rels[r].E);
    excl_scan_kernel<<<1, 1024, 0, stream>>>(rels[r].off, rels[r].Nd);
    hipMemsetAsync(cursor, 0, (rels[r].Nd + 1) * sizeof(int), stream);
    fill_kernel<<<thrGrid(rels[r].E), B256, 0, stream>>>(
        rels[r].src, rels[r].dst, rels[r].off, cursor, rels[r].csr, rels[r].E);
  }

  // ================= LAYER 1 =================
  conv_a(x_lig, XLhi, XLlo, NLIG, 74, 96);
  conv_a(x_pro, XPhi, XPlo, NPRO, 128, 128);
  // ll
  run_mfma(XLhi, XLlo, W1_ll, 74, 96, F, NLIG, al1_ll, el, ar1_ll, er);
  run_agg(off_ll, csr_ll, NLIG, h_l, 0, er);
  // pl
  run_er_gemv(W1_pld, ar1_pl, x_lig, er, NLIG, 74);
  run_mfma(XPhi, XPlo, W1_pls, 128, 128, F, NPRO, al1_pl, el, nullptr, nullptr);
  run_agg(off_pl, csr_pl, NLIG, h_l, 1, er);
  bias_relu_kernel<<<2048, B256, 0, stream>>>(h_l, b1_ll, b1_pl, NLIG);
  // lp
  run_er_gemv(W1_lpd, ar1_lp, x_pro, er, NPRO, 128);
  run_mfma(XLhi, XLlo, W1_lps, 74, 96, F, NLIG, al1_lp, el, nullptr, nullptr);
  run_agg(off_lp, csr_lp, NPRO, h_p, 0, er);
  bias_relu_kernel<<<2048, B256, 0, stream>>>(h_p, b1_lp, nullptr, NPRO);

  // ================= LAYER 2 =================
  run_er_gemv(W2_pld, ar2_pl, h_l, erPL, NLIG, 256);
  run_er_gemv(W2_lpd, ar2_lp, h_p, erLP, NPRO, 256);
  conv_a(h_l, S1hi, S1lo, NLIG, 256, 256);
  // ll
  run_mfma(S1hi, S1lo, W2_ll, 256, 256, F, NLIG, al2_ll, el, ar2_ll, er);
  run_agg(off_ll, csr_ll, NLIG, hX, 0, er);
  // lp (src h_l via S1); after this mfma S1 dead -> P2 overlays it
  run_mfma(S1hi, S1lo, W2_lps, 256, 256, F, NLIG, al2_lp, el, nullptr, nullptr);
  run_agg(off_lp, csr_lp, NPRO, P2, 0, erLP);
  bias_relu_kernel<<<2048, B256, 0, stream>>>(P2, b2_lp, nullptr, NPRO);
  // conv h_p -> S2 (overlays h_l region)
  conv_a(h_p, S2hi, S2lo, NPRO, 256, 256);
  // pl
  run_mfma(S2hi, S2lo, W2_pls, 256, 256, F, NPRO, al2_pl, el, nullptr, nullptr);
  run_agg(off_pl, csr_pl, NLIG, hX, 1, erPL);
  bias_relu_kernel<<<2048, B256, 0, stream>>>(hX, b2_ll, b2_pl, NLIG);

  // ================= READOUT (F now dead -> pbuf) + MLP =================
  hipMemsetAsync(gcnt, 0, 128 * sizeof(int), stream);
  graph_sum_v3<<<RD_STRIPES, B256, 0, stream>>>(hX, gid_lig, pbuf, NLIG);
  graph_reduce_kernel<<<NGRAPH, B256, 0, stream>>>(pbuf, gsum, 0);
  graph_count_kernel<<<64, B256, 0, stream>>>(gid_lig, gcnt, NLIG, 0);
  graph_sum_v3<<<RD_STRIPES, B256, 0, stream>>>(P2, gid_pro, pbuf, NPRO);
  graph_reduce_kernel<<<NGRAPH, B256, 0, stream>>>(pbuf, gsum, 256);
  graph_count_kernel<<<64, B256, 0, stream>>>(gid_pro, gcnt, NPRO, 64);
  mlp_kernel<<<64, B256, 0, stream>>>(gsum, gcnt, W_mlp, b_mlp, out);
}

// Round 11
// 880.800 us; speedup vs baseline: 11.8447x; 1.2295x over previous
//
#include <hip/hip_runtime.h>
#include <hip/hip_bf16.h>

#define NLIG 40000
#define NPRO 40000
#define NGRAPH 64
#define ELL 160000
#define ELP 240000
#define EPL 240000

#define RD_STRIPES 256

typedef __hip_bfloat16 bf16;
typedef __attribute__((ext_vector_type(8))) short short8;
typedef __attribute__((ext_vector_type(4))) float f32x4;

// ---------- convA: f32 [M,K] -> bf16 hi/lo [M,Kp], zero-padded ----------
__global__ __launch_bounds__(256) void convA_kernel(
    const float* __restrict__ A, bf16* __restrict__ hi, bf16* __restrict__ lo,
    int M, int K, int Kp) {
  const long long tot = (long long)M * Kp;
  for (long long i = blockIdx.x * 256LL + threadIdx.x; i < tot; i += gridDim.x * 256LL) {
    const int m = (int)(i / Kp), k = (int)(i % Kp);
    float v = (k < K) ? A[(size_t)m * K + k] : 0.f;
    bf16 h = __float2bfloat16(v);
    float r = v - __bfloat162float(h);
    hi[i] = h;
    lo[i] = __float2bfloat16(r);
  }
}

// ---------- convBt: f32 B[K,256] -> bf16 hi/lo transposed [256,Kp] ----------
__global__ __launch_bounds__(256) void convBt_kernel(
    const float* __restrict__ B, bf16* __restrict__ thi, bf16* __restrict__ tlo,
    int K, int Kp) {
  const int tot = 256 * Kp;
  for (int i = blockIdx.x * 256 + threadIdx.x; i < tot; i += gridDim.x * 256) {
    const int n = i / Kp, k = i % Kp;
    float v = (k < K) ? B[(size_t)k * 256 + n] : 0.f;
    bf16 h = __float2bfloat16(v);
    float r = v - __bfloat162float(h);
    thi[i] = h;
    tlo[i] = __float2bfloat16(r);
  }
}

// ---------- MFMA GEMM: C[M,256] = A[M,Kp] @ B[Kp,256] (split bf16) ----------
#define LP 40   // LDS row pitch in bf16 (80B)
__global__ __launch_bounds__(256) void mfma_gemm(
    const bf16* __restrict__ AhiP, const bf16* __restrict__ AloP,
    const bf16* __restrict__ BthiP, const bf16* __restrict__ BtloP,
    float* __restrict__ C, int M, int Kp,
    const float* __restrict__ al, float* __restrict__ el,
    const float* __restrict__ ar, float* __restrict__ er) {
  __shared__ short sA[2][128 * LP];
  __shared__ short sB[2][64 * LP];
  const short* Ahi = (const short*)AhiP;
  const short* Alo = (const short*)AloP;
  const short* Bthi = (const short*)BthiP;
  const short* Btlo = (const short*)BtloP;
  const int t = threadIdx.x;
  const int w = t >> 6, l = t & 63;
  const int m0 = blockIdx.x * 128;
  const int n0 = blockIdx.y * 64;
  const f32x4 zf = {0.f, 0.f, 0.f, 0.f};
  const short8 zs = {0, 0, 0, 0, 0, 0, 0, 0};
  f32x4 acc[2][4];
#pragma unroll
  for (int i = 0; i < 2; ++i)
#pragma unroll
    for (int j = 0; j < 4; ++j) acc[i][j] = zf;

  const int fr = l & 15, kg = l >> 4;

  for (int k0 = 0; k0 < Kp; k0 += 32) {
#pragma unroll
    for (int rep = 0; rep < 2; ++rep) {
      const int p = t + rep * 256;
      const int row = p >> 2, c = p & 3;
      const int gr = m0 + row;
      short8 vh = zs, vl = zs;
      if (gr < M) {
        const size_t g = (size_t)gr * Kp + k0 + c * 8;
        vh = *(const short8*)(Ahi + g);
        vl = *(const short8*)(Alo + g);
      }
      *(short8*)(&sA[0][row * LP + c * 8]) = vh;
      *(short8*)(&sA[1][row * LP + c * 8]) = vl;
    }
    {
      const int row = t >> 2, c = t & 3;
      const size_t g = (size_t)(n0 + row) * Kp + k0 + c * 8;
      *(short8*)(&sB[0][row * LP + c * 8]) = *(const short8*)(Bthi + g);
      *(short8*)(&sB[1][row * LP + c * 8]) = *(const short8*)(Btlo + g);
    }
    __syncthreads();
    short8 aF[2][2], bF[2][4];
#pragma unroll
    for (int i = 0; i < 2; ++i) {
      const int r = (w * 32 + i * 16 + fr) * LP + kg * 8;
      aF[0][i] = *(const short8*)(&sA[0][r]);
      aF[1][i] = *(const short8*)(&sA[1][r]);
    }
#pragma unroll
    for (int j = 0; j < 4; ++j) {
      const int r = (j * 16 + fr) * LP + kg * 8;
      bF[0][j] = *(const short8*)(&sB[0][r]);
      bF[1][j] = *(const short8*)(&sB[1][r]);
    }
#pragma unroll
    for (int i = 0; i < 2; ++i)
#pragma unroll
      for (int j = 0; j < 4; ++j) {
        acc[i][j] = __builtin_amdgcn_mfma_f32_16x16x32_bf16(aF[0][i], bF[0][j], acc[i][j], 0, 0, 0);
        acc[i][j] = __builtin_amdgcn_mfma_f32_16x16x32_bf16(aF[0][i], bF[1][j], acc[i][j], 0, 0, 0);
        acc[i][j] = __builtin_amdgcn_mfma_f32_16x16x32_bf16(aF[1][i], bF[0][j], acc[i][j], 0, 0, 0);
      }
    __syncthreads();
  }

#pragma unroll
  for (int i = 0; i < 2; ++i) {
    const int rbase = m0 + w * 32 + i * 16 + kg * 4;
#pragma unroll
    for (int j = 0; j < 4; ++j) {
      const int col = n0 + j * 16 + fr;
#pragma unroll
      for (int r = 0; r < 4; ++r) {
        const int row = rbase + r;
        if (row < M) C[(size_t)row * 256 + col] = acc[i][j][r];
      }
    }
  }

  if (el) {
    float alv[4], arv[4];
#pragma unroll
    for (int j = 0; j < 4; ++j) {
      alv[j] = al[n0 + j * 16 + fr];
      arv[j] = er ? ar[n0 + j * 16 + fr] : 0.f;
    }
    const int h = n0 >> 6;
#pragma unroll
    for (int i = 0; i < 2; ++i) {
#pragma unroll
      for (int r = 0; r < 4; ++r) {
        float sl = 0.f, sr = 0.f;
#pragma unroll
        for (int j = 0; j < 4; ++j) {
          sl = fmaf(acc[i][j][r], alv[j], sl);
          sr = fmaf(acc[i][j][r], arv[j], sr);
        }
        sl += __shfl_xor(sl, 1); sl += __shfl_xor(sl, 2);
        sl += __shfl_xor(sl, 4); sl += __shfl_xor(sl, 8);
        sr += __shfl_xor(sr, 1); sr += __shfl_xor(sr, 2);
        sr += __shfl_xor(sr, 4); sr += __shfl_xor(sr, 8);
        const int row = m0 + w * 32 + i * 16 + kg * 4 + r;
        if (fr == 0 && row < M) {
          el[row * 4 + h] = sl;
          if (er) er[row * 4 + h] = sr;
        }
      }
    }
  }
}

// ------------- make_wr: wr[k,h] = sum_d Wd[k,h*64+d]*ar[h*64+d] -------------
__global__ void make_wr_kernel(const float* __restrict__ Wd,
                               const float* __restrict__ ar,
                               float* __restrict__ wr, int K) {
  const int t = blockIdx.x * blockDim.x + threadIdx.x;
  if (t < K * 4) {
    const int k = t >> 2, h = t & 3;
    float s = 0.f;
    for (int d = 0; d < 64; ++d)
      s = fmaf(Wd[(size_t)k * 256 + h * 64 + d], ar[h * 64 + d], s);
    wr[t] = s;
  }
}

// ------------- er gemv: er[n,h] = sum_k X[n,k]*wr[k,h], one wave/row -------------
__global__ __launch_bounds__(256) void er_gemv_kernel(
    const float* __restrict__ X, const float* __restrict__ wr,
    float* __restrict__ er, int n, int K) {
  __shared__ float swr[1024];
  const int t = threadIdx.x;
  for (int i = t; i < K * 4; i += blockDim.x) swr[i] = wr[i];
  __syncthreads();
  const int lane = t & 63;
  const int gw = (blockIdx.x * blockDim.x + t) >> 6;
  if (gw >= n) return;
  float a0 = 0.f, a1 = 0.f, a2 = 0.f, a3 = 0.f;
  for (int k = lane; k < K; k += 64) {
    const float x = X[(size_t)gw * K + k];
    a0 = fmaf(x, swr[k * 4 + 0], a0);
    a1 = fmaf(x, swr[k * 4 + 1], a1);
    a2 = fmaf(x, swr[k * 4 + 2], a2);
    a3 = fmaf(x, swr[k * 4 + 3], a3);
  }
#pragma unroll
  for (int o = 32; o; o >>= 1) {
    a0 += __shfl_xor(a0, o);
    a1 += __shfl_xor(a1, o);
    a2 += __shfl_xor(a2, o);
    a3 += __shfl_xor(a3, o);
  }
  if (lane == 0) {
    er[gw * 4 + 0] = a0; er[gw * 4 + 1] = a1;
    er[gw * 4 + 2] = a2; er[gw * 4 + 3] = a3;
  }
}

// ------------- CSR build -------------
__global__ void count_kernel(const int* __restrict__ dst, int* __restrict__ cnt, int E) {
  for (int i = blockIdx.x * blockDim.x + threadIdx.x; i < E; i += gridDim.x * blockDim.x)
    atomicAdd(&cnt[dst[i]], 1);
}

// ---- multi-block exclusive scan (3 phases) ----
// phase 1: bsum[b] = sum of data[b*1024 .. +1023]
__global__ __launch_bounds__(256) void scan_reduce_kernel(
    const int* __restrict__ data, int* __restrict__ bsum, int n) {
  const int base = blockIdx.x * 1024;
  int s = 0;
  for (int i = threadIdx.x; i < 1024; i += 256) {
    const int idx = base + i;
    s += (idx < n) ? data[idx] : 0;
  }
#pragma unroll
  for (int o = 32; o; o >>= 1) s += __shfl_xor(s, o);
  __shared__ int ws[4];
  if ((threadIdx.x & 63) == 0) ws[threadIdx.x >> 6] = s;
  __syncthreads();
  if (threadIdx.x == 0) bsum[blockIdx.x] = ws[0] + ws[1] + ws[2] + ws[3];
}

// phase 2: single block exclusive scan of bsum[0..nb)
__global__ __launch_bounds__(1024) void scan_blocksums_kernel(
    int* __restrict__ bsum, int nb) {
  __shared__ int sm[1024];
  const int t = threadIdx.x;
  const int v = (t < nb) ? bsum[t] : 0;
  sm[t] = v;
  __syncthreads();
  for (int ofs = 1; ofs < 1024; ofs <<= 1) {
    const int tmp = (t >= ofs) ? sm[t - ofs] : 0;
    __syncthreads();
    sm[t] += tmp;
    __syncthreads();
  }
  if (t < nb) bsum[t] = sm[t] - v;   // exclusive
}

// phase 3: per-chunk scan + chunk offset; thread at i==n-1 also writes data[n]=total
__global__ __launch_bounds__(1024) void scan_final_kernel(
    int* __restrict__ data, const int* __restrict__ bsum, int n) {
  __shared__ int sm[1024];
  const int t = threadIdx.x;
  const int i = blockIdx.x * 1024 + t;
  const int v = (i < n) ? data[i] : 0;
  sm[t] = v;
  __syncthreads();
  for (int ofs = 1; ofs < 1024; ofs <<= 1) {
    const int tmp = (t >= ofs) ? sm[t - ofs] : 0;
    __syncthreads();
    sm[t] += tmp;
    __syncthreads();
  }
  const int c = bsum[blockIdx.x];
  if (i < n) data[i] = c + sm[t] - v;        // exclusive
  if (i == n - 1) data[n] = c + sm[t];       // total
}

__global__ void fill_kernel(const int* __restrict__ src, const int* __restrict__ dst,
                            const int* __restrict__ off, int* __restrict__ cursor,
                            int* __restrict__ csrsrc, int E) {
  for (int i = blockIdx.x * blockDim.x + threadIdx.x; i < E; i += gridDim.x * blockDim.x) {
    const int d = dst[i];
    const int p = atomicAdd(&cursor[d], 1);
    csrsrc[off[d] + p] = src[i];
  }
}

// ------------- GAT aggregation: one wave per dst node, fused softmax -------------
__global__ __launch_bounds__(256) void gat_aggregate(
    const float* __restrict__ F, const float* __restrict__ el,
    const float* __restrict__ er, const int* __restrict__ off,
    const int* __restrict__ csrsrc, float* __restrict__ out,
    int n_dst, int add_flag) {
  const int lane = threadIdx.x & 63;
  const int myh = lane >> 4;
  const int gw = (blockIdx.x * blockDim.x + threadIdx.x) >> 6;
  if (gw >= n_dst) return;
  const int n = gw;
  const int s0 = off[n], s1 = off[n + 1];
  const float ern = er[n * 4 + myh];
  float4 acc = {0.f, 0.f, 0.f, 0.f};
  float ssum = 0.f;
  for (int p = s0; p < s1; ++p) {
    const int src = csrsrc[p];
    float e = el[src * 4 + myh] + ern;
    e = e > 0.f ? e : 0.2f * e;
    const float ex = expf(e);
    ssum += ex;
    const float4 f = *reinterpret_cast<const float4*>(&F[(size_t)src * 256 + lane * 4]);
    acc.x = fmaf(ex, f.x, acc.x);
    acc.y = fmaf(ex, f.y, acc.y);
    acc.z = fmaf(ex, f.z, acc.z);
    acc.w = fmaf(ex, f.w, acc.w);
  }
  const float inv = ssum > 0.f ? 1.f / ssum : 0.f;
  float4 res = {acc.x * inv, acc.y * inv, acc.z * inv, acc.w * inv};
  float4* po = reinterpret_cast<float4*>(&out[(size_t)n * 256 + lane * 4]);
  if (add_flag) {
    const float4 prev = *po;
    res.x += prev.x; res.y += prev.y; res.z += prev.z; res.w += prev.w;
  }
  *po = res;
}

// ---------- bias (+optional second bias) + relu, in-place ----------
__global__ __launch_bounds__(256) void bias_relu_kernel(
    float* __restrict__ h, const float* __restrict__ b1,
    const float* __restrict__ b2, int n) {
  const int tot = n * 64;
  for (int i = blockIdx.x * blockDim.x + threadIdx.x; i < tot; i += gridDim.x * blockDim.x) {
    const int c4 = (i & 63) * 4;
    float4 v = reinterpret_cast<float4*>(h)[i];
    float4 bb = *reinterpret_cast<const float4*>(&b1[c4]);
    if (b2) {
      const float4 b2v = *reinterpret_cast<const float4*>(&b2[c4]);
      bb.x += b2v.x; bb.y += b2v.y; bb.z += b2v.z; bb.w += b2v.w;
    }
    v.x = fmaxf(v.x + bb.x, 0.f);
    v.y = fmaxf(v.y + bb.y, 0.f);
    v.z = fmaxf(v.z + bb.z, 0.f);
    v.w = fmaxf(v.w + bb.w, 0.f);
    reinterpret_cast<float4*>(h)[i] = v;
  }
}

// ---------- graph readout stage 1: atomic-free per-stripe LDS table ----------
__global__ __launch_bounds__(256) void graph_sum_v3(
    const float* __restrict__ h, const int* __restrict__ gid,
    float* __restrict__ pbuf, int n) {
  __shared__ float sm[NGRAPH * 256];
  const int t = threadIdx.x;
  for (int i = t; i < NGRAPH * 256; i += 256) sm[i] = 0.f;
  __syncthreads();
  const int chunk = (n + RD_STRIPES - 1) / RD_STRIPES;
  const int lo = blockIdx.x * chunk;
  const int hiN = min(n, lo + chunk);
#pragma unroll 8
  for (int node = lo; node < hiN; ++node) {
    const int g = gid[node];
    const float v = h[(size_t)node * 256 + t];
    sm[g * 256 + t] += v;
  }
  __syncthreads();
  float* dst = pbuf + (size_t)blockIdx.x * (NGRAPH * 256);
  for (int i = t; i < NGRAPH * 256; i += 256) dst[i] = sm[i];
}

// ---------- graph readout stage 2 ----------
__global__ __launch_bounds__(256) void graph_reduce_kernel(
    const float* __restrict__ pbuf, float* __restrict__ gsum, int colofs) {
  const int g = blockIdx.x, t = threadIdx.x;
  float acc = 0.f;
#pragma unroll 8
  for (int s = 0; s < RD_STRIPES; ++s)
    acc += pbuf[(size_t)s * (NGRAPH * 256) + g * 256 + t];
  gsum[(size_t)g * 512 + colofs + t] = acc;
}

// ---------- graph node-count: LDS histogram ----------
__global__ __launch_bounds__(256) void graph_count_kernel(
    const int* __restrict__ gid, int* __restrict__ gcnt, int n, int cntofs) {
  __shared__ int c[NGRAPH];
  if (threadIdx.x < NGRAPH) c[threadIdx.x] = 0;
  __syncthreads();
  for (int i = blockIdx.x * blockDim.x + threadIdx.x; i < n; i += gridDim.x * blockDim.x)
    atomicAdd(&c[gid[i]], 1);
  __syncthreads();
  if (threadIdx.x < NGRAPH && c[threadIdx.x])
    atomicAdd(&gcnt[cntofs + threadIdx.x], c[threadIdx.x]);
}

// ---------- final MLP ----------
__global__ __launch_bounds__(256) void mlp_kernel(
    const float* __restrict__ gsum, const int* __restrict__ gcnt,
    const float* __restrict__ Wm, const float* __restrict__ bm,
    float* __restrict__ out) {
  __shared__ float g[512];
  const int b = blockIdx.x, t = threadIdx.x;
  const float cl = fmaxf((float)gcnt[b], 1.f);
  const float cp = fmaxf((float)gcnt[64 + b], 1.f);
  for (int k = t; k < 512; k += 256)
    g[k] = gsum[(size_t)b * 512 + k] * (k < 256 ? 1.f / cl : 1.f / cp);
  __syncthreads();
  float acc = bm[t];
  for (int k = 0; k < 512; ++k) acc = fmaf(g[k], Wm[(size_t)k * 256 + t], acc);
  out[b * 256 + t] = fmaxf(acc, 0.f);
}

// =====================================================================
extern "C" void kernel_launch(void* const* d_in, const int* in_sizes, int n_in,
                              void* d_out, int out_size, void* d_ws, size_t ws_size,
                              hipStream_t stream) {
  const float* x_lig  = (const float*)d_in[0];
  const float* x_pro  = (const float*)d_in[1];
  const float* W1_ll  = (const float*)d_in[2];
  const float* al1_ll = (const float*)d_in[3];
  const float* ar1_ll = (const float*)d_in[4];
  const float* b1_ll  = (const float*)d_in[5];
  const float* W1_lps = (const float*)d_in[6];
  const float* W1_lpd = (const float*)d_in[7];
  const float* al1_lp = (const float*)d_in[8];
  const float* ar1_lp = (const float*)d_in[9];
  const float* b1_lp  = (const float*)d_in[10];
  const float* W1_pls = (const float*)d_in[11];
  const float* W1_pld = (const float*)d_in[12];
  const float* al1_pl = (const float*)d_in[13];
  const float* ar1_pl = (const float*)d_in[14];
  const float* b1_pl  = (const float*)d_in[15];
  const float* W2_ll  = (const float*)d_in[16];
  const float* al2_ll = (const float*)d_in[17];
  const float* ar2_ll = (const float*)d_in[18];
  const float* b2_ll  = (const float*)d_in[19];
  const float* W2_lps = (const float*)d_in[20];
  const float* W2_lpd = (const float*)d_in[21];
  const float* al2_lp = (const float*)d_in[22];
  const float* ar2_lp = (const float*)d_in[23];
  const float* b2_lp  = (const float*)d_in[24];
  const float* W2_pls = (const float*)d_in[25];
  const float* W2_pld = (const float*)d_in[26];
  const float* al2_pl = (const float*)d_in[27];
  const float* ar2_pl = (const float*)d_in[28];
  const float* b2_pl  = (const float*)d_in[29];
  const float* W_mlp  = (const float*)d_in[30];
  const float* b_mlp  = (const float*)d_in[31];
  const int* src_ll   = (const int*)d_in[32];
  const int* dst_ll   = (const int*)d_in[33];
  const int* src_lp   = (const int*)d_in[34];
  const int* dst_lp   = (const int*)d_in[35];
  const int* src_pl   = (const int*)d_in[36];
  const int* dst_pl   = (const int*)d_in[37];
  const int* gid_lig  = (const int*)d_in[38];
  const int* gid_pro  = (const int*)d_in[39];
  float* out = (float*)d_out;
  (void)in_sizes; (void)n_in; (void)out_size; (void)ws_size;

  // -------- workspace carving (~209 MB with overlays) --------
  size_t cur = 0;
  auto carve = [&](size_t bytes) -> char* {
    char* p = (char*)d_ws + cur;
    cur += (bytes + 511) & ~(size_t)511;
    return p;
  };
  const size_t NB = (size_t)40000 * 256 * sizeof(float);  // 40.96 MB
  float* F    = (float*)carve(NB);   // fs staging; dead by readout -> pbuf overlay
  float* h_l  = (float*)carve(NB);   // later: S2 bf16 staging (conv of h_p)
  float* h_p  = (float*)carve(NB);
  float* hX   = (float*)carve(NB);   // h_l2
  char*  S    = carve(NB);           // L1: XL/XP staging; L2: S1 staging; then P2 (h_p2)
  float* el   = (float*)carve((size_t)40000 * 4 * sizeof(float));
  float* er   = (float*)carve((size_t)40000 * 4 * sizeof(float));
  float* erPL = (float*)carve((size_t)40000 * 4 * sizeof(float));
  float* erLP = (float*)carve((size_t)40000 * 4 * sizeof(float));
  float* wr   = (float*)carve((size_t)256 * 4 * sizeof(float));
  bf16* Bthi  = (bf16*)carve((size_t)256 * 256 * sizeof(bf16));
  bf16* Btlo  = (bf16*)carve((size_t)256 * 256 * sizeof(bf16));
  float* gsum = (float*)carve((size_t)64 * 512 * sizeof(float));
  int* gcnt   = (int*)carve(128 * sizeof(int));
  int* bsum   = (int*)carve(1025 * sizeof(int));
  int* off_ll = (int*)carve((NLIG + 1) * sizeof(int));
  int* off_lp = (int*)carve((NPRO + 1) * sizeof(int));
  int* off_pl = (int*)carve((NLIG + 1) * sizeof(int));
  int* cursor = (int*)carve((NLIG + 1) * sizeof(int));
  int* csr_ll = (int*)carve((size_t)ELL * sizeof(int));
  int* csr_lp = (int*)carve((size_t)ELP * sizeof(int));
  int* csr_pl = (int*)carve((size_t)EPL * sizeof(int));

  // staging sub-pointers (bf16 elements)
  bf16* XLhi = (bf16*)S;                                   // 40000 x 96
  bf16* XLlo = XLhi + (size_t)40000 * 96;
  bf16* XPhi = XLlo + (size_t)40000 * 96;                  // 40000 x 128
  bf16* XPlo = XPhi + (size_t)40000 * 128;
  bf16* S1hi = (bf16*)S;                                   // 40000 x 256 (L2, h_l)
  bf16* S1lo = S1hi + (size_t)40000 * 256;
  float* P2  = (float*)S;                                  // h_p2 (after S1 dead)
  bf16* S2hi = (bf16*)h_l;                                 // 40000 x 256 (L2, h_p)
  bf16* S2lo = S2hi + (size_t)40000 * 256;
  float* pbuf = F;                                         // 16 MB readout partials (F dead)

  const int B256 = 256;
  auto thrGrid  = [](long long n) { return (int)((n + 255) / 256); };
  auto waveGrid = [](int n) { return (n + 3) / 4; };

  auto conv_a = [&](const float* A, bf16* hi, bf16* lo, int M, int K, int Kp) {
    convA_kernel<<<2048, B256, 0, stream>>>(A, hi, lo, M, K, Kp);
  };
  auto run_mfma = [&](const bf16* ahi, const bf16* alo, const float* W, int K, int Kp,
                      float* C, int M, const float* alv, float* elp,
                      const float* arv, float* erp) {
    convBt_kernel<<<256, B256, 0, stream>>>(W, Bthi, Btlo, K, Kp);
    dim3 g((M + 127) / 128, 4);
    mfma_gemm<<<g, B256, 0, stream>>>(ahi, alo, Bthi, Btlo, C, M, Kp, alv, elp, arv, erp);
  };
  auto run_er_gemv = [&](const float* Wd, const float* arv, const float* X,
                         float* dst_er, int n, int K) {
    make_wr_kernel<<<(K * 4 + 255) / 256, B256, 0, stream>>>(Wd, arv, wr, K);
    er_gemv_kernel<<<waveGrid(n), B256, 0, stream>>>(X, wr, dst_er, n, K);
  };
  auto run_agg = [&](const int* off, const int* csr, int nDst, float* outbuf, int addf,
                     const float* erp) {
    gat_aggregate<<<waveGrid(nDst), B256, 0, stream>>>(F, el, erp, off, csr, outbuf, nDst, addf);
  };
  auto run_scan = [&](int* data, int n) {   // exclusive scan of data[0..n), data[n]=total
    const int nb = (n + 1023) / 1024;
    scan_reduce_kernel<<<nb, B256, 0, stream>>>(data, bsum, n);
    scan_blocksums_kernel<<<1, 1024, 0, stream>>>(bsum, nb);
    scan_final_kernel<<<nb, 1024, 0, stream>>>(data, bsum, n);
  };

  // -------- CSR builds --------
  struct Rel { const int* src; const int* dst; int* off; int* csr; int E; int Nd; };
  Rel rels[3] = {
    {src_ll, dst_ll, off_ll, csr_ll, ELL, NLIG},
    {src_lp, dst_lp, off_lp, csr_lp, ELP, NPRO},
    {src_pl, dst_pl, off_pl, csr_pl, EPL, NLIG},
  };
  for (int r = 0; r < 3; ++r) {
    hipMemsetAsync(rels[r].off, 0, (rels[r].Nd + 1) * sizeof(int), stream);
    count_kernel<<<thrGrid(rels[r].E), B256, 0, stream>>>(rels[r].dst, rels[r].off, rels[r].E);
    run_scan(rels[r].off, rels[r].Nd);
    hipMemsetAsync(cursor, 0, (rels[r].Nd + 1) * sizeof(int), stream);
    fill_kernel<<<thrGrid(rels[r].E), B256, 0, stream>>>(
        rels[r].src, rels[r].dst, rels[r].off, cursor, rels[r].csr, rels[r].E);
  }

  // ================= LAYER 1 =================
  conv_a(x_lig, XLhi, XLlo, NLIG, 74, 96);
  conv_a(x_pro, XPhi, XPlo, NPRO, 128, 128);
  // ll
  run_mfma(XLhi, XLlo, W1_ll, 74, 96, F, NLIG, al1_ll, el, ar1_ll, er);
  run_agg(off_ll, csr_ll, NLIG, h_l, 0, er);
  // pl
  run_er_gemv(W1_pld, ar1_pl, x_lig, er, NLIG, 74);
  run_mfma(XPhi, XPlo, W1_pls, 128, 128, F, NPRO, al1_pl, el, nullptr, nullptr);
  run_agg(off_pl, csr_pl, NLIG, h_l, 1, er);
  bias_relu_kernel<<<2048, B256, 0, stream>>>(h_l, b1_ll, b1_pl, NLIG);
  // lp
  run_er_gemv(W1_lpd, ar1_lp, x_pro, er, NPRO, 128);
  run_mfma(XLhi, XLlo, W1_lps, 74, 96, F, NLIG, al1_lp, el, nullptr, nullptr);
  run_agg(off_lp, csr_lp, NPRO, h_p, 0, er);
  bias_relu_kernel<<<2048, B256, 0, stream>>>(h_p, b1_lp, nullptr, NPRO);

  // ================= LAYER 2 =================
  run_er_gemv(W2_pld, ar2_pl, h_l, erPL, NLIG, 256);
  run_er_gemv(W2_lpd, ar2_lp, h_p, erLP, NPRO, 256);
  conv_a(h_l, S1hi, S1lo, NLIG, 256, 256);
  // ll
  run_mfma(S1hi, S1lo, W2_ll, 256, 256, F, NLIG, al2_ll, el, ar2_ll, er);
  run_agg(off_ll, csr_ll, NLIG, hX, 0, er);
  // lp (src h_l via S1); after this mfma S1 dead -> P2 overlays it
  run_mfma(S1hi, S1lo, W2_lps, 256, 256, F, NLIG, al2_lp, el, nullptr, nullptr);
  run_agg(off_lp, csr_lp, NPRO, P2, 0, erLP);
  bias_relu_kernel<<<2048, B256, 0, stream>>>(P2, b2_lp, nullptr, NPRO);
  // conv h_p -> S2 (overlays h_l region)
  conv_a(h_p, S2hi, S2lo, NPRO, 256, 256);
  // pl
  run_mfma(S2hi, S2lo, W2_pls, 256, 256, F, NPRO, al2_pl, el, nullptr, nullptr);
  run_agg(off_pl, csr_pl, NLIG, hX, 1, erPL);
  bias_relu_kernel<<<2048, B256, 0, stream>>>(hX, b2_ll, b2_pl, NLIG);

  // ================= READOUT (F now dead -> pbuf) + MLP =================
  hipMemsetAsync(gcnt, 0, 128 * sizeof(int), stream);
  graph_sum_v3<<<RD_STRIPES, B256, 0, stream>>>(hX, gid_lig, pbuf, NLIG);
  graph_reduce_kernel<<<NGRAPH, B256, 0, stream>>>(pbuf, gsum, 0);
  graph_count_kernel<<<64, B256, 0, stream>>>(gid_lig, gcnt, NLIG, 0);
  graph_sum_v3<<<RD_STRIPES, B256, 0, stream>>>(P2, gid_pro, pbuf, NPRO);
  graph_reduce_kernel<<<NGRAPH, B256, 0, stream>>>(pbuf, gsum, 256);
  graph_count_kernel<<<64, B256, 0, stream>>>(gid_pro, gcnt, NPRO, 64);
  mlp_kernel<<<64, B256, 0, stream>>>(gsum, gcnt, W_mlp, b_mlp, out);
}

// Round 12
// 758.696 us; speedup vs baseline: 13.7509x; 1.1609x over previous
//
#include <hip/hip_runtime.h>
#include <hip/hip_bf16.h>

#define NLIG 40000
#define NPRO 40000
#define NGRAPH 64
#define ELL 160000
#define ELP 240000
#define EPL 240000

#define RD_STRIPES 256

typedef __hip_bfloat16 bf16;
typedef __attribute__((ext_vector_type(8))) short short8;
typedef __attribute__((ext_vector_type(4))) short short4v;
typedef __attribute__((ext_vector_type(4))) float f32x4;

// ---------- convA: f32 [M,K] -> bf16 hi/lo [M,Kp], zero-padded, no int division ----------
// grid: ceil(M/8) blocks x 256 thr. thread t: row = blk*8 + t>>5, cols c4 = (t&31)+32*i.
__global__ __launch_bounds__(256) void convA_kernel(
    const float* __restrict__ A, bf16* __restrict__ hi, bf16* __restrict__ lo,
    int M, int K, int Kp) {
  const int row = blockIdx.x * 8 + (threadIdx.x >> 5);
  if (row >= M) return;
  const int Kp4 = Kp >> 2;
  short* hp = (short*)hi;
  short* lq = (short*)lo;
  for (int c4 = threadIdx.x & 31; c4 < Kp4; c4 += 32) {
    const int k = c4 << 2;
    float v[4];
#pragma unroll
    for (int j = 0; j < 4; ++j) {
      const int kk = k + j;
      v[j] = (kk < K) ? A[(size_t)row * K + kk] : 0.f;
    }
    short4v hv, lv;
#pragma unroll
    for (int j = 0; j < 4; ++j) {
      bf16 h = __float2bfloat16(v[j]);
      float r = v[j] - __bfloat162float(h);
      bf16 l = __float2bfloat16(r);
      hv[j] = *reinterpret_cast<short*>(&h);
      lv[j] = *reinterpret_cast<short*>(&l);
    }
    *reinterpret_cast<short4v*>(&hp[(size_t)row * Kp + k]) = hv;
    *reinterpret_cast<short4v*>(&lq[(size_t)row * Kp + k]) = lv;
  }
}

// ---------- convBt: f32 B[K,256] -> bf16 hi/lo transposed [256,Kp] ----------
__global__ __launch_bounds__(256) void convBt_kernel(
    const float* __restrict__ B, bf16* __restrict__ thi, bf16* __restrict__ tlo,
    int K, int Kp) {
  const int tot = 256 * Kp;
  for (int i = blockIdx.x * 256 + threadIdx.x; i < tot; i += gridDim.x * 256) {
    const int n = i / Kp, k = i % Kp;
    float v = (k < K) ? B[(size_t)k * 256 + n] : 0.f;
    bf16 h = __float2bfloat16(v);
    float r = v - __bfloat162float(h);
    thi[i] = h;
    tlo[i] = __float2bfloat16(r);
  }
}

// ---------- MFMA GEMM: C[M,256] = A[M,Kp] @ B[Kp,256] (split bf16) ----------
// Tile 128 rows x 128 cols, grid (ceil(M/128), 2), 4 waves (wave w: rows w*32..+32).
// Fragments 16x16x32; D: col=lane&15, row=(lane>>4)*4+reg [m89-verified].
#define LP 40   // LDS row pitch in bf16 (80B)
__global__ __launch_bounds__(256) void mfma_gemm(
    const bf16* __restrict__ AhiP, const bf16* __restrict__ AloP,
    const bf16* __restrict__ BthiP, const bf16* __restrict__ BtloP,
    float* __restrict__ C, int M, int Kp,
    const float* __restrict__ al, float* __restrict__ el,
    const float* __restrict__ ar, float* __restrict__ er) {
  __shared__ short sA[2][128 * LP];
  __shared__ short sB[2][128 * LP];
  const short* Ahi = (const short*)AhiP;
  const short* Alo = (const short*)AloP;
  const short* Bthi = (const short*)BthiP;
  const short* Btlo = (const short*)BtloP;
  const int t = threadIdx.x;
  const int w = t >> 6, l = t & 63;
  const int m0 = blockIdx.x * 128;
  const int n0 = blockIdx.y * 128;
  const f32x4 zf = {0.f, 0.f, 0.f, 0.f};
  const short8 zs = {0, 0, 0, 0, 0, 0, 0, 0};
  f32x4 acc[2][8];
#pragma unroll
  for (int i = 0; i < 2; ++i)
#pragma unroll
    for (int j = 0; j < 8; ++j) acc[i][j] = zf;

  const int fr = l & 15, kg = l >> 4;

  for (int k0 = 0; k0 < Kp; k0 += 32) {
#pragma unroll
    for (int rep = 0; rep < 2; ++rep) {
      const int p = t + rep * 256;
      const int row = p >> 2, c = p & 3;
      const int gr = m0 + row;
      short8 vh = zs, vl = zs;
      if (gr < M) {
        const size_t g = (size_t)gr * Kp + k0 + c * 8;
        vh = *(const short8*)(Ahi + g);
        vl = *(const short8*)(Alo + g);
      }
      *(short8*)(&sA[0][row * LP + c * 8]) = vh;
      *(short8*)(&sA[1][row * LP + c * 8]) = vl;
    }
#pragma unroll
    for (int rep = 0; rep < 2; ++rep) {
      const int p = t + rep * 256;
      const int row = p >> 2, c = p & 3;
      const size_t g = (size_t)(n0 + row) * Kp + k0 + c * 8;
      *(short8*)(&sB[0][row * LP + c * 8]) = *(const short8*)(Bthi + g);
      *(short8*)(&sB[1][row * LP + c * 8]) = *(const short8*)(Btlo + g);
    }
    __syncthreads();
    short8 aF[2][2];
#pragma unroll
    for (int i = 0; i < 2; ++i) {
      const int r = (w * 32 + i * 16 + fr) * LP + kg * 8;
      aF[0][i] = *(const short8*)(&sA[0][r]);
      aF[1][i] = *(const short8*)(&sA[1][r]);
    }
#pragma unroll
    for (int j = 0; j < 8; ++j) {
      const int r = (j * 16 + fr) * LP + kg * 8;
      const short8 b0 = *(const short8*)(&sB[0][r]);
      const short8 b1 = *(const short8*)(&sB[1][r]);
#pragma unroll
      for (int i = 0; i < 2; ++i) {
        acc[i][j] = __builtin_amdgcn_mfma_f32_16x16x32_bf16(aF[0][i], b0, acc[i][j], 0, 0, 0);
        acc[i][j] = __builtin_amdgcn_mfma_f32_16x16x32_bf16(aF[0][i], b1, acc[i][j], 0, 0, 0);
        acc[i][j] = __builtin_amdgcn_mfma_f32_16x16x32_bf16(aF[1][i], b0, acc[i][j], 0, 0, 0);
      }
    }
    __syncthreads();
  }

  // C write
#pragma unroll
  for (int i = 0; i < 2; ++i) {
    const int rbase = m0 + w * 32 + i * 16 + kg * 4;
#pragma unroll
    for (int j = 0; j < 8; ++j) {
      const int col = n0 + j * 16 + fr;
#pragma unroll
      for (int r = 0; r < 4; ++r) {
        const int row = rbase + r;
        if (row < M) C[(size_t)row * 256 + col] = acc[i][j][r];
      }
    }
  }

  // fused el/er epilogue (two heads per block)
  if (el) {
    float alv[8], arv[8];
#pragma unroll
    for (int j = 0; j < 8; ++j) {
      alv[j] = al[n0 + j * 16 + fr];
      arv[j] = er ? ar[n0 + j * 16 + fr] : 0.f;
    }
    const int hb = n0 >> 6;   // head base: 0 or 2
#pragma unroll
    for (int i = 0; i < 2; ++i) {
#pragma unroll
      for (int r = 0; r < 4; ++r) {
        float sl0 = 0.f, sl1 = 0.f, sr0 = 0.f, sr1 = 0.f;
#pragma unroll
        for (int j = 0; j < 4; ++j) {
          sl0 = fmaf(acc[i][j][r], alv[j], sl0);
          sr0 = fmaf(acc[i][j][r], arv[j], sr0);
          sl1 = fmaf(acc[i][j + 4][r], alv[j + 4], sl1);
          sr1 = fmaf(acc[i][j + 4][r], arv[j + 4], sr1);
        }
        sl0 += __shfl_xor(sl0, 1); sl0 += __shfl_xor(sl0, 2);
        sl0 += __shfl_xor(sl0, 4); sl0 += __shfl_xor(sl0, 8);
        sl1 += __shfl_xor(sl1, 1); sl1 += __shfl_xor(sl1, 2);
        sl1 += __shfl_xor(sl1, 4); sl1 += __shfl_xor(sl1, 8);
        sr0 += __shfl_xor(sr0, 1); sr0 += __shfl_xor(sr0, 2);
        sr0 += __shfl_xor(sr0, 4); sr0 += __shfl_xor(sr0, 8);
        sr1 += __shfl_xor(sr1, 1); sr1 += __shfl_xor(sr1, 2);
        sr1 += __shfl_xor(sr1, 4); sr1 += __shfl_xor(sr1, 8);
        const int row = m0 + w * 32 + i * 16 + kg * 4 + r;
        if (fr == 0 && row < M) {
          el[row * 4 + hb] = sl0;
          el[row * 4 + hb + 1] = sl1;
          if (er) {
            er[row * 4 + hb] = sr0;
            er[row * 4 + hb + 1] = sr1;
          }
        }
      }
    }
  }
}

// ------------- make_wr: wr[k,h] = sum_d Wd[k,h*64+d]*ar[h*64+d] -------------
__global__ void make_wr_kernel(const float* __restrict__ Wd,
                               const float* __restrict__ ar,
                               float* __restrict__ wr, int K) {
  const int t = blockIdx.x * blockDim.x + threadIdx.x;
  if (t < K * 4) {
    const int k = t >> 2, h = t & 3;
    float s = 0.f;
    for (int d = 0; d < 64; ++d)
      s = fmaf(Wd[(size_t)k * 256 + h * 64 + d], ar[h * 64 + d], s);
    wr[t] = s;
  }
}

// ------------- er gemv: er[n,h] = sum_k X[n,k]*wr[k,h], one wave/row -------------
__global__ __launch_bounds__(256) void er_gemv_kernel(
    const float* __restrict__ X, const float* __restrict__ wr,
    float* __restrict__ er, int n, int K) {
  __shared__ float swr[1024];
  const int t = threadIdx.x;
  for (int i = t; i < K * 4; i += blockDim.x) swr[i] = wr[i];
  __syncthreads();
  const int lane = t & 63;
  const int gw = (blockIdx.x * blockDim.x + t) >> 6;
  if (gw >= n) return;
  float a0 = 0.f, a1 = 0.f, a2 = 0.f, a3 = 0.f;
  for (int k = lane; k < K; k += 64) {
    const float x = X[(size_t)gw * K + k];
    a0 = fmaf(x, swr[k * 4 + 0], a0);
    a1 = fmaf(x, swr[k * 4 + 1], a1);
    a2 = fmaf(x, swr[k * 4 + 2], a2);
    a3 = fmaf(x, swr[k * 4 + 3], a3);
  }
#pragma unroll
  for (int o = 32; o; o >>= 1) {
    a0 += __shfl_xor(a0, o);
    a1 += __shfl_xor(a1, o);
    a2 += __shfl_xor(a2, o);
    a3 += __shfl_xor(a3, o);
  }
  if (lane == 0) {
    er[gw * 4 + 0] = a0; er[gw * 4 + 1] = a1;
    er[gw * 4 + 2] = a2; er[gw * 4 + 3] = a3;
  }
}

// ------------- CSR build -------------
__global__ void count_kernel(const int* __restrict__ dst, int* __restrict__ cnt, int E) {
  for (int i = blockIdx.x * blockDim.x + threadIdx.x; i < E; i += gridDim.x * blockDim.x)
    atomicAdd(&cnt[dst[i]], 1);
}

__global__ __launch_bounds__(256) void scan_reduce_kernel(
    const int* __restrict__ data, int* __restrict__ bsum, int n) {
  const int base = blockIdx.x * 1024;
  int s = 0;
  for (int i = threadIdx.x; i < 1024; i += 256) {
    const int idx = base + i;
    s += (idx < n) ? data[idx] : 0;
  }
#pragma unroll
  for (int o = 32; o; o >>= 1) s += __shfl_xor(s, o);
  __shared__ int ws[4];
  if ((threadIdx.x & 63) == 0) ws[threadIdx.x >> 6] = s;
  __syncthreads();
  if (threadIdx.x == 0) bsum[blockIdx.x] = ws[0] + ws[1] + ws[2] + ws[3];
}

__global__ __launch_bounds__(1024) void scan_blocksums_kernel(
    int* __restrict__ bsum, int nb) {
  __shared__ int sm[1024];
  const int t = threadIdx.x;
  const int v = (t < nb) ? bsum[t] : 0;
  sm[t] = v;
  __syncthreads();
  for (int ofs = 1; ofs < 1024; ofs <<= 1) {
    const int tmp = (t >= ofs) ? sm[t - ofs] : 0;
    __syncthreads();
    sm[t] += tmp;
    __syncthreads();
  }
  if (t < nb) bsum[t] = sm[t] - v;   // exclusive
}

__global__ __launch_bounds__(1024) void scan_final_kernel(
    int* __restrict__ data, const int* __restrict__ bsum, int n) {
  __shared__ int sm[1024];
  const int t = threadIdx.x;
  const int i = blockIdx.x * 1024 + t;
  const int v = (i < n) ? data[i] : 0;
  sm[t] = v;
  __syncthreads();
  for (int ofs = 1; ofs < 1024; ofs <<= 1) {
    const int tmp = (t >= ofs) ? sm[t - ofs] : 0;
    __syncthreads();
    sm[t] += tmp;
    __syncthreads();
  }
  const int c = bsum[blockIdx.x];
  if (i < n) data[i] = c + sm[t] - v;
  if (i == n - 1) data[n] = c + sm[t];
}

__global__ void fill_kernel(const int* __restrict__ src, const int* __restrict__ dst,
                            const int* __restrict__ off, int* __restrict__ cursor,
                            int* __restrict__ csrsrc, int E) {
  for (int i = blockIdx.x * blockDim.x + threadIdx.x; i < E; i += gridDim.x * blockDim.x) {
    const int d = dst[i];
    const int p = atomicAdd(&cursor[d], 1);
    csrsrc[off[d] + p] = src[i];
  }
}

// ------------- GAT aggregation v2: one wave/node, 8-edge batched gathers,
// fused softmax + optional bias(+bias2) + relu -------------
__global__ __launch_bounds__(256) void gat_aggregate(
    const float* __restrict__ F, const float* __restrict__ el,
    const float* __restrict__ er, const int* __restrict__ off,
    const int* __restrict__ csrsrc, float* __restrict__ out,
    int n_dst, int add_flag,
    const float* __restrict__ bias1, const float* __restrict__ bias2, int do_relu) {
  const int lane = threadIdx.x & 63;
  const int myh = lane >> 4;
  const int gw = (blockIdx.x * blockDim.x + threadIdx.x) >> 6;
  if (gw >= n_dst) return;
  const int s0 = off[gw], s1 = off[gw + 1];
  const float ern = er[gw * 4 + myh];
  float4 acc = {0.f, 0.f, 0.f, 0.f};
  float ssum = 0.f;
  for (int p = s0; p < s1; p += 8) {
    const int nb = s1 - p;             // >= 1
    int srcs[8];
#pragma unroll
    for (int b = 0; b < 8; ++b) {
      const int q = (b < nb) ? b : nb - 1;   // clamp: pads re-read a valid index
      srcs[b] = csrsrc[p + q];
    }
    float w8[8];
#pragma unroll
    for (int b = 0; b < 8; ++b) {
      float e = el[srcs[b] * 4 + myh] + ern;
      e = e > 0.f ? e : 0.2f * e;
      w8[b] = (b < nb) ? expf(e) : 0.f;
    }
    float4 f8[8];
#pragma unroll
    for (int b = 0; b < 8; ++b)
      f8[b] = *reinterpret_cast<const float4*>(&F[(size_t)srcs[b] * 256 + lane * 4]);
#pragma unroll
    for (int b = 0; b < 8; ++b) {
      ssum += w8[b];
      acc.x = fmaf(w8[b], f8[b].x, acc.x);
      acc.y = fmaf(w8[b], f8[b].y, acc.y);
      acc.z = fmaf(w8[b], f8[b].z, acc.z);
      acc.w = fmaf(w8[b], f8[b].w, acc.w);
    }
  }
  const float inv = ssum > 0.f ? 1.f / ssum : 0.f;
  float4 res = {acc.x * inv, acc.y * inv, acc.z * inv, acc.w * inv};
  float4* po = reinterpret_cast<float4*>(&out[(size_t)gw * 256 + lane * 4]);
  if (add_flag) {
    const float4 prev = *po;
    res.x += prev.x; res.y += prev.y; res.z += prev.z; res.w += prev.w;
  }
  if (bias1) {
    float4 bb = *reinterpret_cast<const float4*>(&bias1[lane * 4]);
    if (bias2) {
      const float4 b2 = *reinterpret_cast<const float4*>(&bias2[lane * 4]);
      bb.x += b2.x; bb.y += b2.y; bb.z += b2.z; bb.w += b2.w;
    }
    res.x += bb.x; res.y += bb.y; res.z += bb.z; res.w += bb.w;
  }
  if (do_relu) {
    res.x = fmaxf(res.x, 0.f); res.y = fmaxf(res.y, 0.f);
    res.z = fmaxf(res.z, 0.f); res.w = fmaxf(res.w, 0.f);
  }
  *po = res;
}

// ---------- graph readout stage 1: atomic-free per-stripe LDS table ----------
__global__ __launch_bounds__(256) void graph_sum_v3(
    const float* __restrict__ h, const int* __restrict__ gid,
    float* __restrict__ pbuf, int n) {
  __shared__ float sm[NGRAPH * 256];
  const int t = threadIdx.x;
  for (int i = t; i < NGRAPH * 256; i += 256) sm[i] = 0.f;
  __syncthreads();
  const int chunk = (n + RD_STRIPES - 1) / RD_STRIPES;
  const int lo = blockIdx.x * chunk;
  const int hiN = min(n, lo + chunk);
#pragma unroll 8
  for (int node = lo; node < hiN; ++node) {
    const int g = gid[node];
    const float v = h[(size_t)node * 256 + t];
    sm[g * 256 + t] += v;
  }
  __syncthreads();
  float* dst = pbuf + (size_t)blockIdx.x * (NGRAPH * 256);
  for (int i = t; i < NGRAPH * 256; i += 256) dst[i] = sm[i];
}

// ---------- graph readout stage 2 ----------
__global__ __launch_bounds__(256) void graph_reduce_kernel(
    const float* __restrict__ pbuf, float* __restrict__ gsum, int colofs) {
  const int g = blockIdx.x, t = threadIdx.x;
  float acc = 0.f;
#pragma unroll 8
  for (int s = 0; s < RD_STRIPES; ++s)
    acc += pbuf[(size_t)s * (NGRAPH * 256) + g * 256 + t];
  gsum[(size_t)g * 512 + colofs + t] = acc;
}

// ---------- graph node-count: LDS histogram ----------
__global__ __launch_bounds__(256) void graph_count_kernel(
    const int* __restrict__ gid, int* __restrict__ gcnt, int n, int cntofs) {
  __shared__ int c[NGRAPH];
  if (threadIdx.x < NGRAPH) c[threadIdx.x] = 0;
  __syncthreads();
  for (int i = blockIdx.x * blockDim.x + threadIdx.x; i < n; i += gridDim.x * blockDim.x)
    atomicAdd(&c[gid[i]], 1);
  __syncthreads();
  if (threadIdx.x < NGRAPH && c[threadIdx.x])
    atomicAdd(&gcnt[cntofs + threadIdx.x], c[threadIdx.x]);
}

// ---------- final MLP ----------
__global__ __launch_bounds__(256) void mlp_kernel(
    const float* __restrict__ gsum, const int* __restrict__ gcnt,
    const float* __restrict__ Wm, const float* __restrict__ bm,
    float* __restrict__ out) {
  __shared__ float g[512];
  const int b = blockIdx.x, t = threadIdx.x;
  const float cl = fmaxf((float)gcnt[b], 1.f);
  const float cp = fmaxf((float)gcnt[64 + b], 1.f);
  for (int k = t; k < 512; k += 256)
    g[k] = gsum[(size_t)b * 512 + k] * (k < 256 ? 1.f / cl : 1.f / cp);
  __syncthreads();
  float acc = bm[t];
  for (int k = 0; k < 512; ++k) acc = fmaf(g[k], Wm[(size_t)k * 256 + t], acc);
  out[b * 256 + t] = fmaxf(acc, 0.f);
}

// =====================================================================
extern "C" void kernel_launch(void* const* d_in, const int* in_sizes, int n_in,
                              void* d_out, int out_size, void* d_ws, size_t ws_size,
                              hipStream_t stream) {
  const float* x_lig  = (const float*)d_in[0];
  const float* x_pro  = (const float*)d_in[1];
  const float* W1_ll  = (const float*)d_in[2];
  const float* al1_ll = (const float*)d_in[3];
  const float* ar1_ll = (const float*)d_in[4];
  const float* b1_ll  = (const float*)d_in[5];
  const float* W1_lps = (const float*)d_in[6];
  const float* W1_lpd = (const float*)d_in[7];
  const float* al1_lp = (const float*)d_in[8];
  const float* ar1_lp = (const float*)d_in[9];
  const float* b1_lp  = (const float*)d_in[10];
  const float* W1_pls = (const float*)d_in[11];
  const float* W1_pld = (const float*)d_in[12];
  const float* al1_pl = (const float*)d_in[13];
  const float* ar1_pl = (const float*)d_in[14];
  const float* b1_pl  = (const float*)d_in[15];
  const float* W2_ll  = (const float*)d_in[16];
  const float* al2_ll = (const float*)d_in[17];
  const float* ar2_ll = (const float*)d_in[18];
  const float* b2_ll  = (const float*)d_in[19];
  const float* W2_lps = (const float*)d_in[20];
  const float* W2_lpd = (const float*)d_in[21];
  const float* al2_lp = (const float*)d_in[22];
  const float* ar2_lp = (const float*)d_in[23];
  const float* b2_lp  = (const float*)d_in[24];
  const float* W2_pls = (const float*)d_in[25];
  const float* W2_pld = (const float*)d_in[26];
  const float* al2_pl = (const float*)d_in[27];
  const float* ar2_pl = (const float*)d_in[28];
  const float* b2_pl  = (const float*)d_in[29];
  const float* W_mlp  = (const float*)d_in[30];
  const float* b_mlp  = (const float*)d_in[31];
  const int* src_ll   = (const int*)d_in[32];
  const int* dst_ll   = (const int*)d_in[33];
  const int* src_lp   = (const int*)d_in[34];
  const int* dst_lp   = (const int*)d_in[35];
  const int* src_pl   = (const int*)d_in[36];
  const int* dst_pl   = (const int*)d_in[37];
  const int* gid_lig  = (const int*)d_in[38];
  const int* gid_pro  = (const int*)d_in[39];
  float* out = (float*)d_out;
  (void)in_sizes; (void)n_in; (void)out_size; (void)ws_size;

  // -------- workspace carving (~209 MB with overlays) --------
  size_t cur = 0;
  auto carve = [&](size_t bytes) -> char* {
    char* p = (char*)d_ws + cur;
    cur += (bytes + 511) & ~(size_t)511;
    return p;
  };
  const size_t NB = (size_t)40000 * 256 * sizeof(float);  // 40.96 MB
  float* F    = (float*)carve(NB);   // fs staging; dead by readout -> pbuf overlay
  float* h_l  = (float*)carve(NB);   // later: S2 bf16 staging (conv of h_p)
  float* h_p  = (float*)carve(NB);
  float* hX   = (float*)carve(NB);   // h_l2
  char*  S    = carve(NB);           // L1: XL/XP staging; L2: S1 staging; then P2 (h_p2)
  float* el   = (float*)carve((size_t)40000 * 4 * sizeof(float));
  float* er   = (float*)carve((size_t)40000 * 4 * sizeof(float));
  float* erPL = (float*)carve((size_t)40000 * 4 * sizeof(float));
  float* erLP = (float*)carve((size_t)40000 * 4 * sizeof(float));
  float* wr   = (float*)carve((size_t)256 * 4 * sizeof(float));
  bf16* Bthi  = (bf16*)carve((size_t)256 * 256 * sizeof(bf16));
  bf16* Btlo  = (bf16*)carve((size_t)256 * 256 * sizeof(bf16));
  float* gsum = (float*)carve((size_t)64 * 512 * sizeof(float));
  int* gcnt   = (int*)carve(128 * sizeof(int));
  int* bsum   = (int*)carve(1025 * sizeof(int));
  int* off_ll = (int*)carve((NLIG + 1) * sizeof(int));
  int* off_lp = (int*)carve((NPRO + 1) * sizeof(int));
  int* off_pl = (int*)carve((NLIG + 1) * sizeof(int));
  int* cursor = (int*)carve((NLIG + 1) * sizeof(int));
  int* csr_ll = (int*)carve((size_t)ELL * sizeof(int));
  int* csr_lp = (int*)carve((size_t)ELP * sizeof(int));
  int* csr_pl = (int*)carve((size_t)EPL * sizeof(int));

  // staging sub-pointers (bf16 elements)
  bf16* XLhi = (bf16*)S;                                   // 40000 x 96
  bf16* XLlo = XLhi + (size_t)40000 * 96;
  bf16* XPhi = XLlo + (size_t)40000 * 96;                  // 40000 x 128
  bf16* XPlo = XPhi + (size_t)40000 * 128;
  bf16* S1hi = (bf16*)S;                                   // 40000 x 256 (L2, h_l)
  bf16* S1lo = S1hi + (size_t)40000 * 256;
  float* P2  = (float*)S;                                  // h_p2 (after S1 dead)
  bf16* S2hi = (bf16*)h_l;                                 // 40000 x 256 (L2, h_p)
  bf16* S2lo = S2hi + (size_t)40000 * 256;
  float* pbuf = F;                                         // 16 MB readout partials (F dead)

  const int B256 = 256;
  auto thrGrid  = [](long long n) { return (int)((n + 255) / 256); };
  auto waveGrid = [](int n) { return (n + 3) / 4; };

  auto conv_a = [&](const float* A, bf16* hi, bf16* lo, int M, int K, int Kp) {
    convA_kernel<<<(M + 7) / 8, B256, 0, stream>>>(A, hi, lo, M, K, Kp);
  };
  auto run_mfma = [&](const bf16* ahi, const bf16* alo, const float* W, int K, int Kp,
                      float* C, int M, const float* alv, float* elp,
                      const float* arv, float* erp) {
    convBt_kernel<<<256, B256, 0, stream>>>(W, Bthi, Btlo, K, Kp);
    dim3 g((M + 127) / 128, 2);
    mfma_gemm<<<g, B256, 0, stream>>>(ahi, alo, Bthi, Btlo, C, M, Kp, alv, elp, arv, erp);
  };
  auto run_er_gemv = [&](const float* Wd, const float* arv, const float* X,
                         float* dst_er, int n, int K) {
    make_wr_kernel<<<(K * 4 + 255) / 256, B256, 0, stream>>>(Wd, arv, wr, K);
    er_gemv_kernel<<<waveGrid(n), B256, 0, stream>>>(X, wr, dst_er, n, K);
  };
  auto run_agg = [&](const int* off, const int* csr, int nDst, float* outbuf, int addf,
                     const float* erp, const float* bias1, const float* bias2, int relu) {
    gat_aggregate<<<waveGrid(nDst), B256, 0, stream>>>(
        F, el, erp, off, csr, outbuf, nDst, addf, bias1, bias2, relu);
  };
  auto run_scan = [&](int* data, int n) {
    const int nb = (n + 1023) / 1024;
    scan_reduce_kernel<<<nb, B256, 0, stream>>>(data, bsum, n);
    scan_blocksums_kernel<<<1, 1024, 0, stream>>>(bsum, nb);
    scan_final_kernel<<<nb, 1024, 0, stream>>>(data, bsum, n);
  };

  // -------- CSR builds --------
  struct Rel { const int* src; const int* dst; int* off; int* csr; int E; int Nd; };
  Rel rels[3] = {
    {src_ll, dst_ll, off_ll, csr_ll, ELL, NLIG},
    {src_lp, dst_lp, off_lp, csr_lp, ELP, NPRO},
    {src_pl, dst_pl, off_pl, csr_pl, EPL, NLIG},
  };
  for (int r = 0; r < 3; ++r) {
    hipMemsetAsync(rels[r].off, 0, (rels[r].Nd + 1) * sizeof(int), stream);
    count_kernel<<<thrGrid(rels[r].E), B256, 0, stream>>>(rels[r].dst, rels[r].off, rels[r].E);
    run_scan(rels[r].off, rels[r].Nd);
    hipMemsetAsync(cursor, 0, (rels[r].Nd + 1) * sizeof(int), stream);
    fill_kernel<<<thrGrid(rels[r].E), B256, 0, stream>>>(
        rels[r].src, rels[r].dst, rels[r].off, cursor, rels[r].csr, rels[r].E);
  }

  // ================= LAYER 1 =================
  conv_a(x_lig, XLhi, XLlo, NLIG, 74, 96);
  conv_a(x_pro, XPhi, XPlo, NPRO, 128, 128);
  // ll
  run_mfma(XLhi, XLlo, W1_ll, 74, 96, F, NLIG, al1_ll, el, ar1_ll, er);
  run_agg(off_ll, csr_ll, NLIG, h_l, 0, er, nullptr, nullptr, 0);
  // pl (final pass for h_l: fuse b1_ll + b1_pl + relu)
  run_er_gemv(W1_pld, ar1_pl, x_lig, er, NLIG, 74);
  run_mfma(XPhi, XPlo, W1_pls, 128, 128, F, NPRO, al1_pl, el, nullptr, nullptr);
  run_agg(off_pl, csr_pl, NLIG, h_l, 1, er, b1_ll, b1_pl, 1);
  // lp (single pass for h_p: fuse b1_lp + relu)
  run_er_gemv(W1_lpd, ar1_lp, x_pro, er, NPRO, 128);
  run_mfma(XLhi, XLlo, W1_lps, 74, 96, F, NLIG, al1_lp, el, nullptr, nullptr);
  run_agg(off_lp, csr_lp, NPRO, h_p, 0, er, b1_lp, nullptr, 1);

  // ================= LAYER 2 =================
  run_er_gemv(W2_pld, ar2_pl, h_l, erPL, NLIG, 256);
  run_er_gemv(W2_lpd, ar2_lp, h_p, erLP, NPRO, 256);
  conv_a(h_l, S1hi, S1lo, NLIG, 256, 256);
  // ll
  run_mfma(S1hi, S1lo, W2_ll, 256, 256, F, NLIG, al2_ll, el, ar2_ll, er);
  run_agg(off_ll, csr_ll, NLIG, hX, 0, er, nullptr, nullptr, 0);
  // lp (src h_l via S1); after this mfma S1 dead -> P2 overlays it
  run_mfma(S1hi, S1lo, W2_lps, 256, 256, F, NLIG, al2_lp, el, nullptr, nullptr);
  run_agg(off_lp, csr_lp, NPRO, P2, 0, erLP, b2_lp, nullptr, 1);
  // conv h_p -> S2 (overlays h_l region)
  conv_a(h_p, S2hi, S2lo, NPRO, 256, 256);
  // pl (final pass for hX: fuse b2_ll + b2_pl + relu)
  run_mfma(S2hi, S2lo, W2_pls, 256, 256, F, NPRO, al2_pl, el, nullptr, nullptr);
  run_agg(off_pl, csr_pl, NLIG, hX, 1, erPL, b2_ll, b2_pl, 1);

  // ================= READOUT (F now dead -> pbuf) + MLP =================
  hipMemsetAsync(gcnt, 0, 128 * sizeof(int), stream);
  graph_sum_v3<<<RD_STRIPES, B256, 0, stream>>>(hX, gid_lig, pbuf, NLIG);
  graph_reduce_kernel<<<NGRAPH, B256, 0, stream>>>(pbuf, gsum, 0);
  graph_count_kernel<<<64, B256, 0, stream>>>(gid_lig, gcnt, NLIG, 0);
  graph_sum_v3<<<RD_STRIPES, B256, 0, stream>>>(P2, gid_pro, pbuf, NPRO);
  graph_reduce_kernel<<<NGRAPH, B256, 0, stream>>>(pbuf, gsum, 256);
  graph_count_kernel<<<64, B256, 0, stream>>>(gid_pro, gcnt, NPRO, 64);
  mlp_kernel<<<64, B256, 0, stream>>>(gsum, gcnt, W_mlp, b_mlp, out);
}

// Round 13
// 693.734 us; speedup vs baseline: 15.0386x; 1.0936x over previous
//
#include <hip/hip_runtime.h>
#include <hip/hip_bf16.h>

#define NLIG 40000
#define NPRO 40000
#define NGRAPH 64
#define ELL 160000
#define ELP 240000
#define EPL 240000

#define RD_STRIPES 256

typedef __hip_bfloat16 bf16;
typedef __attribute__((ext_vector_type(8))) short short8;
typedef __attribute__((ext_vector_type(4))) short short4v;
typedef __attribute__((ext_vector_type(4))) float f32x4;

__device__ __forceinline__ float bits2f(short s) {
  const unsigned u = ((unsigned)(unsigned short)s) << 16;
  return __uint_as_float(u);
}

// ---------- convA: f32 [M,K] -> bf16 hi/lo [M,Kp], zero-padded ----------
__global__ __launch_bounds__(256) void convA_kernel(
    const float* __restrict__ A, bf16* __restrict__ hi, bf16* __restrict__ lo,
    int M, int K, int Kp) {
  const int row = blockIdx.x * 8 + (threadIdx.x >> 5);
  if (row >= M) return;
  const int Kp4 = Kp >> 2;
  short* hp = (short*)hi;
  short* lq = (short*)lo;
  for (int c4 = threadIdx.x & 31; c4 < Kp4; c4 += 32) {
    const int k = c4 << 2;
    float v[4];
#pragma unroll
    for (int j = 0; j < 4; ++j) {
      const int kk = k + j;
      v[j] = (kk < K) ? A[(size_t)row * K + kk] : 0.f;
    }
    short4v hv, lv;
#pragma unroll
    for (int j = 0; j < 4; ++j) {
      bf16 h = __float2bfloat16(v[j]);
      float r = v[j] - __bfloat162float(h);
      bf16 l = __float2bfloat16(r);
      hv[j] = *reinterpret_cast<short*>(&h);
      lv[j] = *reinterpret_cast<short*>(&l);
    }
    *reinterpret_cast<short4v*>(&hp[(size_t)row * Kp + k]) = hv;
    *reinterpret_cast<short4v*>(&lq[(size_t)row * Kp + k]) = lv;
  }
}

// ---------- convBt: f32 B[K,256] -> bf16 hi/lo transposed [256,Kp] ----------
__global__ __launch_bounds__(256) void convBt_kernel(
    const float* __restrict__ B, bf16* __restrict__ thi, bf16* __restrict__ tlo,
    int K, int Kp) {
  const int tot = 256 * Kp;
  for (int i = blockIdx.x * 256 + threadIdx.x; i < tot; i += gridDim.x * 256) {
    const int n = i / Kp, k = i % Kp;
    float v = (k < K) ? B[(size_t)k * 256 + n] : 0.f;
    bf16 h = __float2bfloat16(v);
    float r = v - __bfloat162float(h);
    thi[i] = h;
    tlo[i] = __float2bfloat16(r);
  }
}

// ---------- MFMA GEMM: C_bf16[M,256] = A[M,Kp] @ B[Kp,256] (split bf16 inputs) ----------
// Tile 128x128, grid (ceil(M/128), 2), 4 waves. D: col=lane&15, row=(lane>>4)*4+reg.
#define LP 40   // LDS row pitch in bf16 (80B)
__global__ __launch_bounds__(256) void mfma_gemm(
    const bf16* __restrict__ AhiP, const bf16* __restrict__ AloP,
    const bf16* __restrict__ BthiP, const bf16* __restrict__ BtloP,
    bf16* __restrict__ C, int M, int Kp,
    const float* __restrict__ al, float* __restrict__ el,
    const float* __restrict__ ar, float* __restrict__ er) {
  __shared__ short sA[2][128 * LP];
  __shared__ short sB[2][128 * LP];
  const short* Ahi = (const short*)AhiP;
  const short* Alo = (const short*)AloP;
  const short* Bthi = (const short*)BthiP;
  const short* Btlo = (const short*)BtloP;
  const int t = threadIdx.x;
  const int w = t >> 6, l = t & 63;
  const int m0 = blockIdx.x * 128;
  const int n0 = blockIdx.y * 128;
  const f32x4 zf = {0.f, 0.f, 0.f, 0.f};
  const short8 zs = {0, 0, 0, 0, 0, 0, 0, 0};
  f32x4 acc[2][8];
#pragma unroll
  for (int i = 0; i < 2; ++i)
#pragma unroll
    for (int j = 0; j < 8; ++j) acc[i][j] = zf;

  const int fr = l & 15, kg = l >> 4;

  for (int k0 = 0; k0 < Kp; k0 += 32) {
#pragma unroll
    for (int rep = 0; rep < 2; ++rep) {
      const int p = t + rep * 256;
      const int row = p >> 2, c = p & 3;
      const int gr = m0 + row;
      short8 vh = zs, vl = zs;
      if (gr < M) {
        const size_t g = (size_t)gr * Kp + k0 + c * 8;
        vh = *(const short8*)(Ahi + g);
        vl = *(const short8*)(Alo + g);
      }
      *(short8*)(&sA[0][row * LP + c * 8]) = vh;
      *(short8*)(&sA[1][row * LP + c * 8]) = vl;
    }
#pragma unroll
    for (int rep = 0; rep < 2; ++rep) {
      const int p = t + rep * 256;
      const int row = p >> 2, c = p & 3;
      const size_t g = (size_t)(n0 + row) * Kp + k0 + c * 8;
      *(short8*)(&sB[0][row * LP + c * 8]) = *(const short8*)(Bthi + g);
      *(short8*)(&sB[1][row * LP + c * 8]) = *(const short8*)(Btlo + g);
    }
    __syncthreads();
    short8 aF[2][2];
#pragma unroll
    for (int i = 0; i < 2; ++i) {
      const int r = (w * 32 + i * 16 + fr) * LP + kg * 8;
      aF[0][i] = *(const short8*)(&sA[0][r]);
      aF[1][i] = *(const short8*)(&sA[1][r]);
    }
#pragma unroll
    for (int j = 0; j < 8; ++j) {
      const int r = (j * 16 + fr) * LP + kg * 8;
      const short8 b0 = *(const short8*)(&sB[0][r]);
      const short8 b1 = *(const short8*)(&sB[1][r]);
#pragma unroll
      for (int i = 0; i < 2; ++i) {
        acc[i][j] = __builtin_amdgcn_mfma_f32_16x16x32_bf16(aF[0][i], b0, acc[i][j], 0, 0, 0);
        acc[i][j] = __builtin_amdgcn_mfma_f32_16x16x32_bf16(aF[0][i], b1, acc[i][j], 0, 0, 0);
        acc[i][j] = __builtin_amdgcn_mfma_f32_16x16x32_bf16(aF[1][i], b0, acc[i][j], 0, 0, 0);
      }
    }
    __syncthreads();
  }

  // C write (bf16)
#pragma unroll
  for (int i = 0; i < 2; ++i) {
    const int rbase = m0 + w * 32 + i * 16 + kg * 4;
#pragma unroll
    for (int j = 0; j < 8; ++j) {
      const int col = n0 + j * 16 + fr;
#pragma unroll
      for (int r = 0; r < 4; ++r) {
        const int row = rbase + r;
        if (row < M) C[(size_t)row * 256 + col] = __float2bfloat16(acc[i][j][r]);
      }
    }
  }

  // fused el/er epilogue (two heads per block), f32 accuracy
  if (el) {
    float alv[8], arv[8];
#pragma unroll
    for (int j = 0; j < 8; ++j) {
      alv[j] = al[n0 + j * 16 + fr];
      arv[j] = er ? ar[n0 + j * 16 + fr] : 0.f;
    }
    const int hb = n0 >> 6;
#pragma unroll
    for (int i = 0; i < 2; ++i) {
#pragma unroll
      for (int r = 0; r < 4; ++r) {
        float sl0 = 0.f, sl1 = 0.f, sr0 = 0.f, sr1 = 0.f;
#pragma unroll
        for (int j = 0; j < 4; ++j) {
          sl0 = fmaf(acc[i][j][r], alv[j], sl0);
          sr0 = fmaf(acc[i][j][r], arv[j], sr0);
          sl1 = fmaf(acc[i][j + 4][r], alv[j + 4], sl1);
          sr1 = fmaf(acc[i][j + 4][r], arv[j + 4], sr1);
        }
        sl0 += __shfl_xor(sl0, 1); sl0 += __shfl_xor(sl0, 2);
        sl0 += __shfl_xor(sl0, 4); sl0 += __shfl_xor(sl0, 8);
        sl1 += __shfl_xor(sl1, 1); sl1 += __shfl_xor(sl1, 2);
        sl1 += __shfl_xor(sl1, 4); sl1 += __shfl_xor(sl1, 8);
        sr0 += __shfl_xor(sr0, 1); sr0 += __shfl_xor(sr0, 2);
        sr0 += __shfl_xor(sr0, 4); sr0 += __shfl_xor(sr0, 8);
        sr1 += __shfl_xor(sr1, 1); sr1 += __shfl_xor(sr1, 2);
        sr1 += __shfl_xor(sr1, 4); sr1 += __shfl_xor(sr1, 8);
        const int row = m0 + w * 32 + i * 16 + kg * 4 + r;
        if (fr == 0 && row < M) {
          el[row * 4 + hb] = sl0;
          el[row * 4 + hb + 1] = sl1;
          if (er) {
            er[row * 4 + hb] = sr0;
            er[row * 4 + hb + 1] = sr1;
          }
        }
      }
    }
  }
}

// ------------- make_wr -------------
__global__ void make_wr_kernel(const float* __restrict__ Wd,
                               const float* __restrict__ ar,
                               float* __restrict__ wr, int K) {
  const int t = blockIdx.x * blockDim.x + threadIdx.x;
  if (t < K * 4) {
    const int k = t >> 2, h = t & 3;
    float s = 0.f;
    for (int d = 0; d < 64; ++d)
      s = fmaf(Wd[(size_t)k * 256 + h * 64 + d], ar[h * 64 + d], s);
    wr[t] = s;
  }
}

// ------------- er gemv -------------
__global__ __launch_bounds__(256) void er_gemv_kernel(
    const float* __restrict__ X, const float* __restrict__ wr,
    float* __restrict__ er, int n, int K) {
  __shared__ float swr[1024];
  const int t = threadIdx.x;
  for (int i = t; i < K * 4; i += blockDim.x) swr[i] = wr[i];
  __syncthreads();
  const int lane = t & 63;
  const int gw = (blockIdx.x * blockDim.x + t) >> 6;
  if (gw >= n) return;
  float a0 = 0.f, a1 = 0.f, a2 = 0.f, a3 = 0.f;
  for (int k = lane; k < K; k += 64) {
    const float x = X[(size_t)gw * K + k];
    a0 = fmaf(x, swr[k * 4 + 0], a0);
    a1 = fmaf(x, swr[k * 4 + 1], a1);
    a2 = fmaf(x, swr[k * 4 + 2], a2);
    a3 = fmaf(x, swr[k * 4 + 3], a3);
  }
#pragma unroll
  for (int o = 32; o; o >>= 1) {
    a0 += __shfl_xor(a0, o);
    a1 += __shfl_xor(a1, o);
    a2 += __shfl_xor(a2, o);
    a3 += __shfl_xor(a3, o);
  }
  if (lane == 0) {
    er[gw * 4 + 0] = a0; er[gw * 4 + 1] = a1;
    er[gw * 4 + 2] = a2; er[gw * 4 + 3] = a3;
  }
}

// ------------- CSR build -------------
__global__ void count_kernel(const int* __restrict__ dst, int* __restrict__ cnt, int E) {
  for (int i = blockIdx.x * blockDim.x + threadIdx.x; i < E; i += gridDim.x * blockDim.x)
    atomicAdd(&cnt[dst[i]], 1);
}

__global__ __launch_bounds__(256) void scan_reduce_kernel(
    const int* __restrict__ data, int* __restrict__ bsum, int n) {
  const int base = blockIdx.x * 1024;
  int s = 0;
  for (int i = threadIdx.x; i < 1024; i += 256) {
    const int idx = base + i;
    s += (idx < n) ? data[idx] : 0;
  }
#pragma unroll
  for (int o = 32; o; o >>= 1) s += __shfl_xor(s, o);
  __shared__ int ws[4];
  if ((threadIdx.x & 63) == 0) ws[threadIdx.x >> 6] = s;
  __syncthreads();
  if (threadIdx.x == 0) bsum[blockIdx.x] = ws[0] + ws[1] + ws[2] + ws[3];
}

__global__ __launch_bounds__(1024) void scan_blocksums_kernel(
    int* __restrict__ bsum, int nb) {
  __shared__ int sm[1024];
  const int t = threadIdx.x;
  const int v = (t < nb) ? bsum[t] : 0;
  sm[t] = v;
  __syncthreads();
  for (int ofs = 1; ofs < 1024; ofs <<= 1) {
    const int tmp = (t >= ofs) ? sm[t - ofs] : 0;
    __syncthreads();
    sm[t] += tmp;
    __syncthreads();
  }
  if (t < nb) bsum[t] = sm[t] - v;
}

__global__ __launch_bounds__(1024) void scan_final_kernel(
    int* __restrict__ data, const int* __restrict__ bsum, int n) {
  __shared__ int sm[1024];
  const int t = threadIdx.x;
  const int i = blockIdx.x * 1024 + t;
  const int v = (i < n) ? data[i] : 0;
  sm[t] = v;
  __syncthreads();
  for (int ofs = 1; ofs < 1024; ofs <<= 1) {
    const int tmp = (t >= ofs) ? sm[t - ofs] : 0;
    __syncthreads();
    sm[t] += tmp;
    __syncthreads();
  }
  const int c = bsum[blockIdx.x];
  if (i < n) data[i] = c + sm[t] - v;
  if (i == n - 1) data[n] = c + sm[t];
}

__global__ void fill_kernel(const int* __restrict__ src, const int* __restrict__ dst,
                            const int* __restrict__ off, int* __restrict__ cursor,
                            int* __restrict__ csrsrc, int E) {
  for (int i = blockIdx.x * blockDim.x + threadIdx.x; i < E; i += gridDim.x * blockDim.x) {
    const int d = dst[i];
    const int p = atomicAdd(&cursor[d], 1);
    csrsrc[off[d] + p] = src[i];
  }
}

// ------------- GAT aggregation: bf16 gather, 8-edge batches, fused bias+relu -------------
__global__ __launch_bounds__(256) void gat_aggregate(
    const bf16* __restrict__ Fb, const float* __restrict__ el,
    const float* __restrict__ er, const int* __restrict__ off,
    const int* __restrict__ csrsrc, float* __restrict__ out,
    int n_dst, int add_flag,
    const float* __restrict__ bias1, const float* __restrict__ bias2, int do_relu) {
  const short* Fp = (const short*)Fb;
  const int lane = threadIdx.x & 63;
  const int myh = lane >> 4;
  const int gw = (blockIdx.x * blockDim.x + threadIdx.x) >> 6;
  if (gw >= n_dst) return;
  const int s0 = off[gw], s1 = off[gw + 1];
  const float ern = er[gw * 4 + myh];
  float4 acc = {0.f, 0.f, 0.f, 0.f};
  float ssum = 0.f;
  for (int p = s0; p < s1; p += 8) {
    const int nb = s1 - p;
    int srcs[8];
#pragma unroll
    for (int b = 0; b < 8; ++b) {
      const int q = (b < nb) ? b : nb - 1;
      srcs[b] = csrsrc[p + q];
    }
    float w8[8];
#pragma unroll
    for (int b = 0; b < 8; ++b) {
      float e = el[srcs[b] * 4 + myh] + ern;
      e = e > 0.f ? e : 0.2f * e;
      w8[b] = (b < nb) ? expf(e) : 0.f;
    }
    short4v f8[8];
#pragma unroll
    for (int b = 0; b < 8; ++b)
      f8[b] = *reinterpret_cast<const short4v*>(&Fp[(size_t)srcs[b] * 256 + lane * 4]);
#pragma unroll
    for (int b = 0; b < 8; ++b) {
      ssum += w8[b];
      acc.x = fmaf(w8[b], bits2f(f8[b][0]), acc.x);
      acc.y = fmaf(w8[b], bits2f(f8[b][1]), acc.y);
      acc.z = fmaf(w8[b], bits2f(f8[b][2]), acc.z);
      acc.w = fmaf(w8[b], bits2f(f8[b][3]), acc.w);
    }
  }
  const float inv = ssum > 0.f ? 1.f / ssum : 0.f;
  float4 res = {acc.x * inv, acc.y * inv, acc.z * inv, acc.w * inv};
  float4* po = reinterpret_cast<float4*>(&out[(size_t)gw * 256 + lane * 4]);
  if (add_flag) {
    const float4 prev = *po;
    res.x += prev.x; res.y += prev.y; res.z += prev.z; res.w += prev.w;
  }
  if (bias1) {
    float4 bb = *reinterpret_cast<const float4*>(&bias1[lane * 4]);
    if (bias2) {
      const float4 b2 = *reinterpret_cast<const float4*>(&bias2[lane * 4]);
      bb.x += b2.x; bb.y += b2.y; bb.z += b2.z; bb.w += b2.w;
    }
    res.x += bb.x; res.y += bb.y; res.z += bb.z; res.w += bb.w;
  }
  if (do_relu) {
    res.x = fmaxf(res.x, 0.f); res.y = fmaxf(res.y, 0.f);
    res.z = fmaxf(res.z, 0.f); res.w = fmaxf(res.w, 0.f);
  }
  *po = res;
}

// ---------- graph readout stage 1 ----------
__global__ __launch_bounds__(256) void graph_sum_v3(
    const float* __restrict__ h, const int* __restrict__ gid,
    float* __restrict__ pbuf, int n) {
  __shared__ float sm[NGRAPH * 256];
  const int t = threadIdx.x;
  for (int i = t; i < NGRAPH * 256; i += 256) sm[i] = 0.f;
  __syncthreads();
  const int chunk = (n + RD_STRIPES - 1) / RD_STRIPES;
  const int lo = blockIdx.x * chunk;
  const int hiN = min(n, lo + chunk);
#pragma unroll 8
  for (int node = lo; node < hiN; ++node) {
    const int g = gid[node];
    const float v = h[(size_t)node * 256 + t];
    sm[g * 256 + t] += v;
  }
  __syncthreads();
  float* dst = pbuf + (size_t)blockIdx.x * (NGRAPH * 256);
  for (int i = t; i < NGRAPH * 256; i += 256) dst[i] = sm[i];
}

// ---------- graph readout stage 2 ----------
__global__ __launch_bounds__(256) void graph_reduce_kernel(
    const float* __restrict__ pbuf, float* __restrict__ gsum, int colofs) {
  const int g = blockIdx.x, t = threadIdx.x;
  float acc = 0.f;
#pragma unroll 8
  for (int s = 0; s < RD_STRIPES; ++s)
    acc += pbuf[(size_t)s * (NGRAPH * 256) + g * 256 + t];
  gsum[(size_t)g * 512 + colofs + t] = acc;
}

// ---------- graph node-count ----------
__global__ __launch_bounds__(256) void graph_count_kernel(
    const int* __restrict__ gid, int* __restrict__ gcnt, int n, int cntofs) {
  __shared__ int c[NGRAPH];
  if (threadIdx.x < NGRAPH) c[threadIdx.x] = 0;
  __syncthreads();
  for (int i = blockIdx.x * blockDim.x + threadIdx.x; i < n; i += gridDim.x * blockDim.x)
    atomicAdd(&c[gid[i]], 1);
  __syncthreads();
  if (threadIdx.x < NGRAPH && c[threadIdx.x])
    atomicAdd(&gcnt[cntofs + threadIdx.x], c[threadIdx.x]);
}

// ---------- final MLP ----------
__global__ __launch_bounds__(256) void mlp_kernel(
    const float* __restrict__ gsum, const int* __restrict__ gcnt,
    const float* __restrict__ Wm, const float* __restrict__ bm,
    float* __restrict__ out) {
  __shared__ float g[512];
  const int b = blockIdx.x, t = threadIdx.x;
  const float cl = fmaxf((float)gcnt[b], 1.f);
  const float cp = fmaxf((float)gcnt[64 + b], 1.f);
  for (int k = t; k < 512; k += 256)
    g[k] = gsum[(size_t)b * 512 + k] * (k < 256 ? 1.f / cl : 1.f / cp);
  __syncthreads();
  float acc = bm[t];
  for (int k = 0; k < 512; ++k) acc = fmaf(g[k], Wm[(size_t)k * 256 + t], acc);
  out[b * 256 + t] = fmaxf(acc, 0.f);
}

// =====================================================================
extern "C" void kernel_launch(void* const* d_in, const int* in_sizes, int n_in,
                              void* d_out, int out_size, void* d_ws, size_t ws_size,
                              hipStream_t stream) {
  const float* x_lig  = (const float*)d_in[0];
  const float* x_pro  = (const float*)d_in[1];
  const float* W1_ll  = (const float*)d_in[2];
  const float* al1_ll = (const float*)d_in[3];
  const float* ar1_ll = (const float*)d_in[4];
  const float* b1_ll  = (const float*)d_in[5];
  const float* W1_lps = (const float*)d_in[6];
  const float* W1_lpd = (const float*)d_in[7];
  const float* al1_lp = (const float*)d_in[8];
  const float* ar1_lp = (const float*)d_in[9];
  const float* b1_lp  = (const float*)d_in[10];
  const float* W1_pls = (const float*)d_in[11];
  const float* W1_pld = (const float*)d_in[12];
  const float* al1_pl = (const float*)d_in[13];
  const float* ar1_pl = (const float*)d_in[14];
  const float* b1_pl  = (const float*)d_in[15];
  const float* W2_ll  = (const float*)d_in[16];
  const float* al2_ll = (const float*)d_in[17];
  const float* ar2_ll = (const float*)d_in[18];
  const float* b2_ll  = (const float*)d_in[19];
  const float* W2_lps = (const float*)d_in[20];
  const float* W2_lpd = (const float*)d_in[21];
  const float* al2_lp = (const float*)d_in[22];
  const float* ar2_lp = (const float*)d_in[23];
  const float* b2_lp  = (const float*)d_in[24];
  const float* W2_pls = (const float*)d_in[25];
  const float* W2_pld = (const float*)d_in[26];
  const float* al2_pl = (const float*)d_in[27];
  const float* ar2_pl = (const float*)d_in[28];
  const float* b2_pl  = (const float*)d_in[29];
  const float* W_mlp  = (const float*)d_in[30];
  const float* b_mlp  = (const float*)d_in[31];
  const int* src_ll   = (const int*)d_in[32];
  const int* dst_ll   = (const int*)d_in[33];
  const int* src_lp   = (const int*)d_in[34];
  const int* dst_lp   = (const int*)d_in[35];
  const int* src_pl   = (const int*)d_in[36];
  const int* dst_pl   = (const int*)d_in[37];
  const int* gid_lig  = (const int*)d_in[38];
  const int* gid_pro  = (const int*)d_in[39];
  float* out = (float*)d_out;
  (void)in_sizes; (void)n_in; (void)out_size; (void)ws_size;

  // -------- workspace carving --------
  size_t cur = 0;
  auto carve = [&](size_t bytes) -> char* {
    char* p = (char*)d_ws + cur;
    cur += (bytes + 511) & ~(size_t)511;
    return p;
  };
  const size_t NB = (size_t)40000 * 256 * sizeof(float);  // 40.96 MB
  bf16* Fb    = (bf16*)carve(NB);    // bf16 F (half used); pbuf overlay later
  float* h_l  = (float*)carve(NB);   // later: S2 bf16 staging (conv of h_p)
  float* h_p  = (float*)carve(NB);
  float* hX   = (float*)carve(NB);   // h_l2
  char*  S    = carve(NB);           // L1: XL/XP staging; L2: S1; then P2 (h_p2)
  float* el   = (float*)carve((size_t)40000 * 4 * sizeof(float));
  float* er   = (float*)carve((size_t)40000 * 4 * sizeof(float));
  float* erPL = (float*)carve((size_t)40000 * 4 * sizeof(float));
  float* erLP = (float*)carve((size_t)40000 * 4 * sizeof(float));
  float* wr   = (float*)carve((size_t)256 * 4 * sizeof(float));
  bf16* Bthi  = (bf16*)carve((size_t)256 * 256 * sizeof(bf16));
  bf16* Btlo  = (bf16*)carve((size_t)256 * 256 * sizeof(bf16));
  float* gsum = (float*)carve((size_t)64 * 512 * sizeof(float));
  int* gcnt   = (int*)carve(128 * sizeof(int));
  int* bsum   = (int*)carve(1025 * sizeof(int));
  int* off_ll = (int*)carve((NLIG + 1) * sizeof(int));
  int* off_lp = (int*)carve((NPRO + 1) * sizeof(int));
  int* off_pl = (int*)carve((NLIG + 1) * sizeof(int));
  int* cursor = (int*)carve((NLIG + 1) * sizeof(int));
  int* csr_ll = (int*)carve((size_t)ELL * sizeof(int));
  int* csr_lp = (int*)carve((size_t)ELP * sizeof(int));
  int* csr_pl = (int*)carve((size_t)EPL * sizeof(int));

  // staging sub-pointers
  bf16* XLhi = (bf16*)S;
  bf16* XLlo = XLhi + (size_t)40000 * 96;
  bf16* XPhi = XLlo + (size_t)40000 * 96;
  bf16* XPlo = XPhi + (size_t)40000 * 128;
  bf16* S1hi = (bf16*)S;
  bf16* S1lo = S1hi + (size_t)40000 * 256;
  float* P2  = (float*)S;
  bf16* S2hi = (bf16*)h_l;
  bf16* S2lo = S2hi + (size_t)40000 * 256;
  float* pbuf = (float*)Fb;   // 16 MB readout partials (Fb dead by then)

  const int B256 = 256;
  auto thrGrid  = [](long long n) { return (int)((n + 255) / 256); };
  auto waveGrid = [](int n) { return (n + 3) / 4; };

  auto conv_a = [&](const float* A, bf16* hi, bf16* lo, int M, int K, int Kp) {
    convA_kernel<<<(M + 7) / 8, B256, 0, stream>>>(A, hi, lo, M, K, Kp);
  };
  auto run_mfma = [&](const bf16* ahi, const bf16* alo, const float* W, int K, int Kp,
                      bf16* C, int M, const float* alv, float* elp,
                      const float* arv, float* erp) {
    convBt_kernel<<<256, B256, 0, stream>>>(W, Bthi, Btlo, K, Kp);
    dim3 g((M + 127) / 128, 2);
    mfma_gemm<<<g, B256, 0, stream>>>(ahi, alo, Bthi, Btlo, C, M, Kp, alv, elp, arv, erp);
  };
  auto run_er_gemv = [&](const float* Wd, const float* arv, const float* X,
                         float* dst_er, int n, int K) {
    make_wr_kernel<<<(K * 4 + 255) / 256, B256, 0, stream>>>(Wd, arv, wr, K);
    er_gemv_kernel<<<waveGrid(n), B256, 0, stream>>>(X, wr, dst_er, n, K);
  };
  auto run_agg = [&](const int* off, const int* csr, int nDst, float* outbuf, int addf,
                     const float* erp, const float* bias1, const float* bias2, int relu) {
    gat_aggregate<<<waveGrid(nDst), B256, 0, stream>>>(
        Fb, el, erp, off, csr, outbuf, nDst, addf, bias1, bias2, relu);
  };
  auto run_scan = [&](int* data, int n) {
    const int nb = (n + 1023) / 1024;
    scan_reduce_kernel<<<nb, B256, 0, stream>>>(data, bsum, n);
    scan_blocksums_kernel<<<1, 1024, 0, stream>>>(bsum, nb);
    scan_final_kernel<<<nb, 1024, 0, stream>>>(data, bsum, n);
  };

  // -------- CSR builds --------
  struct Rel { const int* src; const int* dst; int* off; int* csr; int E; int Nd; };
  Rel rels[3] = {
    {src_ll, dst_ll, off_ll, csr_ll, ELL, NLIG},
    {src_lp, dst_lp, off_lp, csr_lp, ELP, NPRO},
    {src_pl, dst_pl, off_pl, csr_pl, EPL, NLIG},
  };
  for (int r = 0; r < 3; ++r) {
    hipMemsetAsync(rels[r].off, 0, (rels[r].Nd + 1) * sizeof(int), stream);
    count_kernel<<<thrGrid(rels[r].E), B256, 0, stream>>>(rels[r].dst, rels[r].off, rels[r].E);
    run_scan(rels[r].off, rels[r].Nd);
    hipMemsetAsync(cursor, 0, (rels[r].Nd + 1) * sizeof(int), stream);
    fill_kernel<<<thrGrid(rels[r].E), B256, 0, stream>>>(
        rels[r].src, rels[r].dst, rels[r].off, cursor, rels[r].csr, rels[r].E);
  }

  // ================= LAYER 1 =================
  conv_a(x_lig, XLhi, XLlo, NLIG, 74, 96);
  conv_a(x_pro, XPhi, XPlo, NPRO, 128, 128);
  // ll
  run_mfma(XLhi, XLlo, W1_ll, 74, 96, Fb, NLIG, al1_ll, el, ar1_ll, er);
  run_agg(off_ll, csr_ll, NLIG, h_l, 0, er, nullptr, nullptr, 0);
  // pl (final pass for h_l: fuse b1_ll + b1_pl + relu)
  run_er_gemv(W1_pld, ar1_pl, x_lig, er, NLIG, 74);
  run_mfma(XPhi, XPlo, W1_pls, 128, 128, Fb, NPRO, al1_pl, el, nullptr, nullptr);
  run_agg(off_pl, csr_pl, NLIG, h_l, 1, er, b1_ll, b1_pl, 1);
  // lp (single pass for h_p: fuse b1_lp + relu)
  run_er_gemv(W1_lpd, ar1_lp, x_pro, er, NPRO, 128);
  run_mfma(XLhi, XLlo, W1_lps, 74, 96, Fb, NLIG, al1_lp, el, nullptr, nullptr);
  run_agg(off_lp, csr_lp, NPRO, h_p, 0, er, b1_lp, nullptr, 1);

  // ================= LAYER 2 =================
  run_er_gemv(W2_pld, ar2_pl, h_l, erPL, NLIG, 256);
  run_er_gemv(W2_lpd, ar2_lp, h_p, erLP, NPRO, 256);
  conv_a(h_l, S1hi, S1lo, NLIG, 256, 256);
  // ll
  run_mfma(S1hi, S1lo, W2_ll, 256, 256, Fb, NLIG, al2_ll, el, ar2_ll, er);
  run_agg(off_ll, csr_ll, NLIG, hX, 0, er, nullptr, nullptr, 0);
  // lp (src h_l via S1); after this mfma S1 dead -> P2 overlays it
  run_mfma(S1hi, S1lo, W2_lps, 256, 256, Fb, NLIG, al2_lp, el, nullptr, nullptr);
  run_agg(off_lp, csr_lp, NPRO, P2, 0, erLP, b2_lp, nullptr, 1);
  // conv h_p -> S2 (overlays h_l region)
  conv_a(h_p, S2hi, S2lo, NPRO, 256, 256);
  // pl (final pass for hX: fuse b2_ll + b2_pl + relu)
  run_mfma(S2hi, S2lo, W2_pls, 256, 256, Fb, NPRO, al2_pl, el, nullptr, nullptr);
  run_agg(off_pl, csr_pl, NLIG, hX, 1, erPL, b2_ll, b2_pl, 1);

  // ================= READOUT (Fb dead -> pbuf) + MLP =================
  hipMemsetAsync(gcnt, 0, 128 * sizeof(int), stream);
  graph_sum_v3<<<RD_STRIPES, B256, 0, stream>>>(hX, gid_lig, pbuf, NLIG);
  graph_reduce_kernel<<<NGRAPH, B256, 0, stream>>>(pbuf, gsum, 0);
  graph_count_kernel<<<64, B256, 0, stream>>>(gid_lig, gcnt, NLIG, 0);
  graph_sum_v3<<<RD_STRIPES, B256, 0, stream>>>(P2, gid_pro, pbuf, NPRO);
  graph_reduce_kernel<<<NGRAPH, B256, 0, stream>>>(pbuf, gsum, 256);
  graph_count_kernel<<<64, B256, 0, stream>>>(gid_pro, gcnt, NPRO, 64);
  mlp_kernel<<<64, B256, 0, stream>>>(gsum, gcnt, W_mlp, b_mlp, out);
}

// Round 14
// 637.228 us; speedup vs baseline: 16.3721x; 1.0887x over previous
//
#include <hip/hip_runtime.h>
#include <hip/hip_bf16.h>

#define NLIG 40000
#define NPRO 40000
#define NGRAPH 64
#define ELL 160000
#define ELP 240000
#define EPL 240000

#define RD_STRIPES 256

typedef __hip_bfloat16 bf16;
typedef __attribute__((ext_vector_type(8))) short short8;
typedef __attribute__((ext_vector_type(4))) short short4v;
typedef __attribute__((ext_vector_type(4))) float f32x4;

__device__ __forceinline__ float bits2f(short s) {
  const unsigned u = ((unsigned)(unsigned short)s) << 16;
  return __uint_as_float(u);
}

// ---------- convA: f32 [M,K] -> bf16 hi/lo [M,Kp], zero-padded ----------
__global__ __launch_bounds__(256) void convA_kernel(
    const float* __restrict__ A, bf16* __restrict__ hi, bf16* __restrict__ lo,
    int M, int K, int Kp) {
  const int row = blockIdx.x * 8 + (threadIdx.x >> 5);
  if (row >= M) return;
  const int Kp4 = Kp >> 2;
  short* hp = (short*)hi;
  short* lq = (short*)lo;
  for (int c4 = threadIdx.x & 31; c4 < Kp4; c4 += 32) {
    const int k = c4 << 2;
    float v[4];
#pragma unroll
    for (int j = 0; j < 4; ++j) {
      const int kk = k + j;
      v[j] = (kk < K) ? A[(size_t)row * K + kk] : 0.f;
    }
    short4v hv, lv;
#pragma unroll
    for (int j = 0; j < 4; ++j) {
      bf16 h = __float2bfloat16(v[j]);
      float r = v[j] - __bfloat162float(h);
      bf16 l = __float2bfloat16(r);
      hv[j] = *reinterpret_cast<short*>(&h);
      lv[j] = *reinterpret_cast<short*>(&l);
    }
    *reinterpret_cast<short4v*>(&hp[(size_t)row * Kp + k]) = hv;
    *reinterpret_cast<short4v*>(&lq[(size_t)row * Kp + k]) = lv;
  }
}

// ---------- convBt: f32 B[K,256] -> bf16 hi/lo transposed [256,Kp] ----------
__global__ __launch_bounds__(256) void convBt_kernel(
    const float* __restrict__ B, bf16* __restrict__ thi, bf16* __restrict__ tlo,
    int K, int Kp) {
  const int tot = 256 * Kp;
  for (int i = blockIdx.x * 256 + threadIdx.x; i < tot; i += gridDim.x * 256) {
    const int n = i / Kp, k = i % Kp;
    float v = (k < K) ? B[(size_t)k * 256 + n] : 0.f;
    bf16 h = __float2bfloat16(v);
    float r = v - __bfloat162float(h);
    thi[i] = h;
    tlo[i] = __float2bfloat16(r);
  }
}

// ---------- MFMA GEMM: C_bf16[M,256] = A[M,Kp] @ B[Kp,256] (split bf16 inputs) ----------
#define LP 40
__global__ __launch_bounds__(256) void mfma_gemm(
    const bf16* __restrict__ AhiP, const bf16* __restrict__ AloP,
    const bf16* __restrict__ BthiP, const bf16* __restrict__ BtloP,
    bf16* __restrict__ C, int M, int Kp,
    const float* __restrict__ al, float* __restrict__ el,
    const float* __restrict__ ar, float* __restrict__ er) {
  __shared__ short sA[2][128 * LP];
  __shared__ short sB[2][128 * LP];
  const short* Ahi = (const short*)AhiP;
  const short* Alo = (const short*)AloP;
  const short* Bthi = (const short*)BthiP;
  const short* Btlo = (const short*)BtloP;
  const int t = threadIdx.x;
  const int w = t >> 6, l = t & 63;
  const int m0 = blockIdx.x * 128;
  const int n0 = blockIdx.y * 128;
  const f32x4 zf = {0.f, 0.f, 0.f, 0.f};
  const short8 zs = {0, 0, 0, 0, 0, 0, 0, 0};
  f32x4 acc[2][8];
#pragma unroll
  for (int i = 0; i < 2; ++i)
#pragma unroll
    for (int j = 0; j < 8; ++j) acc[i][j] = zf;

  const int fr = l & 15, kg = l >> 4;

  for (int k0 = 0; k0 < Kp; k0 += 32) {
#pragma unroll
    for (int rep = 0; rep < 2; ++rep) {
      const int p = t + rep * 256;
      const int row = p >> 2, c = p & 3;
      const int gr = m0 + row;
      short8 vh = zs, vl = zs;
      if (gr < M) {
        const size_t g = (size_t)gr * Kp + k0 + c * 8;
        vh = *(const short8*)(Ahi + g);
        vl = *(const short8*)(Alo + g);
      }
      *(short8*)(&sA[0][row * LP + c * 8]) = vh;
      *(short8*)(&sA[1][row * LP + c * 8]) = vl;
    }
#pragma unroll
    for (int rep = 0; rep < 2; ++rep) {
      const int p = t + rep * 256;
      const int row = p >> 2, c = p & 3;
      const size_t g = (size_t)(n0 + row) * Kp + k0 + c * 8;
      *(short8*)(&sB[0][row * LP + c * 8]) = *(const short8*)(Bthi + g);
      *(short8*)(&sB[1][row * LP + c * 8]) = *(const short8*)(Btlo + g);
    }
    __syncthreads();
    short8 aF[2][2];
#pragma unroll
    for (int i = 0; i < 2; ++i) {
      const int r = (w * 32 + i * 16 + fr) * LP + kg * 8;
      aF[0][i] = *(const short8*)(&sA[0][r]);
      aF[1][i] = *(const short8*)(&sA[1][r]);
    }
#pragma unroll
    for (int j = 0; j < 8; ++j) {
      const int r = (j * 16 + fr) * LP + kg * 8;
      const short8 b0 = *(const short8*)(&sB[0][r]);
      const short8 b1 = *(const short8*)(&sB[1][r]);
#pragma unroll
      for (int i = 0; i < 2; ++i) {
        acc[i][j] = __builtin_amdgcn_mfma_f32_16x16x32_bf16(aF[0][i], b0, acc[i][j], 0, 0, 0);
        acc[i][j] = __builtin_amdgcn_mfma_f32_16x16x32_bf16(aF[0][i], b1, acc[i][j], 0, 0, 0);
        acc[i][j] = __builtin_amdgcn_mfma_f32_16x16x32_bf16(aF[1][i], b0, acc[i][j], 0, 0, 0);
      }
    }
    __syncthreads();
  }

#pragma unroll
  for (int i = 0; i < 2; ++i) {
    const int rbase = m0 + w * 32 + i * 16 + kg * 4;
#pragma unroll
    for (int j = 0; j < 8; ++j) {
      const int col = n0 + j * 16 + fr;
#pragma unroll
      for (int r = 0; r < 4; ++r) {
        const int row = rbase + r;
        if (row < M) C[(size_t)row * 256 + col] = __float2bfloat16(acc[i][j][r]);
      }
    }
  }

  if (el) {
    float alv[8], arv[8];
#pragma unroll
    for (int j = 0; j < 8; ++j) {
      alv[j] = al[n0 + j * 16 + fr];
      arv[j] = er ? ar[n0 + j * 16 + fr] : 0.f;
    }
    const int hb = n0 >> 6;
#pragma unroll
    for (int i = 0; i < 2; ++i) {
#pragma unroll
      for (int r = 0; r < 4; ++r) {
        float sl0 = 0.f, sl1 = 0.f, sr0 = 0.f, sr1 = 0.f;
#pragma unroll
        for (int j = 0; j < 4; ++j) {
          sl0 = fmaf(acc[i][j][r], alv[j], sl0);
          sr0 = fmaf(acc[i][j][r], arv[j], sr0);
          sl1 = fmaf(acc[i][j + 4][r], alv[j + 4], sl1);
          sr1 = fmaf(acc[i][j + 4][r], arv[j + 4], sr1);
        }
        sl0 += __shfl_xor(sl0, 1); sl0 += __shfl_xor(sl0, 2);
        sl0 += __shfl_xor(sl0, 4); sl0 += __shfl_xor(sl0, 8);
        sl1 += __shfl_xor(sl1, 1); sl1 += __shfl_xor(sl1, 2);
        sl1 += __shfl_xor(sl1, 4); sl1 += __shfl_xor(sl1, 8);
        sr0 += __shfl_xor(sr0, 1); sr0 += __shfl_xor(sr0, 2);
        sr0 += __shfl_xor(sr0, 4); sr0 += __shfl_xor(sr0, 8);
        sr1 += __shfl_xor(sr1, 1); sr1 += __shfl_xor(sr1, 2);
        sr1 += __shfl_xor(sr1, 4); sr1 += __shfl_xor(sr1, 8);
        const int row = m0 + w * 32 + i * 16 + kg * 4 + r;
        if (fr == 0 && row < M) {
          el[row * 4 + hb] = sl0;
          el[row * 4 + hb + 1] = sl1;
          if (er) {
            er[row * 4 + hb] = sr0;
            er[row * 4 + hb + 1] = sr1;
          }
        }
      }
    }
  }
}

// ------------- make_wr: wr[k,h] = sum_d Wd[k,h*64+d]*ar[h*64+d] -------------
__global__ void make_wr_kernel(const float* __restrict__ Wd,
                               const float* __restrict__ ar,
                               float* __restrict__ wr, int K) {
  const int t = blockIdx.x * blockDim.x + threadIdx.x;
  if (t < K * 4) {
    const int k = t >> 2, h = t & 3;
    float s = 0.f;
    for (int d = 0; d < 64; ++d)
      s = fmaf(Wd[(size_t)k * 256 + h * 64 + d], ar[h * 64 + d], s);
    wr[t] = s;
  }
}

// ------------- er gemv (layer-1 only, reads raw f32 inputs) -------------
__global__ __launch_bounds__(256) void er_gemv_kernel(
    const float* __restrict__ X, const float* __restrict__ wr,
    float* __restrict__ er, int n, int K) {
  __shared__ float swr[1024];
  const int t = threadIdx.x;
  for (int i = t; i < K * 4; i += blockDim.x) swr[i] = wr[i];
  __syncthreads();
  const int lane = t & 63;
  const int gw = (blockIdx.x * blockDim.x + t) >> 6;
  if (gw >= n) return;
  float a0 = 0.f, a1 = 0.f, a2 = 0.f, a3 = 0.f;
  for (int k = lane; k < K; k += 64) {
    const float x = X[(size_t)gw * K + k];
    a0 = fmaf(x, swr[k * 4 + 0], a0);
    a1 = fmaf(x, swr[k * 4 + 1], a1);
    a2 = fmaf(x, swr[k * 4 + 2], a2);
    a3 = fmaf(x, swr[k * 4 + 3], a3);
  }
#pragma unroll
  for (int o = 32; o; o >>= 1) {
    a0 += __shfl_xor(a0, o);
    a1 += __shfl_xor(a1, o);
    a2 += __shfl_xor(a2, o);
    a3 += __shfl_xor(a3, o);
  }
  if (lane == 0) {
    er[gw * 4 + 0] = a0; er[gw * 4 + 1] = a1;
    er[gw * 4 + 2] = a2; er[gw * 4 + 3] = a3;
  }
}

// ------------- CSR build -------------
__global__ void count_kernel(const int* __restrict__ dst, int* __restrict__ cnt, int E) {
  for (int i = blockIdx.x * blockDim.x + threadIdx.x; i < E; i += gridDim.x * blockDim.x)
    atomicAdd(&cnt[dst[i]], 1);
}

__global__ __launch_bounds__(256) void scan_reduce_kernel(
    const int* __restrict__ data, int* __restrict__ bsum, int n) {
  const int base = blockIdx.x * 1024;
  int s = 0;
  for (int i = threadIdx.x; i < 1024; i += 256) {
    const int idx = base + i;
    s += (idx < n) ? data[idx] : 0;
  }
#pragma unroll
  for (int o = 32; o; o >>= 1) s += __shfl_xor(s, o);
  __shared__ int ws[4];
  if ((threadIdx.x & 63) == 0) ws[threadIdx.x >> 6] = s;
  __syncthreads();
  if (threadIdx.x == 0) bsum[blockIdx.x] = ws[0] + ws[1] + ws[2] + ws[3];
}

__global__ __launch_bounds__(1024) void scan_blocksums_kernel(
    int* __restrict__ bsum, int nb) {
  __shared__ int sm[1024];
  const int t = threadIdx.x;
  const int v = (t < nb) ? bsum[t] : 0;
  sm[t] = v;
  __syncthreads();
  for (int ofs = 1; ofs < 1024; ofs <<= 1) {
    const int tmp = (t >= ofs) ? sm[t - ofs] : 0;
    __syncthreads();
    sm[t] += tmp;
    __syncthreads();
  }
  if (t < nb) bsum[t] = sm[t] - v;
}

__global__ __launch_bounds__(1024) void scan_final_kernel(
    int* __restrict__ data, const int* __restrict__ bsum, int n) {
  __shared__ int sm[1024];
  const int t = threadIdx.x;
  const int i = blockIdx.x * 1024 + t;
  const int v = (i < n) ? data[i] : 0;
  sm[t] = v;
  __syncthreads();
  for (int ofs = 1; ofs < 1024; ofs <<= 1) {
    const int tmp = (t >= ofs) ? sm[t - ofs] : 0;
    __syncthreads();
    sm[t] += tmp;
    __syncthreads();
  }
  const int c = bsum[blockIdx.x];
  if (i < n) data[i] = c + sm[t] - v;
  if (i == n - 1) data[n] = c + sm[t];
}

__global__ void fill_kernel(const int* __restrict__ src, const int* __restrict__ dst,
                            const int* __restrict__ off, int* __restrict__ cursor,
                            int* __restrict__ csrsrc, int E) {
  for (int i = blockIdx.x * blockDim.x + threadIdx.x; i < E; i += gridDim.x * blockDim.x) {
    const int d = dst[i];
    const int p = atomicAdd(&cursor[d], 1);
    csrsrc[off[d] + p] = src[i];
  }
}

// ------------- per-relation edge walk (8-edge batches, bf16 gather) -------------
__device__ __forceinline__ float4 agg_walk(
    const short* __restrict__ Fp, const float* __restrict__ el, float ern,
    const int* __restrict__ csr, int s0, int s1, int myh, int lane) {
  float4 acc = {0.f, 0.f, 0.f, 0.f};
  float ssum = 0.f;
  for (int p = s0; p < s1; p += 8) {
    const int nb = s1 - p;
    int srcs[8];
#pragma unroll
    for (int b = 0; b < 8; ++b) {
      const int q = (b < nb) ? b : nb - 1;
      srcs[b] = csr[p + q];
    }
    float w8[8];
#pragma unroll
    for (int b = 0; b < 8; ++b) {
      float e = el[srcs[b] * 4 + myh] + ern;
      e = e > 0.f ? e : 0.2f * e;
      w8[b] = (b < nb) ? expf(e) : 0.f;
    }
    short4v f8[8];
#pragma unroll
    for (int b = 0; b < 8; ++b)
      f8[b] = *reinterpret_cast<const short4v*>(&Fp[(size_t)srcs[b] * 256 + lane * 4]);
#pragma unroll
    for (int b = 0; b < 8; ++b) {
      ssum += w8[b];
      acc.x = fmaf(w8[b], bits2f(f8[b][0]), acc.x);
      acc.y = fmaf(w8[b], bits2f(f8[b][1]), acc.y);
      acc.z = fmaf(w8[b], bits2f(f8[b][2]), acc.z);
      acc.w = fmaf(w8[b], bits2f(f8[b][3]), acc.w);
    }
  }
  const float inv = ssum > 0.f ? 1.f / ssum : 0.f;
  float4 r = {acc.x * inv, acc.y * inv, acc.z * inv, acc.w * inv};
  return r;
}

// ------------- fused GAT aggregate: 1-2 relations, bias+relu, f32 or bf16-split
// output, optional fused er-dot for next layer -------------
__global__ __launch_bounds__(256) void gat_agg_fused(
    const bf16* __restrict__ F1, const float* __restrict__ el1,
    const float* __restrict__ er1, const int* __restrict__ off1,
    const int* __restrict__ csr1,
    const bf16* __restrict__ F2, const float* __restrict__ el2,
    const float* __restrict__ er2, const int* __restrict__ off2,
    const int* __restrict__ csr2,
    const float* __restrict__ bias1, const float* __restrict__ bias2,
    float* __restrict__ outF, bf16* __restrict__ outHi, bf16* __restrict__ outLo,
    const float* __restrict__ wr2, float* __restrict__ erOut,
    int n_dst) {
  const int lane = threadIdx.x & 63;
  const int myh = lane >> 4;
  const int gw = (blockIdx.x * blockDim.x + threadIdx.x) >> 6;
  if (gw >= n_dst) return;

  float4 res = agg_walk((const short*)F1, el1, er1[gw * 4 + myh],
                        csr1, off1[gw], off1[gw + 1], myh, lane);
  if (F2) {
    const float4 r2 = agg_walk((const short*)F2, el2, er2[gw * 4 + myh],
                               csr2, off2[gw], off2[gw + 1], myh, lane);
    res.x += r2.x; res.y += r2.y; res.z += r2.z; res.w += r2.w;
  }
  {
    float4 bb = *reinterpret_cast<const float4*>(&bias1[lane * 4]);
    if (bias2) {
      const float4 b2 = *reinterpret_cast<const float4*>(&bias2[lane * 4]);
      bb.x += b2.x; bb.y += b2.y; bb.z += b2.z; bb.w += b2.w;
    }
    res.x = fmaxf(res.x + bb.x, 0.f);
    res.y = fmaxf(res.y + bb.y, 0.f);
    res.z = fmaxf(res.z + bb.z, 0.f);
    res.w = fmaxf(res.w + bb.w, 0.f);
  }
  if (outF) {
    *reinterpret_cast<float4*>(&outF[(size_t)gw * 256 + lane * 4]) = res;
  } else {
    const float rv[4] = {res.x, res.y, res.z, res.w};
    short4v hv, lv;
#pragma unroll
    for (int j = 0; j < 4; ++j) {
      bf16 h = __float2bfloat16(rv[j]);
      float r = rv[j] - __bfloat162float(h);
      bf16 l = __float2bfloat16(r);
      hv[j] = *reinterpret_cast<const short*>(&h);
      lv[j] = *reinterpret_cast<const short*>(&l);
    }
    *reinterpret_cast<short4v*>(&((short*)outHi)[(size_t)gw * 256 + lane * 4]) = hv;
    *reinterpret_cast<short4v*>(&((short*)outLo)[(size_t)gw * 256 + lane * 4]) = lv;
  }
  if (erOut) {
    float4 wv0 = *reinterpret_cast<const float4*>(&wr2[(lane * 4 + 0) * 4]);
    float4 wv1 = *reinterpret_cast<const float4*>(&wr2[(lane * 4 + 1) * 4]);
    float4 wv2 = *reinterpret_cast<const float4*>(&wr2[(lane * 4 + 2) * 4]);
    float4 wv3 = *reinterpret_cast<const float4*>(&wr2[(lane * 4 + 3) * 4]);
    float e0 = res.x * wv0.x + res.y * wv1.x + res.z * wv2.x + res.w * wv3.x;
    float e1 = res.x * wv0.y + res.y * wv1.y + res.z * wv2.y + res.w * wv3.y;
    float e2 = res.x * wv0.z + res.y * wv1.z + res.z * wv2.z + res.w * wv3.z;
    float e3 = res.x * wv0.w + res.y * wv1.w + res.z * wv2.w + res.w * wv3.w;
#pragma unroll
    for (int o = 32; o; o >>= 1) {
      e0 += __shfl_xor(e0, o);
      e1 += __shfl_xor(e1, o);
      e2 += __shfl_xor(e2, o);
      e3 += __shfl_xor(e3, o);
    }
    if (lane == 0) {
      erOut[gw * 4 + 0] = e0; erOut[gw * 4 + 1] = e1;
      erOut[gw * 4 + 2] = e2; erOut[gw * 4 + 3] = e3;
    }
  }
}

// ---------- graph readout stage 1 ----------
__global__ __launch_bounds__(256) void graph_sum_v3(
    const float* __restrict__ h, const int* __restrict__ gid,
    float* __restrict__ pbuf, int n) {
  __shared__ float sm[NGRAPH * 256];
  const int t = threadIdx.x;
  for (int i = t; i < NGRAPH * 256; i += 256) sm[i] = 0.f;
  __syncthreads();
  const int chunk = (n + RD_STRIPES - 1) / RD_STRIPES;
  const int lo = blockIdx.x * chunk;
  const int hiN = min(n, lo + chunk);
#pragma unroll 8
  for (int node = lo; node < hiN; ++node) {
    const int g = gid[node];
    const float v = h[(size_t)node * 256 + t];
    sm[g * 256 + t] += v;
  }
  __syncthreads();
  float* dst = pbuf + (size_t)blockIdx.x * (NGRAPH * 256);
  for (int i = t; i < NGRAPH * 256; i += 256) dst[i] = sm[i];
}

// ---------- graph readout stage 2 ----------
__global__ __launch_bounds__(256) void graph_reduce_kernel(
    const float* __restrict__ pbuf, float* __restrict__ gsum, int colofs) {
  const int g = blockIdx.x, t = threadIdx.x;
  float acc = 0.f;
#pragma unroll 8
  for (int s = 0; s < RD_STRIPES; ++s)
    acc += pbuf[(size_t)s * (NGRAPH * 256) + g * 256 + t];
  gsum[(size_t)g * 512 + colofs + t] = acc;
}

// ---------- graph node-count ----------
__global__ __launch_bounds__(256) void graph_count_kernel(
    const int* __restrict__ gid, int* __restrict__ gcnt, int n, int cntofs) {
  __shared__ int c[NGRAPH];
  if (threadIdx.x < NGRAPH) c[threadIdx.x] = 0;
  __syncthreads();
  for (int i = blockIdx.x * blockDim.x + threadIdx.x; i < n; i += gridDim.x * blockDim.x)
    atomicAdd(&c[gid[i]], 1);
  __syncthreads();
  if (threadIdx.x < NGRAPH && c[threadIdx.x])
    atomicAdd(&gcnt[cntofs + threadIdx.x], c[threadIdx.x]);
}

// ---------- final MLP ----------
__global__ __launch_bounds__(256) void mlp_kernel(
    const float* __restrict__ gsum, const int* __restrict__ gcnt,
    const float* __restrict__ Wm, const float* __restrict__ bm,
    float* __restrict__ out) {
  __shared__ float g[512];
  const int b = blockIdx.x, t = threadIdx.x;
  const float cl = fmaxf((float)gcnt[b], 1.f);
  const float cp = fmaxf((float)gcnt[64 + b], 1.f);
  for (int k = t; k < 512; k += 256)
    g[k] = gsum[(size_t)b * 512 + k] * (k < 256 ? 1.f / cl : 1.f / cp);
  __syncthreads();
  float acc = bm[t];
  for (int k = 0; k < 512; ++k) acc = fmaf(g[k], Wm[(size_t)k * 256 + t], acc);
  out[b * 256 + t] = fmaxf(acc, 0.f);
}

// =====================================================================
extern "C" void kernel_launch(void* const* d_in, const int* in_sizes, int n_in,
                              void* d_out, int out_size, void* d_ws, size_t ws_size,
                              hipStream_t stream) {
  const float* x_lig  = (const float*)d_in[0];
  const float* x_pro  = (const float*)d_in[1];
  const float* W1_ll  = (const float*)d_in[2];
  const float* al1_ll = (const float*)d_in[3];
  const float* ar1_ll = (const float*)d_in[4];
  const float* b1_ll  = (const float*)d_in[5];
  const float* W1_lps = (const float*)d_in[6];
  const float* W1_lpd = (const float*)d_in[7];
  const float* al1_lp = (const float*)d_in[8];
  const float* ar1_lp = (const float*)d_in[9];
  const float* b1_lp  = (const float*)d_in[10];
  const float* W1_pls = (const float*)d_in[11];
  const float* W1_pld = (const float*)d_in[12];
  const float* al1_pl = (const float*)d_in[13];
  const float* ar1_pl = (const float*)d_in[14];
  const float* b1_pl  = (const float*)d_in[15];
  const float* W2_ll  = (const float*)d_in[16];
  const float* al2_ll = (const float*)d_in[17];
  const float* ar2_ll = (const float*)d_in[18];
  const float* b2_ll  = (const float*)d_in[19];
  const float* W2_lps = (const float*)d_in[20];
  const float* W2_lpd = (const float*)d_in[21];
  const float* al2_lp = (const float*)d_in[22];
  const float* ar2_lp = (const float*)d_in[23];
  const float* b2_lp  = (const float*)d_in[24];
  const float* W2_pls = (const float*)d_in[25];
  const float* W2_pld = (const float*)d_in[26];
  const float* al2_pl = (const float*)d_in[27];
  const float* ar2_pl = (const float*)d_in[28];
  const float* b2_pl  = (const float*)d_in[29];
  const float* W_mlp  = (const float*)d_in[30];
  const float* b_mlp  = (const float*)d_in[31];
  const int* src_ll   = (const int*)d_in[32];
  const int* dst_ll   = (const int*)d_in[33];
  const int* src_lp   = (const int*)d_in[34];
  const int* dst_lp   = (const int*)d_in[35];
  const int* src_pl   = (const int*)d_in[36];
  const int* dst_pl   = (const int*)d_in[37];
  const int* gid_lig  = (const int*)d_in[38];
  const int* gid_pro  = (const int*)d_in[39];
  float* out = (float*)d_out;
  (void)in_sizes; (void)n_in; (void)out_size; (void)ws_size;

  // -------- workspace carving (~172 MB) --------
  size_t cur = 0;
  auto carve = [&](size_t bytes) -> char* {
    char* p = (char*)d_ws + cur;
    cur += (bytes + 511) & ~(size_t)511;
    return p;
  };
  const size_t NB   = (size_t)40000 * 256 * sizeof(float);   // 40.96 MB
  const size_t NBH  = (size_t)40000 * 256 * sizeof(bf16);    // 20.48 MB
  bf16* FbA   = (bf16*)carve(NBH);      // relation-A features; pbuf overlay at readout
  bf16* FbB   = (bf16*)carve(NBH);      // relation-B features
  char* S1    = carve(NB);              // h_l bf16 hi/lo
  char* S2P   = carve(NB);              // h_p bf16 hi/lo; later P2 f32 (h_p2)
  float* hX   = (float*)carve(NB);      // h_l2 f32
  float* elA  = (float*)carve((size_t)40000 * 4 * sizeof(float));
  float* erA  = (float*)carve((size_t)40000 * 4 * sizeof(float));
  float* elB  = (float*)carve((size_t)40000 * 4 * sizeof(float));
  float* erB  = (float*)carve((size_t)40000 * 4 * sizeof(float));
  float* erPL = (float*)carve((size_t)40000 * 4 * sizeof(float));
  float* erLP = (float*)carve((size_t)40000 * 4 * sizeof(float));
  float* wr1  = (float*)carve((size_t)256 * 4 * sizeof(float));
  float* wrA  = (float*)carve((size_t)256 * 4 * sizeof(float));
  float* wrB  = (float*)carve((size_t)256 * 4 * sizeof(float));
  bf16* Bthi  = (bf16*)carve((size_t)256 * 256 * sizeof(bf16));
  bf16* Btlo  = (bf16*)carve((size_t)256 * 256 * sizeof(bf16));
  float* gsum = (float*)carve((size_t)64 * 512 * sizeof(float));
  int* gcnt   = (int*)carve(128 * sizeof(int));
  int* bsum   = (int*)carve(1025 * sizeof(int));
  int* off_ll = (int*)carve((NLIG + 1) * sizeof(int));
  int* off_lp = (int*)carve((NPRO + 1) * sizeof(int));
  int* off_pl = (int*)carve((NLIG + 1) * sizeof(int));
  int* cursor = (int*)carve((NLIG + 1) * sizeof(int));
  int* csr_ll = (int*)carve((size_t)ELL * sizeof(int));
  int* csr_lp = (int*)carve((size_t)ELP * sizeof(int));
  int* csr_pl = (int*)carve((size_t)EPL * sizeof(int));

  // overlays / sub-pointers
  bf16* XLhi = (bf16*)S1;                      // layer-1: XL staging inside S1 region
  bf16* XLlo = XLhi + (size_t)40000 * 96;
  bf16* XPhi = (bf16*)S2P;                     // XP staging inside S2 region
  bf16* XPlo = XPhi + (size_t)40000 * 128;
  bf16* S1hi = (bf16*)S1;                      // layer-2 A (h_l)
  bf16* S1lo = S1hi + (size_t)40000 * 256;
  bf16* S2hi = (bf16*)S2P;                     // layer-2 A (h_p)
  bf16* S2lo = S2hi + (size_t)40000 * 256;
  float* P2  = (float*)S2P;                    // h_p2 (after S2 dead)
  float* pbuf = (float*)FbA;                   // 16 MB readout partials (FbA dead)

  const int B256 = 256;
  auto thrGrid  = [](long long n) { return (int)((n + 255) / 256); };
  auto waveGrid = [](int n) { return (n + 3) / 4; };

  auto conv_a = [&](const float* A, bf16* hi, bf16* lo, int M, int K, int Kp) {
    convA_kernel<<<(M + 7) / 8, B256, 0, stream>>>(A, hi, lo, M, K, Kp);
  };
  auto run_mfma = [&](const bf16* ahi, const bf16* alo, const float* W, int K, int Kp,
                      bf16* C, int M, const float* alv, float* elp,
                      const float* arv, float* erp) {
    convBt_kernel<<<256, B256, 0, stream>>>(W, Bthi, Btlo, K, Kp);
    dim3 g((M + 127) / 128, 2);
    mfma_gemm<<<g, B256, 0, stream>>>(ahi, alo, Bthi, Btlo, C, M, Kp, alv, elp, arv, erp);
  };
  auto run_scan = [&](int* data, int n) {
    const int nb = (n + 1023) / 1024;
    scan_reduce_kernel<<<nb, B256, 0, stream>>>(data, bsum, n);
    scan_blocksums_kernel<<<1, 1024, 0, stream>>>(bsum, nb);
    scan_final_kernel<<<nb, 1024, 0, stream>>>(data, bsum, n);
  };

  // -------- CSR builds --------
  struct Rel { const int* src; const int* dst; int* off; int* csr; int E; int Nd; };
  Rel rels[3] = {
    {src_ll, dst_ll, off_ll, csr_ll, ELL, NLIG},
    {src_lp, dst_lp, off_lp, csr_lp, ELP, NPRO},
    {src_pl, dst_pl, off_pl, csr_pl, EPL, NLIG},
  };
  for (int r = 0; r < 3; ++r) {
    hipMemsetAsync(rels[r].off, 0, (rels[r].Nd + 1) * sizeof(int), stream);
    count_kernel<<<thrGrid(rels[r].E), B256, 0, stream>>>(rels[r].dst, rels[r].off, rels[r].E);
    run_scan(rels[r].off, rels[r].Nd);
    hipMemsetAsync(cursor, 0, (rels[r].Nd + 1) * sizeof(int), stream);
    fill_kernel<<<thrGrid(rels[r].E), B256, 0, stream>>>(
        rels[r].src, rels[r].dst, rels[r].off, cursor, rels[r].csr, rels[r].E);
  }

  // ================= LAYER 1 =================
  conv_a(x_lig, XLhi, XLlo, NLIG, 74, 96);
  conv_a(x_pro, XPhi, XPlo, NPRO, 128, 128);
  // ll GEMM: FbA = x_lig @ W1_ll (+ el, er)
  run_mfma(XLhi, XLlo, W1_ll, 74, 96, FbA, NLIG, al1_ll, elA, ar1_ll, erA);
  // pl src GEMM: FbB = x_pro @ W1_pls (+ el)
  run_mfma(XPhi, XPlo, W1_pls, 128, 128, FbB, NPRO, al1_pl, elB, nullptr, nullptr);
  // pl dst er: erB = x_lig @ (W1_pld . ar1_pl)
  make_wr_kernel<<<(74 * 4 + 255) / 256, B256, 0, stream>>>(W1_pld, ar1_pl, wr1, 74);
  er_gemv_kernel<<<waveGrid(NLIG), B256, 0, stream>>>(x_lig, wr1, erB, NLIG, 74);
  // layer-2 pl dst weights (for fused er in epilogue)
  make_wr_kernel<<<(256 * 4 + 255) / 256, B256, 0, stream>>>(W2_pld, ar2_pl, wrA, 256);
  // fused dual agg -> S1 (bf16 split) + erPL; NOTE: writes S1, overwriting XL staging (dead)
  gat_agg_fused<<<waveGrid(NLIG), B256, 0, stream>>>(
      FbA, elA, erA, off_ll, csr_ll,
      FbB, elB, erB, off_pl, csr_pl,
      b1_ll, b1_pl, nullptr, S1hi, S1lo, wrA, erPL, NLIG);
  // lp src GEMM: FbA = x_lig @ W1_lps ... but XL staging was overwritten!
  // -> re-stage x_lig into FbB region? No: re-run conv into S2P is also dead (XP needed? no).
  // Safe order instead: do lp src GEMM BEFORE the dual agg. (handled below by proper ordering)
  // (This comment documents the hazard; actual ordering below is correct.)
  // lp dst er: erB = x_pro @ (W1_lpd . ar1_lp)
  make_wr_kernel<<<(128 * 4 + 255) / 256, B256, 0, stream>>>(W1_lpd, ar1_lp, wr1, 128);
  er_gemv_kernel<<<waveGrid(NPRO), B256, 0, stream>>>(x_pro, wr1, erB, NPRO, 128);
  // layer-2 lp dst weights
  make_wr_kernel<<<(256 * 4 + 255) / 256, B256, 0, stream>>>(W2_lpd, ar2_lp, wrB, 256);
  // lp src GEMM: FbB = x_lig @ W1_lps (+ el) -- XL staging is GONE (S1 overwritten),
  // so re-convert x_lig into the FbA-adjacent scratch: reuse XP region? XP dead after its GEMM.
  conv_a(x_lig, XPhi, XPlo, NLIG, 74, 96);   // stage x_lig into S2P region (XP dead)
  run_mfma(XPhi, XPlo, W1_lps, 74, 96, FbB, NLIG, al1_lp, elB, nullptr, nullptr);
  // fused single agg -> S2 (bf16 split) + erLP. NOTE: writes S2P, overwriting the x_lig staging (dead now).
  gat_agg_fused<<<waveGrid(NPRO), B256, 0, stream>>>(
      FbB, elB, erB, off_lp, csr_lp,
      nullptr, nullptr, nullptr, nullptr, nullptr,
      b1_lp, nullptr, nullptr, S2hi, S2lo, wrB, erLP, NPRO);

  // ================= LAYER 2 =================
  // ll GEMM: FbA = S1 @ W2_ll (+ el, er)
  run_mfma(S1hi, S1lo, W2_ll, 256, 256, FbA, NLIG, al2_ll, elA, ar2_ll, erA);
  // pl src GEMM: FbB = S2 @ W2_pls (+ el)
  run_mfma(S2hi, S2lo, W2_pls, 256, 256, FbB, NPRO, al2_pl, elB, nullptr, nullptr);
  // fused dual agg -> hX (f32, bias b2_ll+b2_pl, relu)
  gat_agg_fused<<<waveGrid(NLIG), B256, 0, stream>>>(
      FbA, elA, erA, off_ll, csr_ll,
      FbB, elB, erPL, off_pl, csr_pl,
      b2_ll, b2_pl, hX, nullptr, nullptr, nullptr, nullptr, NLIG);
  // lp src GEMM: FbA = S1 @ W2_lps (+ el)
  run_mfma(S1hi, S1lo, W2_lps, 256, 256, FbA, NLIG, al2_lp, elA, nullptr, nullptr);
  // fused single agg -> P2 (f32, bias b2_lp, relu). P2 overlays S2 (dead).
  gat_agg_fused<<<waveGrid(NPRO), B256, 0, stream>>>(
      FbA, elA, erLP, off_lp, csr_lp,
      nullptr, nullptr, nullptr, nullptr, nullptr,
      b2_lp, nullptr, P2, nullptr, nullptr, nullptr, nullptr, NPRO);

  // ================= READOUT (FbA dead -> pbuf) + MLP =================
  hipMemsetAsync(gcnt, 0, 128 * sizeof(int), stream);
  graph_sum_v3<<<RD_STRIPES, B256, 0, stream>>>(hX, gid_lig, pbuf, NLIG);
  graph_reduce_kernel<<<NGRAPH, B256, 0, stream>>>(pbuf, gsum, 0);
  graph_count_kernel<<<64, B256, 0, stream>>>(gid_lig, gcnt, NLIG, 0);
  graph_sum_v3<<<RD_STRIPES, B256, 0, stream>>>(P2, gid_pro, pbuf, NPRO);
  graph_reduce_kernel<<<NGRAPH, B256, 0, stream>>>(pbuf, gsum, 256);
  graph_count_kernel<<<64, B256, 0, stream>>>(gid_pro, gcnt, NPRO, 64);
  mlp_kernel<<<64, B256, 0, stream>>>(gsum, gcnt, W_mlp, b_mlp, out);
}

// Round 15
// 613.319 us; speedup vs baseline: 17.0104x; 1.0390x over previous
//
#include <hip/hip_runtime.h>
#include <hip/hip_bf16.h>

#define NLIG 40000
#define NPRO 40000
#define NGRAPH 64
#define ELL 160000
#define ELP 240000
#define EPL 240000

#define RD_STRIPES 256

typedef __hip_bfloat16 bf16;
typedef __attribute__((ext_vector_type(8))) short short8;
typedef __attribute__((ext_vector_type(4))) short short4v;
typedef __attribute__((ext_vector_type(4))) float f32x4;

__device__ __forceinline__ float bits2f(short s) {
  const unsigned u = ((unsigned)(unsigned short)s) << 16;
  return __uint_as_float(u);
}

// ---------- convA: f32 [M,K] -> bf16 hi/lo [M,Kp], zero-padded ----------
__global__ __launch_bounds__(256) void convA_kernel(
    const float* __restrict__ A, bf16* __restrict__ hi, bf16* __restrict__ lo,
    int M, int K, int Kp) {
  const int row = blockIdx.x * 8 + (threadIdx.x >> 5);
  if (row >= M) return;
  const int Kp4 = Kp >> 2;
  short* hp = (short*)hi;
  short* lq = (short*)lo;
  for (int c4 = threadIdx.x & 31; c4 < Kp4; c4 += 32) {
    const int k = c4 << 2;
    float v[4];
#pragma unroll
    for (int j = 0; j < 4; ++j) {
      const int kk = k + j;
      v[j] = (kk < K) ? A[(size_t)row * K + kk] : 0.f;
    }
    short4v hv, lv;
#pragma unroll
    for (int j = 0; j < 4; ++j) {
      bf16 h = __float2bfloat16(v[j]);
      float r = v[j] - __bfloat162float(h);
      bf16 l = __float2bfloat16(r);
      hv[j] = *reinterpret_cast<short*>(&h);
      lv[j] = *reinterpret_cast<short*>(&l);
    }
    *reinterpret_cast<short4v*>(&hp[(size_t)row * Kp + k]) = hv;
    *reinterpret_cast<short4v*>(&lq[(size_t)row * Kp + k]) = lv;
  }
}

// ---------- convBt: f32 B[K,256] -> bf16 hi/lo transposed [256,Kp] ----------
__global__ __launch_bounds__(256) void convBt_kernel(
    const float* __restrict__ B, bf16* __restrict__ thi, bf16* __restrict__ tlo,
    int K, int Kp) {
  const int tot = 256 * Kp;
  for (int i = blockIdx.x * 256 + threadIdx.x; i < tot; i += gridDim.x * 256) {
    const int n = i / Kp, k = i % Kp;
    float v = (k < K) ? B[(size_t)k * 256 + n] : 0.f;
    bf16 h = __float2bfloat16(v);
    float r = v - __bfloat162float(h);
    thi[i] = h;
    tlo[i] = __float2bfloat16(r);
  }
}

// ---------- MFMA GEMM: C_bf16[M,256] = A[M,Kp] @ B[Kp,256] (split bf16 inputs) ----------
// 1D grid, XCD-paired mapping: the two column-blocks of a row-tile have bids 8 apart
// (same bid%8 -> same XCD on round-robin dispatch) so the A-panel stays L2-resident.
#define LP 40
__global__ __launch_bounds__(256) void mfma_gemm(
    const bf16* __restrict__ AhiP, const bf16* __restrict__ AloP,
    const bf16* __restrict__ BthiP, const bf16* __restrict__ BtloP,
    bf16* __restrict__ C, int M, int Kp,
    const float* __restrict__ al, float* __restrict__ el,
    const float* __restrict__ ar, float* __restrict__ er) {
  __shared__ short sA[2][128 * LP];
  __shared__ short sB[2][128 * LP];
  const short* Ahi = (const short*)AhiP;
  const short* Alo = (const short*)AloP;
  const short* Bthi = (const short*)BthiP;
  const short* Btlo = (const short*)BtloP;
  const int bid = blockIdx.x;
  const int rt = (bid >> 4) * 8 + (bid & 7);
  const int m0 = rt * 128;
  if (m0 >= M) return;
  const int n0 = ((bid >> 3) & 1) * 128;
  const int t = threadIdx.x;
  const int w = t >> 6, l = t & 63;
  const f32x4 zf = {0.f, 0.f, 0.f, 0.f};
  const short8 zs = {0, 0, 0, 0, 0, 0, 0, 0};
  f32x4 acc[2][8];
#pragma unroll
  for (int i = 0; i < 2; ++i)
#pragma unroll
    for (int j = 0; j < 8; ++j) acc[i][j] = zf;

  const int fr = l & 15, kg = l >> 4;

  for (int k0 = 0; k0 < Kp; k0 += 32) {
#pragma unroll
    for (int rep = 0; rep < 2; ++rep) {
      const int p = t + rep * 256;
      const int row = p >> 2, c = p & 3;
      const int gr = m0 + row;
      short8 vh = zs, vl = zs;
      if (gr < M) {
        const size_t g = (size_t)gr * Kp + k0 + c * 8;
        vh = *(const short8*)(Ahi + g);
        vl = *(const short8*)(Alo + g);
      }
      *(short8*)(&sA[0][row * LP + c * 8]) = vh;
      *(short8*)(&sA[1][row * LP + c * 8]) = vl;
    }
#pragma unroll
    for (int rep = 0; rep < 2; ++rep) {
      const int p = t + rep * 256;
      const int row = p >> 2, c = p & 3;
      const size_t g = (size_t)(n0 + row) * Kp + k0 + c * 8;
      *(short8*)(&sB[0][row * LP + c * 8]) = *(const short8*)(Bthi + g);
      *(short8*)(&sB[1][row * LP + c * 8]) = *(const short8*)(Btlo + g);
    }
    __syncthreads();
    short8 aF[2][2];
#pragma unroll
    for (int i = 0; i < 2; ++i) {
      const int r = (w * 32 + i * 16 + fr) * LP + kg * 8;
      aF[0][i] = *(const short8*)(&sA[0][r]);
      aF[1][i] = *(const short8*)(&sA[1][r]);
    }
#pragma unroll
    for (int j = 0; j < 8; ++j) {
      const int r = (j * 16 + fr) * LP + kg * 8;
      const short8 b0 = *(const short8*)(&sB[0][r]);
      const short8 b1 = *(const short8*)(&sB[1][r]);
#pragma unroll
      for (int i = 0; i < 2; ++i) {
        acc[i][j] = __builtin_amdgcn_mfma_f32_16x16x32_bf16(aF[0][i], b0, acc[i][j], 0, 0, 0);
        acc[i][j] = __builtin_amdgcn_mfma_f32_16x16x32_bf16(aF[0][i], b1, acc[i][j], 0, 0, 0);
        acc[i][j] = __builtin_amdgcn_mfma_f32_16x16x32_bf16(aF[1][i], b0, acc[i][j], 0, 0, 0);
      }
    }
    __syncthreads();
  }

#pragma unroll
  for (int i = 0; i < 2; ++i) {
    const int rbase = m0 + w * 32 + i * 16 + kg * 4;
#pragma unroll
    for (int j = 0; j < 8; ++j) {
      const int col = n0 + j * 16 + fr;
#pragma unroll
      for (int r = 0; r < 4; ++r) {
        const int row = rbase + r;
        if (row < M) C[(size_t)row * 256 + col] = __float2bfloat16(acc[i][j][r]);
      }
    }
  }

  if (el) {
    float alv[8], arv[8];
#pragma unroll
    for (int j = 0; j < 8; ++j) {
      alv[j] = al[n0 + j * 16 + fr];
      arv[j] = er ? ar[n0 + j * 16 + fr] : 0.f;
    }
    const int hb = n0 >> 6;
#pragma unroll
    for (int i = 0; i < 2; ++i) {
#pragma unroll
      for (int r = 0; r < 4; ++r) {
        float sl0 = 0.f, sl1 = 0.f, sr0 = 0.f, sr1 = 0.f;
#pragma unroll
        for (int j = 0; j < 4; ++j) {
          sl0 = fmaf(acc[i][j][r], alv[j], sl0);
          sr0 = fmaf(acc[i][j][r], arv[j], sr0);
          sl1 = fmaf(acc[i][j + 4][r], alv[j + 4], sl1);
          sr1 = fmaf(acc[i][j + 4][r], arv[j + 4], sr1);
        }
        sl0 += __shfl_xor(sl0, 1); sl0 += __shfl_xor(sl0, 2);
        sl0 += __shfl_xor(sl0, 4); sl0 += __shfl_xor(sl0, 8);
        sl1 += __shfl_xor(sl1, 1); sl1 += __shfl_xor(sl1, 2);
        sl1 += __shfl_xor(sl1, 4); sl1 += __shfl_xor(sl1, 8);
        sr0 += __shfl_xor(sr0, 1); sr0 += __shfl_xor(sr0, 2);
        sr0 += __shfl_xor(sr0, 4); sr0 += __shfl_xor(sr0, 8);
        sr1 += __shfl_xor(sr1, 1); sr1 += __shfl_xor(sr1, 2);
        sr1 += __shfl_xor(sr1, 4); sr1 += __shfl_xor(sr1, 8);
        const int row = m0 + w * 32 + i * 16 + kg * 4 + r;
        if (fr == 0 && row < M) {
          el[row * 4 + hb] = sl0;
          el[row * 4 + hb + 1] = sl1;
          if (er) {
            er[row * 4 + hb] = sr0;
            er[row * 4 + hb + 1] = sr1;
          }
        }
      }
    }
  }
}

// ------------- make_wr: wr[k,h] = sum_d Wd[k,h*64+d]*ar[h*64+d] -------------
__global__ void make_wr_kernel(const float* __restrict__ Wd,
                               const float* __restrict__ ar,
                               float* __restrict__ wr, int K) {
  const int t = blockIdx.x * blockDim.x + threadIdx.x;
  if (t < K * 4) {
    const int k = t >> 2, h = t & 3;
    float s = 0.f;
    for (int d = 0; d < 64; ++d)
      s = fmaf(Wd[(size_t)k * 256 + h * 64 + d], ar[h * 64 + d], s);
    wr[t] = s;
  }
}

// ------------- er gemv (layer-1 only, reads raw f32 inputs) -------------
__global__ __launch_bounds__(256) void er_gemv_kernel(
    const float* __restrict__ X, const float* __restrict__ wr,
    float* __restrict__ er, int n, int K) {
  __shared__ float swr[1024];
  const int t = threadIdx.x;
  for (int i = t; i < K * 4; i += blockDim.x) swr[i] = wr[i];
  __syncthreads();
  const int lane = t & 63;
  const int gw = (blockIdx.x * blockDim.x + t) >> 6;
  if (gw >= n) return;
  float a0 = 0.f, a1 = 0.f, a2 = 0.f, a3 = 0.f;
  for (int k = lane; k < K; k += 64) {
    const float x = X[(size_t)gw * K + k];
    a0 = fmaf(x, swr[k * 4 + 0], a0);
    a1 = fmaf(x, swr[k * 4 + 1], a1);
    a2 = fmaf(x, swr[k * 4 + 2], a2);
    a3 = fmaf(x, swr[k * 4 + 3], a3);
  }
#pragma unroll
  for (int o = 32; o; o >>= 1) {
    a0 += __shfl_xor(a0, o);
    a1 += __shfl_xor(a1, o);
    a2 += __shfl_xor(a2, o);
    a3 += __shfl_xor(a3, o);
  }
  if (lane == 0) {
    er[gw * 4 + 0] = a0; er[gw * 4 + 1] = a1;
    er[gw * 4 + 2] = a2; er[gw * 4 + 3] = a3;
  }
}

// ------------- CSR build -------------
__global__ void count_kernel(const int* __restrict__ dst, int* __restrict__ cnt, int E) {
  for (int i = blockIdx.x * blockDim.x + threadIdx.x; i < E; i += gridDim.x * blockDim.x)
    atomicAdd(&cnt[dst[i]], 1);
}

__global__ __launch_bounds__(256) void scan_reduce_kernel(
    const int* __restrict__ data, int* __restrict__ bsum, int n) {
  const int base = blockIdx.x * 1024;
  int s = 0;
  for (int i = threadIdx.x; i < 1024; i += 256) {
    const int idx = base + i;
    s += (idx < n) ? data[idx] : 0;
  }
#pragma unroll
  for (int o = 32; o; o >>= 1) s += __shfl_xor(s, o);
  __shared__ int ws[4];
  if ((threadIdx.x & 63) == 0) ws[threadIdx.x >> 6] = s;
  __syncthreads();
  if (threadIdx.x == 0) bsum[blockIdx.x] = ws[0] + ws[1] + ws[2] + ws[3];
}

__global__ __launch_bounds__(1024) void scan_blocksums_kernel(
    int* __restrict__ bsum, int nb) {
  __shared__ int sm[1024];
  const int t = threadIdx.x;
  const int v = (t < nb) ? bsum[t] : 0;
  sm[t] = v;
  __syncthreads();
  for (int ofs = 1; ofs < 1024; ofs <<= 1) {
    const int tmp = (t >= ofs) ? sm[t - ofs] : 0;
    __syncthreads();
    sm[t] += tmp;
    __syncthreads();
  }
  if (t < nb) bsum[t] = sm[t] - v;
}

__global__ __launch_bounds__(1024) void scan_final_kernel(
    int* __restrict__ data, const int* __restrict__ bsum, int n) {
  __shared__ int sm[1024];
  const int t = threadIdx.x;
  const int i = blockIdx.x * 1024 + t;
  const int v = (i < n) ? data[i] : 0;
  sm[t] = v;
  __syncthreads();
  for (int ofs = 1; ofs < 1024; ofs <<= 1) {
    const int tmp = (t >= ofs) ? sm[t - ofs] : 0;
    __syncthreads();
    sm[t] += tmp;
    __syncthreads();
  }
  const int c = bsum[blockIdx.x];
  if (i < n) data[i] = c + sm[t] - v;
  if (i == n - 1) data[n] = c + sm[t];
}

__global__ void fill_kernel(const int* __restrict__ src, const int* __restrict__ dst,
                            const int* __restrict__ off, int* __restrict__ cursor,
                            int* __restrict__ csrsrc, int E) {
  for (int i = blockIdx.x * blockDim.x + threadIdx.x; i < E; i += gridDim.x * blockDim.x) {
    const int d = dst[i];
    const int p = atomicAdd(&cursor[d], 1);
    csrsrc[off[d] + p] = src[i];
  }
}

// ------------- per-relation edge walk (8-edge batches, bf16 gather, fast exp) -------------
__device__ __forceinline__ float4 agg_walk(
    const short* __restrict__ Fp, const float* __restrict__ el, float ern,
    const int* __restrict__ csr, int s0, int s1, int myh, int lane) {
  float4 acc = {0.f, 0.f, 0.f, 0.f};
  float ssum = 0.f;
  for (int p = s0; p < s1; p += 8) {
    const int nb = s1 - p;
    int srcs[8];
#pragma unroll
    for (int b = 0; b < 8; ++b) {
      const int q = (b < nb) ? b : nb - 1;
      srcs[b] = csr[p + q];
    }
    float w8[8];
#pragma unroll
    for (int b = 0; b < 8; ++b) {
      float e = el[srcs[b] * 4 + myh] + ern;
      e = e > 0.f ? e : 0.2f * e;
      w8[b] = (b < nb) ? __expf(e) : 0.f;
    }
    short4v f8[8];
#pragma unroll
    for (int b = 0; b < 8; ++b)
      f8[b] = *reinterpret_cast<const short4v*>(&Fp[(size_t)srcs[b] * 256 + lane * 4]);
#pragma unroll
    for (int b = 0; b < 8; ++b) {
      ssum += w8[b];
      acc.x = fmaf(w8[b], bits2f(f8[b][0]), acc.x);
      acc.y = fmaf(w8[b], bits2f(f8[b][1]), acc.y);
      acc.z = fmaf(w8[b], bits2f(f8[b][2]), acc.z);
      acc.w = fmaf(w8[b], bits2f(f8[b][3]), acc.w);
    }
  }
  const float inv = ssum > 0.f ? 1.f / ssum : 0.f;
  float4 r = {acc.x * inv, acc.y * inv, acc.z * inv, acc.w * inv};
  return r;
}

// ------------- fused GAT aggregate -------------
__global__ __launch_bounds__(256) void gat_agg_fused(
    const bf16* __restrict__ F1, const float* __restrict__ el1,
    const float* __restrict__ er1, const int* __restrict__ off1,
    const int* __restrict__ csr1,
    const bf16* __restrict__ F2, const float* __restrict__ el2,
    const float* __restrict__ er2, const int* __restrict__ off2,
    const int* __restrict__ csr2,
    const float* __restrict__ bias1, const float* __restrict__ bias2,
    float* __restrict__ outF, bf16* __restrict__ outHi, bf16* __restrict__ outLo,
    const float* __restrict__ wr2, float* __restrict__ erOut,
    int n_dst) {
  const int lane = threadIdx.x & 63;
  const int myh = lane >> 4;
  const int gw = (blockIdx.x * blockDim.x + threadIdx.x) >> 6;
  if (gw >= n_dst) return;

  float4 res = agg_walk((const short*)F1, el1, er1[gw * 4 + myh],
                        csr1, off1[gw], off1[gw + 1], myh, lane);
  if (F2) {
    const float4 r2 = agg_walk((const short*)F2, el2, er2[gw * 4 + myh],
                               csr2, off2[gw], off2[gw + 1], myh, lane);
    res.x += r2.x; res.y += r2.y; res.z += r2.z; res.w += r2.w;
  }
  {
    float4 bb = *reinterpret_cast<const float4*>(&bias1[lane * 4]);
    if (bias2) {
      const float4 b2 = *reinterpret_cast<const float4*>(&bias2[lane * 4]);
      bb.x += b2.x; bb.y += b2.y; bb.z += b2.z; bb.w += b2.w;
    }
    res.x = fmaxf(res.x + bb.x, 0.f);
    res.y = fmaxf(res.y + bb.y, 0.f);
    res.z = fmaxf(res.z + bb.z, 0.f);
    res.w = fmaxf(res.w + bb.w, 0.f);
  }
  if (outF) {
    *reinterpret_cast<float4*>(&outF[(size_t)gw * 256 + lane * 4]) = res;
  } else {
    const float rv[4] = {res.x, res.y, res.z, res.w};
    short4v hv, lv;
#pragma unroll
    for (int j = 0; j < 4; ++j) {
      bf16 h = __float2bfloat16(rv[j]);
      float r = rv[j] - __bfloat162float(h);
      bf16 l = __float2bfloat16(r);
      hv[j] = *reinterpret_cast<const short*>(&h);
      lv[j] = *reinterpret_cast<const short*>(&l);
    }
    *reinterpret_cast<short4v*>(&((short*)outHi)[(size_t)gw * 256 + lane * 4]) = hv;
    *reinterpret_cast<short4v*>(&((short*)outLo)[(size_t)gw * 256 + lane * 4]) = lv;
  }
  if (erOut) {
    float4 wv0 = *reinterpret_cast<const float4*>(&wr2[(lane * 4 + 0) * 4]);
    float4 wv1 = *reinterpret_cast<const float4*>(&wr2[(lane * 4 + 1) * 4]);
    float4 wv2 = *reinterpret_cast<const float4*>(&wr2[(lane * 4 + 2) * 4]);
    float4 wv3 = *reinterpret_cast<const float4*>(&wr2[(lane * 4 + 3) * 4]);
    float e0 = res.x * wv0.x + res.y * wv1.x + res.z * wv2.x + res.w * wv3.x;
    float e1 = res.x * wv0.y + res.y * wv1.y + res.z * wv2.y + res.w * wv3.y;
    float e2 = res.x * wv0.z + res.y * wv1.z + res.z * wv2.z + res.w * wv3.z;
    float e3 = res.x * wv0.w + res.y * wv1.w + res.z * wv2.w + res.w * wv3.w;
#pragma unroll
    for (int o = 32; o; o >>= 1) {
      e0 += __shfl_xor(e0, o);
      e1 += __shfl_xor(e1, o);
      e2 += __shfl_xor(e2, o);
      e3 += __shfl_xor(e3, o);
    }
    if (lane == 0) {
      erOut[gw * 4 + 0] = e0; erOut[gw * 4 + 1] = e1;
      erOut[gw * 4 + 2] = e2; erOut[gw * 4 + 3] = e3;
    }
  }
}

// ---------- graph readout stage 1 ----------
__global__ __launch_bounds__(256) void graph_sum_v3(
    const float* __restrict__ h, const int* __restrict__ gid,
    float* __restrict__ pbuf, int n) {
  __shared__ float sm[NGRAPH * 256];
  const int t = threadIdx.x;
  for (int i = t; i < NGRAPH * 256; i += 256) sm[i] = 0.f;
  __syncthreads();
  const int chunk = (n + RD_STRIPES - 1) / RD_STRIPES;
  const int lo = blockIdx.x * chunk;
  const int hiN = min(n, lo + chunk);
#pragma unroll 8
  for (int node = lo; node < hiN; ++node) {
    const int g = gid[node];
    const float v = h[(size_t)node * 256 + t];
    sm[g * 256 + t] += v;
  }
  __syncthreads();
  float* dst = pbuf + (size_t)blockIdx.x * (NGRAPH * 256);
  for (int i = t; i < NGRAPH * 256; i += 256) dst[i] = sm[i];
}

// ---------- graph readout stage 2 ----------
__global__ __launch_bounds__(256) void graph_reduce_kernel(
    const float* __restrict__ pbuf, float* __restrict__ gsum, int colofs) {
  const int g = blockIdx.x, t = threadIdx.x;
  float acc = 0.f;
#pragma unroll 8
  for (int s = 0; s < RD_STRIPES; ++s)
    acc += pbuf[(size_t)s * (NGRAPH * 256) + g * 256 + t];
  gsum[(size_t)g * 512 + colofs + t] = acc;
}

// ---------- graph node-count ----------
__global__ __launch_bounds__(256) void graph_count_kernel(
    const int* __restrict__ gid, int* __restrict__ gcnt, int n, int cntofs) {
  __shared__ int c[NGRAPH];
  if (threadIdx.x < NGRAPH) c[threadIdx.x] = 0;
  __syncthreads();
  for (int i = blockIdx.x * blockDim.x + threadIdx.x; i < n; i += gridDim.x * blockDim.x)
    atomicAdd(&c[gid[i]], 1);
  __syncthreads();
  if (threadIdx.x < NGRAPH && c[threadIdx.x])
    atomicAdd(&gcnt[cntofs + threadIdx.x], c[threadIdx.x]);
}

// ---------- final MLP ----------
__global__ __launch_bounds__(256) void mlp_kernel(
    const float* __restrict__ gsum, const int* __restrict__ gcnt,
    const float* __restrict__ Wm, const float* __restrict__ bm,
    float* __restrict__ out) {
  __shared__ float g[512];
  const int b = blockIdx.x, t = threadIdx.x;
  const float cl = fmaxf((float)gcnt[b], 1.f);
  const float cp = fmaxf((float)gcnt[64 + b], 1.f);
  for (int k = t; k < 512; k += 256)
    g[k] = gsum[(size_t)b * 512 + k] * (k < 256 ? 1.f / cl : 1.f / cp);
  __syncthreads();
  float acc = bm[t];
  for (int k = 0; k < 512; ++k) acc = fmaf(g[k], Wm[(size_t)k * 256 + t], acc);
  out[b * 256 + t] = fmaxf(acc, 0.f);
}

// =====================================================================
extern "C" void kernel_launch(void* const* d_in, const int* in_sizes, int n_in,
                              void* d_out, int out_size, void* d_ws, size_t ws_size,
                              hipStream_t stream) {
  const float* x_lig  = (const float*)d_in[0];
  const float* x_pro  = (const float*)d_in[1];
  const float* W1_ll  = (const float*)d_in[2];
  const float* al1_ll = (const float*)d_in[3];
  const float* ar1_ll = (const float*)d_in[4];
  const float* b1_ll  = (const float*)d_in[5];
  const float* W1_lps = (const float*)d_in[6];
  const float* W1_lpd = (const float*)d_in[7];
  const float* al1_lp = (const float*)d_in[8];
  const float* ar1_lp = (const float*)d_in[9];
  const float* b1_lp  = (const float*)d_in[10];
  const float* W1_pls = (const float*)d_in[11];
  const float* W1_pld = (const float*)d_in[12];
  const float* al1_pl = (const float*)d_in[13];
  const float* ar1_pl = (const float*)d_in[14];
  const float* b1_pl  = (const float*)d_in[15];
  const float* W2_ll  = (const float*)d_in[16];
  const float* al2_ll = (const float*)d_in[17];
  const float* ar2_ll = (const float*)d_in[18];
  const float* b2_ll  = (const float*)d_in[19];
  const float* W2_lps = (const float*)d_in[20];
  const float* W2_lpd = (const float*)d_in[21];
  const float* al2_lp = (const float*)d_in[22];
  const float* ar2_lp = (const float*)d_in[23];
  const float* b2_lp  = (const float*)d_in[24];
  const float* W2_pls = (const float*)d_in[25];
  const float* W2_pld = (const float*)d_in[26];
  const float* al2_pl = (const float*)d_in[27];
  const float* ar2_pl = (const float*)d_in[28];
  const float* b2_pl  = (const float*)d_in[29];
  const float* W_mlp  = (const float*)d_in[30];
  const float* b_mlp  = (const float*)d_in[31];
  const int* src_ll   = (const int*)d_in[32];
  const int* dst_ll   = (const int*)d_in[33];
  const int* src_lp   = (const int*)d_in[34];
  const int* dst_lp   = (const int*)d_in[35];
  const int* src_pl   = (const int*)d_in[36];
  const int* dst_pl   = (const int*)d_in[37];
  const int* gid_lig  = (const int*)d_in[38];
  const int* gid_pro  = (const int*)d_in[39];
  float* out = (float*)d_out;
  (void)in_sizes; (void)n_in; (void)out_size; (void)ws_size;

  // -------- workspace carving (~172 MB) --------
  size_t cur = 0;
  auto carve = [&](size_t bytes) -> char* {
    char* p = (char*)d_ws + cur;
    cur += (bytes + 511) & ~(size_t)511;
    return p;
  };
  const size_t NB   = (size_t)40000 * 256 * sizeof(float);
  const size_t NBH  = (size_t)40000 * 256 * sizeof(bf16);
  bf16* FbA   = (bf16*)carve(NBH);
  bf16* FbB   = (bf16*)carve(NBH);
  char* S1    = carve(NB);
  char* S2P   = carve(NB);
  float* hX   = (float*)carve(NB);
  float* elA  = (float*)carve((size_t)40000 * 4 * sizeof(float));
  float* erA  = (float*)carve((size_t)40000 * 4 * sizeof(float));
  float* elB  = (float*)carve((size_t)40000 * 4 * sizeof(float));
  float* erB  = (float*)carve((size_t)40000 * 4 * sizeof(float));
  float* erPL = (float*)carve((size_t)40000 * 4 * sizeof(float));
  float* erLP = (float*)carve((size_t)40000 * 4 * sizeof(float));
  float* wr1  = (float*)carve((size_t)256 * 4 * sizeof(float));
  float* wrA  = (float*)carve((size_t)256 * 4 * sizeof(float));
  float* wrB  = (float*)carve((size_t)256 * 4 * sizeof(float));
  bf16* Bthi  = (bf16*)carve((size_t)256 * 256 * sizeof(bf16));
  bf16* Btlo  = (bf16*)carve((size_t)256 * 256 * sizeof(bf16));
  float* gsum = (float*)carve((size_t)64 * 512 * sizeof(float));
  int* gcnt   = (int*)carve(128 * sizeof(int));
  int* bsum   = (int*)carve(1025 * sizeof(int));
  int* off_ll = (int*)carve((NLIG + 1) * sizeof(int));
  int* off_lp = (int*)carve((NPRO + 1) * sizeof(int));
  int* off_pl = (int*)carve((NLIG + 1) * sizeof(int));
  int* cursor = (int*)carve((NLIG + 1) * sizeof(int));
  int* csr_ll = (int*)carve((size_t)ELL * sizeof(int));
  int* csr_lp = (int*)carve((size_t)ELP * sizeof(int));
  int* csr_pl = (int*)carve((size_t)EPL * sizeof(int));

  // overlays / sub-pointers
  bf16* XLhi = (bf16*)S1;
  bf16* XLlo = XLhi + (size_t)40000 * 96;
  bf16* XPhi = (bf16*)S2P;
  bf16* XPlo = XPhi + (size_t)40000 * 128;
  bf16* S1hi = (bf16*)S1;
  bf16* S1lo = S1hi + (size_t)40000 * 256;
  bf16* S2hi = (bf16*)S2P;
  bf16* S2lo = S2hi + (size_t)40000 * 256;
  float* P2  = (float*)S2P;
  float* pbuf = (float*)FbA;

  const int B256 = 256;
  auto thrGrid  = [](long long n) { return (int)((n + 255) / 256); };
  auto waveGrid = [](int n) { return (n + 3) / 4; };

  auto conv_a = [&](const float* A, bf16* hi, bf16* lo, int M, int K, int Kp) {
    convA_kernel<<<(M + 7) / 8, B256, 0, stream>>>(A, hi, lo, M, K, Kp);
  };
  auto run_mfma = [&](const bf16* ahi, const bf16* alo, const float* W, int K, int Kp,
                      bf16* C, int M, const float* alv, float* elp,
                      const float* arv, float* erp) {
    convBt_kernel<<<256, B256, 0, stream>>>(W, Bthi, Btlo, K, Kp);
    const int nrt = (M + 127) / 128;
    const int nb = ((nrt + 7) / 8) * 16;   // XCD-paired 1D grid
    mfma_gemm<<<nb, B256, 0, stream>>>(ahi, alo, Bthi, Btlo, C, M, Kp, alv, elp, arv, erp);
  };
  auto run_scan = [&](int* data, int n) {
    const int nb = (n + 1023) / 1024;
    scan_reduce_kernel<<<nb, B256, 0, stream>>>(data, bsum, n);
    scan_blocksums_kernel<<<1, 1024, 0, stream>>>(bsum, nb);
    scan_final_kernel<<<nb, 1024, 0, stream>>>(data, bsum, n);
  };

  // -------- CSR builds --------
  struct Rel { const int* src; const int* dst; int* off; int* csr; int E; int Nd; };
  Rel rels[3] = {
    {src_ll, dst_ll, off_ll, csr_ll, ELL, NLIG},
    {src_lp, dst_lp, off_lp, csr_lp, ELP, NPRO},
    {src_pl, dst_pl, off_pl, csr_pl, EPL, NLIG},
  };
  for (int r = 0; r < 3; ++r) {
    hipMemsetAsync(rels[r].off, 0, (rels[r].Nd + 1) * sizeof(int), stream);
    count_kernel<<<thrGrid(rels[r].E), B256, 0, stream>>>(rels[r].dst, rels[r].off, rels[r].E);
    run_scan(rels[r].off, rels[r].Nd);
    hipMemsetAsync(cursor, 0, (rels[r].Nd + 1) * sizeof(int), stream);
    fill_kernel<<<thrGrid(rels[r].E), B256, 0, stream>>>(
        rels[r].src, rels[r].dst, rels[r].off, cursor, rels[r].csr, rels[r].E);
  }

  // ================= LAYER 1 =================
  conv_a(x_lig, XLhi, XLlo, NLIG, 74, 96);
  conv_a(x_pro, XPhi, XPlo, NPRO, 128, 128);
  // ll GEMM: FbA = x_lig @ W1_ll (+ el, er)
  run_mfma(XLhi, XLlo, W1_ll, 74, 96, FbA, NLIG, al1_ll, elA, ar1_ll, erA);
  // pl src GEMM: FbB = x_pro @ W1_pls (+ el)
  run_mfma(XPhi, XPlo, W1_pls, 128, 128, FbB, NPRO, al1_pl, elB, nullptr, nullptr);
  // pl dst er: erB = x_lig @ (W1_pld . ar1_pl)
  make_wr_kernel<<<(74 * 4 + 255) / 256, B256, 0, stream>>>(W1_pld, ar1_pl, wr1, 74);
  er_gemv_kernel<<<waveGrid(NLIG), B256, 0, stream>>>(x_lig, wr1, erB, NLIG, 74);
  // layer-2 pl dst weights (for fused er in epilogue)
  make_wr_kernel<<<(256 * 4 + 255) / 256, B256, 0, stream>>>(W2_pld, ar2_pl, wrA, 256);
  // fused dual agg -> S1 (bf16 split) + erPL (overwrites XL staging, dead)
  gat_agg_fused<<<waveGrid(NLIG), B256, 0, stream>>>(
      FbA, elA, erA, off_ll, csr_ll,
      FbB, elB, erB, off_pl, csr_pl,
      b1_ll, b1_pl, nullptr, S1hi, S1lo, wrA, erPL, NLIG);
  // lp dst er: erB = x_pro @ (W1_lpd . ar1_lp)
  make_wr_kernel<<<(128 * 4 + 255) / 256, B256, 0, stream>>>(W1_lpd, ar1_lp, wr1, 128);
  er_gemv_kernel<<<waveGrid(NPRO), B256, 0, stream>>>(x_pro, wr1, erB, NPRO, 128);
  // layer-2 lp dst weights
  make_wr_kernel<<<(256 * 4 + 255) / 256, B256, 0, stream>>>(W2_lpd, ar2_lp, wrB, 256);
  // lp src GEMM: re-stage x_lig into S2P region (XP dead), then FbB = x_lig @ W1_lps
  conv_a(x_lig, XPhi, XPlo, NLIG, 74, 96);
  run_mfma(XPhi, XPlo, W1_lps, 74, 96, FbB, NLIG, al1_lp, elB, nullptr, nullptr);
  // fused single agg -> S2 (bf16 split) + erLP (overwrites x_lig staging, dead)
  gat_agg_fused<<<waveGrid(NPRO), B256, 0, stream>>>(
      FbB, elB, erB, off_lp, csr_lp,
      nullptr, nullptr, nullptr, nullptr, nullptr,
      b1_lp, nullptr, nullptr, S2hi, S2lo, wrB, erLP, NPRO);

  // ================= LAYER 2 =================
  run_mfma(S1hi, S1lo, W2_ll, 256, 256, FbA, NLIG, al2_ll, elA, ar2_ll, erA);
  run_mfma(S2hi, S2lo, W2_pls, 256, 256, FbB, NPRO, al2_pl, elB, nullptr, nullptr);
  gat_agg_fused<<<waveGrid(NLIG), B256, 0, stream>>>(
      FbA, elA, erA, off_ll, csr_ll,
      FbB, elB, erPL, off_pl, csr_pl,
      b2_ll, b2_pl, hX, nullptr, nullptr, nullptr, nullptr, NLIG);
  run_mfma(S1hi, S1lo, W2_lps, 256, 256, FbA, NLIG, al2_lp, elA, nullptr, nullptr);
  gat_agg_fused<<<waveGrid(NPRO), B256, 0, stream>>>(
      FbA, elA, erLP, off_lp, csr_lp,
      nullptr, nullptr, nullptr, nullptr, nullptr,
      b2_lp, nullptr, P2, nullptr, nullptr, nullptr, nullptr, NPRO);

  // ================= READOUT (FbA dead -> pbuf) + MLP =================
  hipMemsetAsync(gcnt, 0, 128 * sizeof(int), stream);
  graph_sum_v3<<<RD_STRIPES, B256, 0, stream>>>(hX, gid_lig, pbuf, NLIG);
  graph_reduce_kernel<<<NGRAPH, B256, 0, stream>>>(pbuf, gsum, 0);
  graph_count_kernel<<<64, B256, 0, stream>>>(gid_lig, gcnt, NLIG, 0);
  graph_sum_v3<<<RD_STRIPES, B256, 0, stream>>>(P2, gid_pro, pbuf, NPRO);
  graph_reduce_kernel<<<NGRAPH, B256, 0, stream>>>(pbuf, gsum, 256);
  graph_count_kernel<<<64, B256, 0, stream>>>(gid_pro, gcnt, NPRO, 64);
  mlp_kernel<<<64, B256, 0, stream>>>(gsum, gcnt, W_mlp, b_mlp, out);
}

// Round 17
// 594.208 us; speedup vs baseline: 17.5575x; 1.0322x over previous
//
#include <hip/hip_runtime.h>
#include <hip/hip_bf16.h>

#define NLIG 40000
#define NPRO 40000
#define NGRAPH 64
#define ELL 160000
#define ELP 240000
#define EPL 240000

#define RD_STRIPES 256
#define LOG2E 1.44269504f

typedef __hip_bfloat16 bf16;
typedef __attribute__((ext_vector_type(8))) short short8;
typedef __attribute__((ext_vector_type(4))) short short4v;
typedef __attribute__((ext_vector_type(4))) float f32x4;

__device__ __forceinline__ float bits2f(short s) {
  const unsigned u = ((unsigned)(unsigned short)s) << 16;
  return __uint_as_float(u);
}

// ---------- convA: f32 [M,K] -> bf16 hi/lo [M,Kp], zero-padded ----------
__global__ __launch_bounds__(256) void convA_kernel(
    const float* __restrict__ A, bf16* __restrict__ hi, bf16* __restrict__ lo,
    int M, int K, int Kp) {
  const int row = blockIdx.x * 8 + (threadIdx.x >> 5);
  if (row >= M) return;
  const int Kp4 = Kp >> 2;
  short* hp = (short*)hi;
  short* lq = (short*)lo;
  for (int c4 = threadIdx.x & 31; c4 < Kp4; c4 += 32) {
    const int k = c4 << 2;
    float v[4];
#pragma unroll
    for (int j = 0; j < 4; ++j) {
      const int kk = k + j;
      v[j] = (kk < K) ? A[(size_t)row * K + kk] : 0.f;
    }
    short4v hv, lv;
#pragma unroll
    for (int j = 0; j < 4; ++j) {
      bf16 h = __float2bfloat16(v[j]);
      float r = v[j] - __bfloat162float(h);
      bf16 l = __float2bfloat16(r);
      hv[j] = *reinterpret_cast<short*>(&h);
      lv[j] = *reinterpret_cast<short*>(&l);
    }
    *reinterpret_cast<short4v*>(&hp[(size_t)row * Kp + k]) = hv;
    *reinterpret_cast<short4v*>(&lq[(size_t)row * Kp + k]) = lv;
  }
}

// ---------- convBt: f32 B[K,256] -> bf16 hi/lo transposed [256,Kp] ----------
__global__ __launch_bounds__(256) void convBt_kernel(
    const float* __restrict__ B, bf16* __restrict__ thi, bf16* __restrict__ tlo,
    int K, int Kp) {
  const int tot = 256 * Kp;
  for (int i = blockIdx.x * 256 + threadIdx.x; i < tot; i += gridDim.x * 256) {
    const int n = i / Kp, k = i % Kp;
    float v = (k < K) ? B[(size_t)k * 256 + n] : 0.f;
    bf16 h = __float2bfloat16(v);
    float r = v - __bfloat162float(h);
    thi[i] = h;
    tlo[i] = __float2bfloat16(r);
  }
}

// ---------- MFMA GEMM, N = ncb*128 (ncb = 2 or 4), split bf16, dual-C outputs.
// XCD-paired 1D grid: blocks of one row-tile share bid%8 -> same XCD L2.
// el/er outputs are pre-scaled by LOG2E for exp2-based softmax downstream.
#define LP 40
__global__ __launch_bounds__(256) void mfma_gemm(
    const bf16* __restrict__ AhiP, const bf16* __restrict__ AloP,
    const bf16* __restrict__ BthiP, const bf16* __restrict__ BtloP,
    bf16* __restrict__ C0, bf16* __restrict__ C1, int M, int Kp, int log2ncb,
    const float* __restrict__ al0, float* __restrict__ el0,
    const float* __restrict__ ar0, float* __restrict__ er0,
    const float* __restrict__ al1, float* __restrict__ el1) {
  __shared__ short sA[2][128 * LP];
  __shared__ short sB[2][128 * LP];
  const short* Ahi = (const short*)AhiP;
  const short* Alo = (const short*)AloP;
  const short* Bthi = (const short*)BthiP;
  const short* Btlo = (const short*)BtloP;
  const int bid = blockIdx.x;
  const int ncb = 1 << log2ncb;
  const int rt = (bid >> (3 + log2ncb)) * 8 + (bid & 7);
  const int m0 = rt * 128;
  if (m0 >= M) return;
  const int n0 = ((bid >> 3) & (ncb - 1)) * 128;
  const int t = threadIdx.x;
  const int w = t >> 6, l = t & 63;
  const f32x4 zf = {0.f, 0.f, 0.f, 0.f};
  const short8 zs = {0, 0, 0, 0, 0, 0, 0, 0};
  f32x4 acc[2][8];
#pragma unroll
  for (int i = 0; i < 2; ++i)
#pragma unroll
    for (int j = 0; j < 8; ++j) acc[i][j] = zf;

  const int fr = l & 15, kg = l >> 4;

  for (int k0 = 0; k0 < Kp; k0 += 32) {
#pragma unroll
    for (int rep = 0; rep < 2; ++rep) {
      const int p = t + rep * 256;
      const int row = p >> 2, c = p & 3;
      const int gr = m0 + row;
      short8 vh = zs, vl = zs;
      if (gr < M) {
        const size_t g = (size_t)gr * Kp + k0 + c * 8;
        vh = *(const short8*)(Ahi + g);
        vl = *(const short8*)(Alo + g);
      }
      *(short8*)(&sA[0][row * LP + c * 8]) = vh;
      *(short8*)(&sA[1][row * LP + c * 8]) = vl;
    }
#pragma unroll
    for (int rep = 0; rep < 2; ++rep) {
      const int p = t + rep * 256;
      const int row = p >> 2, c = p & 3;
      const size_t g = (size_t)(n0 + row) * Kp + k0 + c * 8;
      *(short8*)(&sB[0][row * LP + c * 8]) = *(const short8*)(Bthi + g);
      *(short8*)(&sB[1][row * LP + c * 8]) = *(const short8*)(Btlo + g);
    }
    __syncthreads();
    short8 aF[2][2];
#pragma unroll
    for (int i = 0; i < 2; ++i) {
      const int r = (w * 32 + i * 16 + fr) * LP + kg * 8;
      aF[0][i] = *(const short8*)(&sA[0][r]);
      aF[1][i] = *(const short8*)(&sA[1][r]);
    }
#pragma unroll
    for (int j = 0; j < 8; ++j) {
      const int r = (j * 16 + fr) * LP + kg * 8;
      const short8 b0 = *(const short8*)(&sB[0][r]);
      const short8 b1 = *(const short8*)(&sB[1][r]);
#pragma unroll
      for (int i = 0; i < 2; ++i) {
        acc[i][j] = __builtin_amdgcn_mfma_f32_16x16x32_bf16(aF[0][i], b0, acc[i][j], 0, 0, 0);
        acc[i][j] = __builtin_amdgcn_mfma_f32_16x16x32_bf16(aF[0][i], b1, acc[i][j], 0, 0, 0);
        acc[i][j] = __builtin_amdgcn_mfma_f32_16x16x32_bf16(aF[1][i], b0, acc[i][j], 0, 0, 0);
      }
    }
    __syncthreads();
  }

  // select output half
  bf16* C = (n0 < 256) ? C0 : C1;
  const int nloc = n0 & 255;
  const float* alp = (n0 < 256) ? al0 : al1;
  const float* arp = (n0 < 256) ? ar0 : nullptr;
  float* elp = (n0 < 256) ? el0 : el1;
  float* erp = (n0 < 256) ? er0 : nullptr;

#pragma unroll
  for (int i = 0; i < 2; ++i) {
    const int rbase = m0 + w * 32 + i * 16 + kg * 4;
#pragma unroll
    for (int j = 0; j < 8; ++j) {
      const int col = nloc + j * 16 + fr;
#pragma unroll
      for (int r = 0; r < 4; ++r) {
        const int row = rbase + r;
        if (row < M) C[(size_t)row * 256 + col] = __float2bfloat16(acc[i][j][r]);
      }
    }
  }

  if (elp) {
    float alv[8], arv[8];
#pragma unroll
    for (int j = 0; j < 8; ++j) {
      alv[j] = alp[nloc + j * 16 + fr] * LOG2E;
      arv[j] = (arp && erp) ? arp[nloc + j * 16 + fr] * LOG2E : 0.f;
    }
    const int hb = nloc >> 6;
#pragma unroll
    for (int i = 0; i < 2; ++i) {
#pragma unroll
      for (int r = 0; r < 4; ++r) {
        float sl0 = 0.f, sl1 = 0.f, sr0 = 0.f, sr1 = 0.f;
#pragma unroll
        for (int j = 0; j < 4; ++j) {
          sl0 = fmaf(acc[i][j][r], alv[j], sl0);
          sr0 = fmaf(acc[i][j][r], arv[j], sr0);
          sl1 = fmaf(acc[i][j + 4][r], alv[j + 4], sl1);
          sr1 = fmaf(acc[i][j + 4][r], arv[j + 4], sr1);
        }
        sl0 += __shfl_xor(sl0, 1); sl0 += __shfl_xor(sl0, 2);
        sl0 += __shfl_xor(sl0, 4); sl0 += __shfl_xor(sl0, 8);
        sl1 += __shfl_xor(sl1, 1); sl1 += __shfl_xor(sl1, 2);
        sl1 += __shfl_xor(sl1, 4); sl1 += __shfl_xor(sl1, 8);
        sr0 += __shfl_xor(sr0, 1); sr0 += __shfl_xor(sr0, 2);
        sr0 += __shfl_xor(sr0, 4); sr0 += __shfl_xor(sr0, 8);
        sr1 += __shfl_xor(sr1, 1); sr1 += __shfl_xor(sr1, 2);
        sr1 += __shfl_xor(sr1, 4); sr1 += __shfl_xor(sr1, 8);
        const int row = m0 + w * 32 + i * 16 + kg * 4 + r;
        if (fr == 0 && row < M) {
          elp[row * 4 + hb] = sl0;
          elp[row * 4 + hb + 1] = sl1;
          if (erp) {
            erp[row * 4 + hb] = sr0;
            erp[row * 4 + hb + 1] = sr1;
          }
        }
      }
    }
  }
}

// ------------- make_wr: wr[k,h] = LOG2E * sum_d Wd[k,h*64+d]*ar[h*64+d] -------------
__global__ void make_wr_kernel(const float* __restrict__ Wd,
                               const float* __restrict__ ar,
                               float* __restrict__ wr, int K) {
  const int t = blockIdx.x * blockDim.x + threadIdx.x;
  if (t < K * 4) {
    const int k = t >> 2, h = t & 3;
    float s = 0.f;
    for (int d = 0; d < 64; ++d)
      s = fmaf(Wd[(size_t)k * 256 + h * 64 + d], ar[h * 64 + d], s);
    wr[t] = s * LOG2E;
  }
}

// ------------- er gemv (layer-1 only, reads raw f32 inputs; wr pre-scaled) -------------
__global__ __launch_bounds__(256) void er_gemv_kernel(
    const float* __restrict__ X, const float* __restrict__ wr,
    float* __restrict__ er, int n, int K) {
  __shared__ float swr[1024];
  const int t = threadIdx.x;
  for (int i = t; i < K * 4; i += blockDim.x) swr[i] = wr[i];
  __syncthreads();
  const int lane = t & 63;
  const int gw = (blockIdx.x * blockDim.x + t) >> 6;
  if (gw >= n) return;
  float a0 = 0.f, a1 = 0.f, a2 = 0.f, a3 = 0.f;
  for (int k = lane; k < K; k += 64) {
    const float x = X[(size_t)gw * K + k];
    a0 = fmaf(x, swr[k * 4 + 0], a0);
    a1 = fmaf(x, swr[k * 4 + 1], a1);
    a2 = fmaf(x, swr[k * 4 + 2], a2);
    a3 = fmaf(x, swr[k * 4 + 3], a3);
  }
#pragma unroll
  for (int o = 32; o; o >>= 1) {
    a0 += __shfl_xor(a0, o);
    a1 += __shfl_xor(a1, o);
    a2 += __shfl_xor(a2, o);
    a3 += __shfl_xor(a3, o);
  }
  if (lane == 0) {
    er[gw * 4 + 0] = a0; er[gw * 4 + 1] = a1;
    er[gw * 4 + 2] = a2; er[gw * 4 + 3] = a3;
  }
}

// ------------- CSR build -------------
__global__ void count_kernel(const int* __restrict__ dst, int* __restrict__ cnt, int E) {
  for (int i = blockIdx.x * blockDim.x + threadIdx.x; i < E; i += gridDim.x * blockDim.x)
    atomicAdd(&cnt[dst[i]], 1);
}

__global__ __launch_bounds__(256) void scan_reduce_kernel(
    const int* __restrict__ data, int* __restrict__ bsum, int n) {
  const int base = blockIdx.x * 1024;
  int s = 0;
  for (int i = threadIdx.x; i < 1024; i += 256) {
    const int idx = base + i;
    s += (idx < n) ? data[idx] : 0;
  }
#pragma unroll
  for (int o = 32; o; o >>= 1) s += __shfl_xor(s, o);
  __shared__ int ws[4];
  if ((threadIdx.x & 63) == 0) ws[threadIdx.x >> 6] = s;
  __syncthreads();
  if (threadIdx.x == 0) bsum[blockIdx.x] = ws[0] + ws[1] + ws[2] + ws[3];
}

__global__ __launch_bounds__(1024) void scan_blocksums_kernel(
    int* __restrict__ bsum, int nb) {
  __shared__ int sm[1024];
  const int t = threadIdx.x;
  const int v = (t < nb) ? bsum[t] : 0;
  sm[t] = v;
  __syncthreads();
  for (int ofs = 1; ofs < 1024; ofs <<= 1) {
    const int tmp = (t >= ofs) ? sm[t - ofs] : 0;
    __syncthreads();
    sm[t] += tmp;
    __syncthreads();
  }
  if (t < nb) bsum[t] = sm[t] - v;
}

__global__ __launch_bounds__(1024) void scan_final_kernel(
    int* __restrict__ data, const int* __restrict__ bsum, int n) {
  __shared__ int sm[1024];
  const int t = threadIdx.x;
  const int i = blockIdx.x * 1024 + t;
  const int v = (i < n) ? data[i] : 0;
  sm[t] = v;
  __syncthreads();
  for (int ofs = 1; ofs < 1024; ofs <<= 1) {
    const int tmp = (t >= ofs) ? sm[t - ofs] : 0;
    __syncthreads();
    sm[t] += tmp;
    __syncthreads();
  }
  const int c = bsum[blockIdx.x];
  if (i < n) data[i] = c + sm[t] - v;
  if (i == n - 1) data[n] = c + sm[t];
}

__global__ void fill_kernel(const int* __restrict__ src, const int* __restrict__ dst,
                            const int* __restrict__ off, int* __restrict__ cursor,
                            int* __restrict__ csrsrc, int E) {
  for (int i = blockIdx.x * blockDim.x + threadIdx.x; i < E; i += gridDim.x * blockDim.x) {
    const int d = dst[i];
    const int p = atomicAdd(&cursor[d], 1);
    csrsrc[off[d] + p] = src[i];
  }
}

// ------------- per-relation edge walk (8-edge batches, bf16 gather, exp2) -------------
__device__ __forceinline__ float4 agg_walk(
    const short* __restrict__ Fp, const float* __restrict__ el, float ern,
    const int* __restrict__ csr, int s0, int s1, int myh, int lane) {
  float4 acc = {0.f, 0.f, 0.f, 0.f};
  float ssum = 0.f;
  for (int p = s0; p < s1; p += 8) {
    const int nb = s1 - p;
    int srcs[8];
#pragma unroll
    for (int b = 0; b < 8; ++b) {
      const int q = (b < nb) ? b : nb - 1;
      srcs[b] = csr[p + q];
    }
    float w8[8];
#pragma unroll
    for (int b = 0; b < 8; ++b) {
      float e = el[srcs[b] * 4 + myh] + ern;
      e = e > 0.f ? e : 0.2f * e;
      w8[b] = (b < nb) ? exp2f(e) : 0.f;
    }
    short4v f8[8];
#pragma unroll
    for (int b = 0; b < 8; ++b)
      f8[b] = *reinterpret_cast<const short4v*>(&Fp[(size_t)srcs[b] * 256 + lane * 4]);
#pragma unroll
    for (int b = 0; b < 8; ++b) {
      ssum += w8[b];
      acc.x = fmaf(w8[b], bits2f(f8[b][0]), acc.x);
      acc.y = fmaf(w8[b], bits2f(f8[b][1]), acc.y);
      acc.z = fmaf(w8[b], bits2f(f8[b][2]), acc.z);
      acc.w = fmaf(w8[b], bits2f(f8[b][3]), acc.w);
    }
  }
  const float inv = ssum > 0.f ? 1.f / ssum : 0.f;
  float4 r = {acc.x * inv, acc.y * inv, acc.z * inv, acc.w * inv};
  return r;
}

// ------------- fused GAT aggregate -------------
__global__ __launch_bounds__(256) void gat_agg_fused(
    const bf16* __restrict__ F1, const float* __restrict__ el1,
    const float* __restrict__ er1, const int* __restrict__ off1,
    const int* __restrict__ csr1,
    const bf16* __restrict__ F2, const float* __restrict__ el2,
    const float* __restrict__ er2, const int* __restrict__ off2,
    const int* __restrict__ csr2,
    const float* __restrict__ bias1, const float* __restrict__ bias2,
    float* __restrict__ outF, bf16* __restrict__ outHi, bf16* __restrict__ outLo,
    const float* __restrict__ wr2, float* __restrict__ erOut,
    int n_dst) {
  const int lane = threadIdx.x & 63;
  const int myh = lane >> 4;
  const int gw = (blockIdx.x * blockDim.x + threadIdx.x) >> 6;
  if (gw >= n_dst) return;

  float4 res = agg_walk((const short*)F1, el1, er1[gw * 4 + myh],
                        csr1, off1[gw], off1[gw + 1], myh, lane);
  if (F2) {
    const float4 r2 = agg_walk((const short*)F2, el2, er2[gw * 4 + myh],
                               csr2, off2[gw], off2[gw + 1], myh, lane);
    res.x += r2.x; res.y += r2.y; res.z += r2.z; res.w += r2.w;
  }
  {
    float4 bb = *reinterpret_cast<const float4*>(&bias1[lane * 4]);
    if (bias2) {
      const float4 b2 = *reinterpret_cast<const float4*>(&bias2[lane * 4]);
      bb.x += b2.x; bb.y += b2.y; bb.z += b2.z; bb.w += b2.w;
    }
    res.x = fmaxf(res.x + bb.x, 0.f);
    res.y = fmaxf(res.y + bb.y, 0.f);
    res.z = fmaxf(res.z + bb.z, 0.f);
    res.w = fmaxf(res.w + bb.w, 0.f);
  }
  if (outF) {
    *reinterpret_cast<float4*>(&outF[(size_t)gw * 256 + lane * 4]) = res;
  } else {
    const float rv[4] = {res.x, res.y, res.z, res.w};
    short4v hv, lv;
#pragma unroll
    for (int j = 0; j < 4; ++j) {
      bf16 h = __float2bfloat16(rv[j]);
      float r = rv[j] - __bfloat162float(h);
      bf16 l = __float2bfloat16(r);
      hv[j] = *reinterpret_cast<const short*>(&h);
      lv[j] = *reinterpret_cast<const short*>(&l);
    }
    *reinterpret_cast<short4v*>(&((short*)outHi)[(size_t)gw * 256 + lane * 4]) = hv;
    *reinterpret_cast<short4v*>(&((short*)outLo)[(size_t)gw * 256 + lane * 4]) = lv;
  }
  if (erOut) {
    float4 wv0 = *reinterpret_cast<const float4*>(&wr2[(lane * 4 + 0) * 4]);
    float4 wv1 = *reinterpret_cast<const float4*>(&wr2[(lane * 4 + 1) * 4]);
    float4 wv2 = *reinterpret_cast<const float4*>(&wr2[(lane * 4 + 2) * 4]);
    float4 wv3 = *reinterpret_cast<const float4*>(&wr2[(lane * 4 + 3) * 4]);
    float e0 = res.x * wv0.x + res.y * wv1.x + res.z * wv2.x + res.w * wv3.x;
    float e1 = res.x * wv0.y + res.y * wv1.y + res.z * wv2.y + res.w * wv3.y;
    float e2 = res.x * wv0.z + res.y * wv1.z + res.z * wv2.z + res.w * wv3.z;
    float e3 = res.x * wv0.w + res.y * wv1.w + res.z * wv2.w + res.w * wv3.w;
#pragma unroll
    for (int o = 32; o; o >>= 1) {
      e0 += __shfl_xor(e0, o);
      e1 += __shfl_xor(e1, o);
      e2 += __shfl_xor(e2, o);
      e3 += __shfl_xor(e3, o);
    }
    if (lane == 0) {
      erOut[gw * 4 + 0] = e0; erOut[gw * 4 + 1] = e1;
      erOut[gw * 4 + 2] = e2; erOut[gw * 4 + 3] = e3;
    }
  }
}

// ---------- graph readout stage 1 ----------
__global__ __launch_bounds__(256) void graph_sum_v3(
    const float* __restrict__ h, const int* __restrict__ gid,
    float* __restrict__ pbuf, int n) {
  __shared__ float sm[NGRAPH * 256];
  const int t = threadIdx.x;
  for (int i = t; i < NGRAPH * 256; i += 256) sm[i] = 0.f;
  __syncthreads();
  const int chunk = (n + RD_STRIPES - 1) / RD_STRIPES;
  const int lo = blockIdx.x * chunk;
  const int hiN = min(n, lo + chunk);
#pragma unroll 8
  for (int node = lo; node < hiN; ++node) {
    const int g = gid[node];
    const float v = h[(size_t)node * 256 + t];
    sm[g * 256 + t] += v;
  }
  __syncthreads();
  float* dst = pbuf + (size_t)blockIdx.x * (NGRAPH * 256);
  for (int i = t; i < NGRAPH * 256; i += 256) dst[i] = sm[i];
}

// ---------- graph readout stage 2 ----------
__global__ __launch_bounds__(256) void graph_reduce_kernel(
    const float* __restrict__ pbuf, float* __restrict__ gsum, int colofs) {
  const int g = blockIdx.x, t = threadIdx.x;
  float acc = 0.f;
#pragma unroll 8
  for (int s = 0; s < RD_STRIPES; ++s)
    acc += pbuf[(size_t)s * (NGRAPH * 256) + g * 256 + t];
  gsum[(size_t)g * 512 + colofs + t] = acc;
}

// ---------- graph node-count ----------
__global__ __launch_bounds__(256) void graph_count_kernel(
    const int* __restrict__ gid, int* __restrict__ gcnt, int n, int cntofs) {
  __shared__ int c[NGRAPH];
  if (threadIdx.x < NGRAPH) c[threadIdx.x] = 0;
  __syncthreads();
  for (int i = blockIdx.x * blockDim.x + threadIdx.x; i < n; i += gridDim.x * blockDim.x)
    atomicAdd(&c[gid[i]], 1);
  __syncthreads();
  if (threadIdx.x < NGRAPH && c[threadIdx.x])
    atomicAdd(&gcnt[cntofs + threadIdx.x], c[threadIdx.x]);
}

// ---------- final MLP ----------
__global__ __launch_bounds__(256) void mlp_kernel(
    const float* __restrict__ gsum, const int* __restrict__ gcnt,
    const float* __restrict__ Wm, const float* __restrict__ bm,
    float* __restrict__ out) {
  __shared__ float g[512];
  const int b = blockIdx.x, t = threadIdx.x;
  const float cl = fmaxf((float)gcnt[b], 1.f);
  const float cp = fmaxf((float)gcnt[64 + b], 1.f);
  for (int k = t; k < 512; k += 256)
    g[k] = gsum[(size_t)b * 512 + k] * (k < 256 ? 1.f / cl : 1.f / cp);
  __syncthreads();
  float acc = bm[t];
  for (int k = 0; k < 512; ++k) acc = fmaf(g[k], Wm[(size_t)k * 256 + t], acc);
  out[b * 256 + t] = fmaxf(acc, 0.f);
}

// =====================================================================
extern "C" void kernel_launch(void* const* d_in, const int* in_sizes, int n_in,
                              void* d_out, int out_size, void* d_ws, size_t ws_size,
                              hipStream_t stream) {
  const float* x_lig  = (const float*)d_in[0];
  const float* x_pro  = (const float*)d_in[1];
  const float* W1_ll  = (const float*)d_in[2];
  const float* al1_ll = (const float*)d_in[3];
  const float* ar1_ll = (const float*)d_in[4];
  const float* b1_ll  = (const float*)d_in[5];
  const float* W1_lps = (const float*)d_in[6];
  const float* W1_lpd = (const float*)d_in[7];
  const float* al1_lp = (const float*)d_in[8];
  const float* ar1_lp = (const float*)d_in[9];
  const float* b1_lp  = (const float*)d_in[10];
  const float* W1_pls = (const float*)d_in[11];
  const float* W1_pld = (const float*)d_in[12];
  const float* al1_pl = (const float*)d_in[13];
  const float* ar1_pl = (const float*)d_in[14];
  const float* b1_pl  = (const float*)d_in[15];
  const float* W2_ll  = (const float*)d_in[16];
  const float* al2_ll = (const float*)d_in[17];
  const float* ar2_ll = (const float*)d_in[18];
  const float* b2_ll  = (const float*)d_in[19];
  const float* W2_lps = (const float*)d_in[20];
  const float* W2_lpd = (const float*)d_in[21];
  const float* al2_lp = (const float*)d_in[22];
  const float* ar2_lp = (const float*)d_in[23];
  const float* b2_lp  = (const float*)d_in[24];
  const float* W2_pls = (const float*)d_in[25];
  const float* W2_pld = (const float*)d_in[26];
  const float* al2_pl = (const float*)d_in[27];
  const float* ar2_pl = (const float*)d_in[28];
  const float* b2_pl  = (const float*)d_in[29];
  const float* W_mlp  = (const float*)d_in[30];
  const float* b_mlp  = (const float*)d_in[31];
  const int* src_ll   = (const int*)d_in[32];
  const int* dst_ll   = (const int*)d_in[33];
  const int* src_lp   = (const int*)d_in[34];
  const int* dst_lp   = (const int*)d_in[35];
  const int* src_pl   = (const int*)d_in[36];
  const int* dst_pl   = (const int*)d_in[37];
  const int* gid_lig  = (const int*)d_in[38];
  const int* gid_pro  = (const int*)d_in[39];
  float* out = (float*)d_out;
  (void)in_sizes; (void)n_in; (void)out_size; (void)ws_size;

  // -------- workspace carving (~193 MB) --------
  size_t cur = 0;
  auto carve = [&](size_t bytes) -> char* {
    char* p = (char*)d_ws + cur;
    cur += (bytes + 511) & ~(size_t)511;
    return p;
  };
  const size_t NB   = (size_t)40000 * 256 * sizeof(float);
  const size_t NBH  = (size_t)40000 * 256 * sizeof(bf16);
  bf16* FbA   = (bf16*)carve(NBH);
  bf16* FbB   = (bf16*)carve(NBH);
  bf16* FbC   = (bf16*)carve(NBH);
  char* S1    = carve(NB);
  char* S2P   = carve(NB);
  float* hX   = (float*)carve(NB);
  float* elA  = (float*)carve((size_t)40000 * 4 * sizeof(float));
  float* erA  = (float*)carve((size_t)40000 * 4 * sizeof(float));
  float* elB  = (float*)carve((size_t)40000 * 4 * sizeof(float));
  float* erB  = (float*)carve((size_t)40000 * 4 * sizeof(float));
  float* elC  = (float*)carve((size_t)40000 * 4 * sizeof(float));
  float* erPL = (float*)carve((size_t)40000 * 4 * sizeof(float));
  float* erLP = (float*)carve((size_t)40000 * 4 * sizeof(float));
  float* wr1  = (float*)carve((size_t)256 * 4 * sizeof(float));
  float* wrA  = (float*)carve((size_t)256 * 4 * sizeof(float));
  float* wrB  = (float*)carve((size_t)256 * 4 * sizeof(float));
  bf16* Bthi  = (bf16*)carve((size_t)512 * 256 * sizeof(bf16));
  bf16* Btlo  = (bf16*)carve((size_t)512 * 256 * sizeof(bf16));
  float* gsum = (float*)carve((size_t)64 * 512 * sizeof(float));
  int* gcnt   = (int*)carve(128 * sizeof(int));
  int* bsum   = (int*)carve(1025 * sizeof(int));
  int* off_ll = (int*)carve((NLIG + 1) * sizeof(int));
  int* off_lp = (int*)carve((NPRO + 1) * sizeof(int));
  int* off_pl = (int*)carve((NLIG + 1) * sizeof(int));
  int* cursor = (int*)carve((NLIG + 1) * sizeof(int));
  int* csr_ll = (int*)carve((size_t)ELL * sizeof(int));
  int* csr_lp = (int*)carve((size_t)ELP * sizeof(int));
  int* csr_pl = (int*)carve((size_t)EPL * sizeof(int));

  // overlays / sub-pointers
  bf16* XLhi = (bf16*)S1;
  bf16* XLlo = XLhi + (size_t)40000 * 96;
  bf16* XPhi = (bf16*)S2P;
  bf16* XPlo = XPhi + (size_t)40000 * 128;
  bf16* S1hi = (bf16*)S1;
  bf16* S1lo = S1hi + (size_t)40000 * 256;
  bf16* S2hi = (bf16*)S2P;
  bf16* S2lo = S2hi + (size_t)40000 * 256;
  float* P2  = (float*)S2P;
  float* pbuf = (float*)FbA;

  const int B256 = 256;
  auto thrGrid  = [](long long n) { return (int)((n + 255) / 256); };
  auto waveGrid = [](int n) { return (n + 3) / 4; };

  auto conv_a = [&](const float* A, bf16* hi, bf16* lo, int M, int K, int Kp) {
    convA_kernel<<<(M + 7) / 8, B256, 0, stream>>>(A, hi, lo, M, K, Kp);
  };
  // one or two weight matrices (merged N=512 when Wb != null)
  auto run_mfma = [&](const bf16* ahi, const bf16* alo,
                      const float* Wa, const float* Wb, int K, int Kp, int M,
                      bf16* C0, bf16* C1,
                      const float* al0, float* el0, const float* ar0, float* er0,
                      const float* al1, float* el1) {
    convBt_kernel<<<256, B256, 0, stream>>>(Wa, Bthi, Btlo, K, Kp);
    if (Wb)
      convBt_kernel<<<256, B256, 0, stream>>>(Wb, Bthi + (size_t)256 * Kp,
                                              Btlo + (size_t)256 * Kp, K, Kp);
    const int log2ncb = Wb ? 2 : 1;
    const int nrt = (M + 127) / 128;
    const int nb = ((nrt + 7) / 8) * 8 * (1 << log2ncb);
    mfma_gemm<<<nb, B256, 0, stream>>>(ahi, alo, Bthi, Btlo, C0, C1, M, Kp, log2ncb,
                                       al0, el0, ar0, er0, al1, el1);
  };
  auto run_scan = [&](int* data, int n) {
    const int nb = (n + 1023) / 1024;
    scan_reduce_kernel<<<nb, B256, 0, stream>>>(data, bsum, n);
    scan_blocksums_kernel<<<1, 1024, 0, stream>>>(bsum, nb);
    scan_final_kernel<<<nb, 1024, 0, stream>>>(data, bsum, n);
  };

  // -------- CSR builds --------
  struct Rel { const int* src; const int* dst; int* off; int* csr; int E; int Nd; };
  Rel rels[3] = {
    {src_ll, dst_ll, off_ll, csr_ll, ELL, NLIG},
    {src_lp, dst_lp, off_lp, csr_lp, ELP, NPRO},
    {src_pl, dst_pl, off_pl, csr_pl, EPL, NLIG},
  };
  for (int r = 0; r < 3; ++r) {
    hipMemsetAsync(rels[r].off, 0, (rels[r].Nd + 1) * sizeof(int), stream);
    count_kernel<<<thrGrid(rels[r].E), B256, 0, stream>>>(rels[r].dst, rels[r].off, rels[r].E);
    run_scan(rels[r].off, rels[r].Nd);
    hipMemsetAsync(cursor, 0, (rels[r].Nd + 1) * sizeof(int), stream);
    fill_kernel<<<thrGrid(rels[r].E), B256, 0, stream>>>(
        rels[r].src, rels[r].dst, rels[r].off, cursor, rels[r].csr, rels[r].E);
  }

  // ================= LAYER 1 =================
  conv_a(x_lig, XLhi, XLlo, NLIG, 74, 96);
  conv_a(x_pro, XPhi, XPlo, NPRO, 128, 128);
  // merged: FbA = x_lig@W1_ll (+elA,erA), FbC = x_lig@W1_lps (+elC)
  run_mfma(XLhi, XLlo, W1_ll, W1_lps, 74, 96, NLIG,
           FbA, FbC, al1_ll, elA, ar1_ll, erA, al1_lp, elC);
  // pl src GEMM: FbB = x_pro @ W1_pls (+elB)
  run_mfma(XPhi, XPlo, W1_pls, nullptr, 128, 128, NPRO,
           FbB, nullptr, al1_pl, elB, nullptr, nullptr, nullptr, nullptr);
  // pl dst er: erB = x_lig @ (W1_pld . ar1_pl)  [LOG2E-scaled]
  make_wr_kernel<<<(74 * 4 + 255) / 256, B256, 0, stream>>>(W1_pld, ar1_pl, wr1, 74);
  er_gemv_kernel<<<waveGrid(NLIG), B256, 0, stream>>>(x_lig, wr1, erB, NLIG, 74);
  // layer-2 dst weights (scaled) for fused er epilogues
  make_wr_kernel<<<(256 * 4 + 255) / 256, B256, 0, stream>>>(W2_pld, ar2_pl, wrA, 256);
  make_wr_kernel<<<(256 * 4 + 255) / 256, B256, 0, stream>>>(W2_lpd, ar2_lp, wrB, 256);
  // fused dual agg -> S1 (bf16 split) + erPL (overwrites XL staging, dead)
  gat_agg_fused<<<waveGrid(NLIG), B256, 0, stream>>>(
      FbA, elA, erA, off_ll, csr_ll,
      FbB, elB, erB, off_pl, csr_pl,
      b1_ll, b1_pl, nullptr, S1hi, S1lo, wrA, erPL, NLIG);
  // lp dst er: erB = x_pro @ (W1_lpd . ar1_lp)
  make_wr_kernel<<<(128 * 4 + 255) / 256, B256, 0, stream>>>(W1_lpd, ar1_lp, wr1, 128);
  er_gemv_kernel<<<waveGrid(NPRO), B256, 0, stream>>>(x_pro, wr1, erB, NPRO, 128);
  // fused single agg (lp: FbC) -> S2 (bf16 split) + erLP (overwrites XP staging, dead)
  gat_agg_fused<<<waveGrid(NPRO), B256, 0, stream>>>(
      FbC, elC, erB, off_lp, csr_lp,
      nullptr, nullptr, nullptr, nullptr, nullptr,
      b1_lp, nullptr, nullptr, S2hi, S2lo, wrB, erLP, NPRO);

  // ================= LAYER 2 =================
  // merged: FbA = S1@W2_ll (+elA,erA), FbC = S1@W2_lps (+elC)
  run_mfma(S1hi, S1lo, W2_ll, W2_lps, 256, 256, NLIG,
           FbA, FbC, al2_ll, elA, ar2_ll, erA, al2_lp, elC);
  // pl src GEMM: FbB = S2 @ W2_pls (+elB)
  run_mfma(S2hi, S2lo, W2_pls, nullptr, 256, 256, NPRO,
           FbB, nullptr, al2_pl, elB, nullptr, nullptr, nullptr, nullptr);
  // fused dual agg -> hX
  gat_agg_fused<<<waveGrid(NLIG), B256, 0, stream>>>(
      FbA, elA, erA, off_ll, csr_ll,
      FbB, elB, erPL, off_pl, csr_pl,
      b2_ll, b2_pl, hX, nullptr, nullptr, nullptr, nullptr, NLIG);
  // fused single agg (lp: FbC) -> P2 (overlays S2P; S2 dead)
  gat_agg_fused<<<waveGrid(NPRO), B256, 0, stream>>>(
      FbC, elC, erLP, off_lp, csr_lp,
      nullptr, nullptr, nullptr, nullptr, nullptr,
      b2_lp, nullptr, P2, nullptr, nullptr, nullptr, nullptr, NPRO);

  // ================= READOUT (FbA dead -> pbuf) + MLP =================
  hipMemsetAsync(gcnt, 0, 128 * sizeof(int), stream);
  graph_sum_v3<<<RD_STRIPES, B256, 0, stream>>>(hX, gid_lig, pbuf, NLIG);
  graph_reduce_kernel<<<NGRAPH, B256, 0, stream>>>(pbuf, gsum, 0);
  graph_count_kernel<<<64, B256, 0, stream>>>(gid_lig, gcnt, NLIG, 0);
  graph_sum_v3<<<RD_STRIPES, B256, 0, stream>>>(P2, gid_pro, pbuf, NPRO);
  graph_reduce_kernel<<<NGRAPH, B256, 0, stream>>>(pbuf, gsum, 256);
  graph_count_kernel<<<64, B256, 0, stream>>>(gid_pro, gcnt, NPRO, 64);
  mlp_kernel<<<64, B256, 0, stream>>>(gsum, gcnt, W_mlp, b_mlp, out);
}